// Round 3
// baseline (369.607 us; speedup 1.0000x reference)
//
#include <hip/hip_runtime.h>
#include <hip/hip_bf16.h>
#include <math.h>

#define NB 4
#define NHW 4096
#define NBN (NB * NHW)
#define KSPLIT 8

typedef const float* fp;
typedef unsigned short us;
typedef __attribute__((ext_vector_type(8))) short short8;
typedef __attribute__((ext_vector_type(4))) short short4v;
typedef __attribute__((ext_vector_type(4))) float floatx4;
typedef __attribute__((ext_vector_type(2))) unsigned int uint2v;
typedef __attribute__((ext_vector_type(4))) unsigned int uint4v;

__device__ __forceinline__ float b2f(__hip_bfloat16 v) { return __bfloat162float(v); }
__device__ __forceinline__ __hip_bfloat16 f2b(float v) { return __float2bfloat16(v); }
__device__ __forceinline__ us f2bu(float f) {
  __hip_bfloat16 h = __float2bfloat16(f);
  return *reinterpret_cast<us*>(&h);
}
__device__ __forceinline__ float bu2f(us u) {
  __hip_bfloat16 h = *reinterpret_cast<__hip_bfloat16*>(&u);
  return __bfloat162float(h);
}
__device__ __forceinline__ float gelu_ex(float x) { return 0.5f * x * (1.0f + erff(x * 0.70710678118654752f)); }
__device__ __forceinline__ short8 ld8(const us* p) { return *(const short8*)p; }

// packed f32x2 -> bf16x2 (RNE), single instruction (T12; no builtin on gfx950)
__device__ __forceinline__ unsigned cvt_pk_bf16(float lo, float hi) {
  unsigned r;
  asm("v_cvt_pk_bf16_f32 %0, %1, %2" : "=v"(r) : "v"(lo), "v"(hi));
  return r;
}
// cross-quad reductions via permlane swaps (VALU-speed, no LDS/bpermute latency)
__device__ __forceinline__ float qmax4(float v) {
  uint2v p = __builtin_amdgcn_permlane16_swap(__float_as_uint(v), __float_as_uint(v), false, false);
  v = fmaxf(__uint_as_float(p.x), __uint_as_float(p.y));
  p = __builtin_amdgcn_permlane32_swap(__float_as_uint(v), __float_as_uint(v), false, false);
  return fmaxf(__uint_as_float(p.x), __uint_as_float(p.y));
}
__device__ __forceinline__ float qsum4(float v) {
  uint2v p = __builtin_amdgcn_permlane16_swap(__float_as_uint(v), __float_as_uint(v), false, false);
  v = __uint_as_float(p.x) + __uint_as_float(p.y);
  p = __builtin_amdgcn_permlane32_swap(__float_as_uint(v), __float_as_uint(v), false, false);
  return __uint_as_float(p.x) + __uint_as_float(p.y);
}

// ---------------- 0a. cast qkv weights f32 [96][256] -> bf16
__global__ __launch_bounds__(256) void k_wq(fp qw, us* wq) {
  int i = blockIdx.x * 256 + threadIdx.x;
  if (i >= 96 * 256) return;
  wq[i] = f2bu(qw[i]);
}

// ---------------- 0b. cast weights -> bf16 (offsets in shorts)
// proj @0, mlp1 @8192, down @24576, mlp2 @45056, up @61440, dwT[tap][ch] @77824,
// ewT[tap][oc] @80128, woff[32 pad][9*64] @80704; total 99136
__global__ __launch_bounds__(256) void k_wcast(fp pw, fp m1w, fp dnw, fp m2w, fp uw, fp dww,
                                               fp ew, fp ow, us* wc) {
  int i = blockIdx.x * 256 + threadIdx.x;
  if (i >= 99136) return;
  float v;
  if (i < 8192) v = pw[i];
  else if (i < 24576) v = m1w[i - 8192];
  else if (i < 45056) v = dnw[i - 24576];
  else if (i < 61440) v = m2w[i - 45056];
  else if (i < 77824) v = uw[i - 61440];
  else if (i < 80128) {
    int i2 = i - 77824;           // dwT: tap = i2>>8, ch = i2&255
    v = dww[(i2 & 255) * 9 + (i2 >> 8)];
  } else if (i < 80704) {
    int i2 = i - 80128;           // ewT: tap = i2>>6, oc = i2&63
    v = ew[(i2 & 63) * 9 + (i2 >> 6)];
  } else {
    int i2 = i - 80704;           // woff[oc][tap*64+c], oc padded to 32
    int oc = i2 / 576, rem = i2 % 576;
    int tap = rem >> 6, c = rem & 63;
    v = (oc < 18) ? ow[(oc * 64 + c) * 9 + tap] : 0.f;
  }
  wc[i] = f2bu(v);
}

// ---------------- 0c. deform weights: dw[oc][c][tap] -> wbf[tap][oc][c] bf16 (r8 verbatim)
__global__ __launch_bounds__(256) void k_wprep(fp dw, us* wbf) {
  int idx = blockIdx.x * 256 + threadIdx.x;
  if (idx >= 9 * 64 * 64) return;
  int c = idx & 63, oc = (idx >> 6) & 63, k = idx >> 12;
  wbf[idx] = f2bu(dw[(oc * 64 + c) * 9 + k]);
}

// ---------------- 1. bilinear upsample -> su f32 (r8 verbatim)
__global__ __launch_bounds__(256) void k_upsample(fp skip, float* su) {
  int idx = blockIdx.x * 256 + threadIdx.x;
  if (idx >= NB * 64 * NHW) return;
  int hw = idx & 4095, bc = idx >> 12;
  int y = hw >> 6, x = hw & 63;
  float fy = 0.5f * y - 0.25f, fx = 0.5f * x - 0.25f;
  float y0f = floorf(fy), x0f = floorf(fx);
  float wy = fy - y0f, wx = fx - x0f;
  int y0 = (int)y0f, x0 = (int)x0f;
  int y0c = min(31, max(0, y0)), y1c = min(31, max(0, y0 + 1));
  int x0c = min(31, max(0, x0)), x1c = min(31, max(0, x0 + 1));
  const float* p = skip + (size_t)bc * 1024;
  float v00 = p[y0c * 32 + x0c], v01 = p[y0c * 32 + x1c];
  float v10 = p[y1c * 32 + x0c], v11 = p[y1c * 32 + x1c];
  su[idx] = (1.f - wy) * ((1.f - wx) * v00 + wx * v01) + wy * ((1.f - wx) * v10 + wx * v11);
}

// ---------------- 2. transpose x f32 -> xT bf16 [b*4096][256] (r8 verbatim)
__global__ __launch_bounds__(256) void k_xpose(fp x, us* xT) {
  __shared__ float tile[64][65];
  int bid = blockIdx.x;
  int pt = bid & 63, ct = (bid >> 6) & 3, b = bid >> 8;
  int px0 = pt * 64, c0 = ct * 64;
  int tx = threadIdx.x & 63, ty = threadIdx.x >> 6;
  const float* src = x + ((size_t)(b * 256 + c0)) * NHW + px0;
#pragma unroll
  for (int i = 0; i < 16; i++) {
    int r = i * 4 + ty;
    tile[r][tx] = src[(size_t)r * NHW + tx];
  }
  __syncthreads();
  int cseg = threadIdx.x & 7, p0 = threadIdx.x >> 3;
#pragma unroll
  for (int h = 0; h < 2; h++) {
    int p = p0 + h * 32;
    short8 v;
#pragma unroll
    for (int j = 0; j < 8; j++) v[j] = (short)f2bu(tile[cseg * 8 + j][p]);
    *(short8*)&xT[((size_t)(b * NHW) + px0 + p) * 256 + c0 + cseg * 8] = v;
  }
}

// ---------------- 3. qkv GEMM -> Q,V ch-major bf16 [b][96][N]; K px-major kpx[b*N][32]
// Q scale folds 1/sqrt(32) * log2(e) so attention runs in exp2 domain.
__global__ __launch_bounds__(256) void k_qkv_g(const us* xT, const us* wq, fp bias, us* qkvb, us* kpx) {
  int wave = threadIdx.x >> 6, lane = threadIdx.x & 63;
  int quad = lane >> 4, l16 = lane & 15;
  int pxg0 = blockIdx.x * 64 + wave * 16;
  int b = pxg0 >> 12, hw0 = pxg0 & 4095;
  floatx4 acc[6];
#pragma unroll
  for (int m = 0; m < 6; m++) acc[m] = (floatx4){0.f, 0.f, 0.f, 0.f};
  const us* xrow = xT + (size_t)(pxg0 + l16) * 256 + quad * 8;
#pragma unroll
  for (int k0 = 0; k0 < 256; k0 += 32) {
    short8 bf = ld8(xrow + k0);
#pragma unroll
    for (int m = 0; m < 6; m++) {
      short8 af = ld8(wq + (size_t)(m * 16 + l16) * 256 + k0 + quad * 8);
      acc[m] = __builtin_amdgcn_mfma_f32_16x16x32_bf16(af, bf, acc[m], 0, 0, 0);
    }
  }
#pragma unroll
  for (int m = 0; m < 6; m++) {
    if (m == 2 || m == 3) {
      // K channels -> px-major, 4 consecutive oc per lane -> one b64 store
      short4v pkv;
#pragma unroll
      for (int r = 0; r < 4; r++) {
        int oc = m * 16 + quad * 4 + r;
        pkv[r] = (short)f2bu(acc[m][r] + bias[oc]);
      }
      *(short4v*)&kpx[((size_t)(b * NHW) + hw0 + l16) * 32 + (m - 2) * 16 + quad * 4] = pkv;
    } else {
#pragma unroll
      for (int r = 0; r < 4; r++) {
        int oc = m * 16 + quad * 4 + r;
        float v = acc[m][r] + bias[oc];
        if (oc < 32) v *= 0.25503485f;   // (1/sqrt(32)) * log2(e)
        qkvb[(size_t)(b * 96 + oc) * NHW + hw0 + l16] = f2bu(v);
      }
    }
  }
}

// ---------------- 4. LDS-free flash attention, SPLIT-K x8, swapped QK^T.
// Each lane owns one query (q = l16). S^T = mfma(K_px, Q); softmax reduce =
// max3-fused in-lane tree + permlane swaps; P packed via v_cvt_pk_bf16_f32;
// P^T in-register via permlane32/16_swap; O^T = mfma(V, P^T). 56 VGPR -> 8 waves/SIMD.
__global__ __launch_bounds__(256, 8) void k_attn(const us* qkvb, const us* kpx, us* Opart, float* ml) {
  int tid = threadIdx.x;
  int wave = tid >> 6, lane = tid & 63;
  int quad = lane >> 4, l16 = lane & 15;
  int blk = blockIdx.x;
  int kh = blk & 7;
  int rest = blk >> 3;
  int b = rest >> 6;
  int qbase = (rest & 63) * 64 + wave * 16;
  const us* qp = qkvb + (size_t)b * 96 * NHW;
  const us* vp = qp + 64 * NHW;
  const us* kb_base = kpx + (size_t)b * NHW * 32;

  // Q fragment as B-operand: B[col=q=l16][k=ch=quad*8+j]
  short8 bq;
#pragma unroll
  for (int j = 0; j < 8; j++)
    bq[j] = (short)qp[(size_t)(quad * 8 + j) * NHW + qbase + l16];

  float m_r = -1e30f, l_r = 0.f;
  floatx4 o0 = {0.f, 0.f, 0.f, 0.f}, o1 = {0.f, 0.f, 0.f, 0.f};

  int kb0 = kh * 512;
  // prefetch first K tile: A[row=key=l16][k=ch]
  short8 akf[8];
#pragma unroll
  for (int t = 0; t < 8; t++)
    akf[t] = ld8(kb_base + (size_t)(kb0 + t * 16 + l16) * 32 + quad * 8);

  for (int kb = kb0; kb < kb0 + 512; kb += 128) {
    // S^T: sT[t][r] = S[key = kb + t*16 + quad*4 + r][q = l16]
    floatx4 sT[8];
    __builtin_amdgcn_s_setprio(1);
#pragma unroll
    for (int t = 0; t < 8; t++) {
      floatx4 z = {0.f, 0.f, 0.f, 0.f};
      sT[t] = __builtin_amdgcn_mfma_f32_16x16x32_bf16(akf[t], bq, z, 0, 0, 0);
    }
    __builtin_amdgcn_s_setprio(0);

    // prefetch next K tile under the softmax VALU work
    int kbn = (kb + 128 < kb0 + 512) ? kb + 128 : kb0;
#pragma unroll
    for (int t = 0; t < 8; t++)
      akf[t] = ld8(kb_base + (size_t)(kbn + t * 16 + l16) * 32 + quad * 8);

    // running max: chained in-lane tree (fuses to v_max3) + 2 permlane swaps
    float tm[8];
#pragma unroll
    for (int t = 0; t < 8; t++)
      tm[t] = fmaxf(fmaxf(fmaxf(sT[t][0], sT[t][1]), sT[t][2]), sT[t][3]);
    float mx = fmaxf(fmaxf(fmaxf(tm[0], tm[1]), tm[2]), tm[3]);
    mx = fmaxf(fmaxf(fmaxf(fmaxf(mx, tm[4]), tm[5]), tm[6]), tm[7]);
    mx = qmax4(mx);
    float mnew = fmaxf(m_r, mx);
    float alpha = exp2f(m_r - mnew);
    m_r = mnew;

    // P = 2^(s - m), packed to bf16 pairs via v_cvt_pk_bf16_f32
    float rs0 = 0.f, rs1 = 0.f;
    unsigned pkw[8][2];
#pragma unroll
    for (int t = 0; t < 8; t++) {
      float p0 = exp2f(sT[t][0] - mnew);
      float p1 = exp2f(sT[t][1] - mnew);
      float p2 = exp2f(sT[t][2] - mnew);
      float p3 = exp2f(sT[t][3] - mnew);
      rs0 += p0 + p1;
      rs1 += p2 + p3;
      pkw[t][0] = cvt_pk_bf16(p0, p1);
      pkw[t][1] = cvt_pk_bf16(p2, p3);
    }
    float rs = qsum4(rs0 + rs1);
    l_r = l_r * alpha + rs;
#pragma unroll
    for (int r = 0; r < 4; r++) { o0[r] *= alpha; o1[r] *= alpha; }

    // PV: O^T += V * P^T. P^T redistributed across quads:
    // (w0,w2) = permlane16_swap(permlane32_swap(X0, Y0)); (w1,w3) likewise on (X1, Y1).
    __builtin_amdgcn_s_setprio(1);
#pragma unroll
    for (int cc = 0; cc < 4; cc++) {
      uint2v t1 = __builtin_amdgcn_permlane32_swap(pkw[2 * cc][0], pkw[2 * cc + 1][0], false, false);
      uint2v t2 = __builtin_amdgcn_permlane16_swap(t1.x, t1.y, false, false);
      uint2v t3 = __builtin_amdgcn_permlane32_swap(pkw[2 * cc][1], pkw[2 * cc + 1][1], false, false);
      uint2v t4 = __builtin_amdgcn_permlane16_swap(t3.x, t3.y, false, false);
      uint4v pw = {t2.x, t4.x, t2.y, t4.y};
      short8 pa = *(short8*)&pw;
      short8 av0 = ld8(vp + (size_t)l16 * NHW + kb + cc * 32 + quad * 8);
      short8 av1 = ld8(vp + (size_t)(l16 + 16) * NHW + kb + cc * 32 + quad * 8);
      o0 = __builtin_amdgcn_mfma_f32_16x16x32_bf16(av0, pa, o0, 0, 0, 0);
      o1 = __builtin_amdgcn_mfma_f32_16x16x32_bf16(av1, pa, o1, 0, 0, 0);
    }
    __builtin_amdgcn_s_setprio(0);
  }

  // epilogue: lane owns q = qbase + l16, channels quad*4+r (o0) and 16+quad*4+r (o1)
  int q = qbase + l16;
  size_t qg = (size_t)b * NHW + q;
  us* dst = Opart + ((size_t)kh * NBN + qg) * 32;
  short4v e0, e1;
#pragma unroll
  for (int r = 0; r < 4; r++) { e0[r] = (short)f2bu(o0[r]); e1[r] = (short)f2bu(o1[r]); }
  *(short4v*)(dst + quad * 4) = e0;
  *(short4v*)(dst + 16 + quad * 4) = e1;
  if (quad == 0) {
    ml[(size_t)kh * NBN + qg] = m_r;
    ml[(size_t)KSPLIT * NBN + (size_t)kh * NBN + qg] = l_r;
  }
}

// ---------------- 4b. merge 8 split-K partials -> avb px-major bf16 (exp2 domain)
__global__ __launch_bounds__(256) void k_merge(const us* Opart, const float* ml, us* avb) {
  int idx = blockIdx.x * 256 + threadIdx.x;
  int ch = idx & 31, qg = idx >> 5;
  float mk[KSPLIT];
  float m = -1e30f;
#pragma unroll
  for (int kh = 0; kh < KSPLIT; kh++) { mk[kh] = ml[kh * NBN + qg]; m = fmaxf(m, mk[kh]); }
  float l = 0.f, v = 0.f;
#pragma unroll
  for (int kh = 0; kh < KSPLIT; kh++) {
    float a = exp2f(mk[kh] - m);
    l += ml[KSPLIT * NBN + kh * NBN + qg] * a;
    v += bu2f(Opart[((size_t)(kh * NBN) + qg) * 32 + ch]) * a;
  }
  avb[idx] = f2bu(v / l);
}

// ---------------- 5. proj GEMM act-first (r10 verbatim)
__global__ __launch_bounds__(256) void k_proj_g(const us* avb, const us* xT, const us* wpj, fp bias, us* x2T) {
  int wave = threadIdx.x >> 6, lane = threadIdx.x & 63;
  int quad = lane >> 4, l16 = lane & 15;
  int pxg0 = blockIdx.x * 64 + wave * 16;
  short8 act = ld8(avb + (size_t)(pxg0 + l16) * 32 + quad * 8);
  floatx4 acc[16];
#pragma unroll
  for (int n = 0; n < 16; n++) {
    short8 wf = ld8(wpj + (size_t)(n * 16 + l16) * 32 + quad * 8);
    floatx4 z = {0.f, 0.f, 0.f, 0.f};
    acc[n] = __builtin_amdgcn_mfma_f32_16x16x32_bf16(act, wf, z, 0, 0, 0);
  }
#pragma unroll
  for (int n = 0; n < 16; n++)
#pragma unroll
    for (int r = 0; r < 4; r++) {
      int px = pxg0 + quad * 4 + r;
      int oc = n * 16 + l16;
      size_t oidx = (size_t)px * 256 + oc;
      x2T[oidx] = f2bu(acc[n][r] + bias[oc] + bu2f(xT[oidx]));
    }
}

// ---------------- 6. channel mean + thick (r8 verbatim)
__global__ __launch_bounds__(256) void k_meanthick(const float* su, fp tw, fp tb, float* sm, float* thick) {
  int idx = blockIdx.x * 256 + threadIdx.x;
  if (idx >= NB * NHW) return;
  int hw = idx & 4095, b = idx >> 12;
  const float* p = su + (size_t)b * 64 * NHW + hw;
  float s = 0.f, ts = 0.f;
#pragma unroll 8
  for (int c = 0; c < 64; c++) {
    float v = p[(size_t)c * NHW];
    s += v;
    ts += v * tw[c];
  }
  sm[idx] = s * (1.f / 64.f);
  float z = ts + tb[0];
  thick[idx] = 1.f / (1.f + __expf(-z));
}

// ---------------- 7. edge conv 3x3 px-major: thread=(px, 8-oc block) -> edgeT bf16 [b*N][64]
__global__ __launch_bounds__(256) void k_edge_px(const float* sm, const us* ewT, us* edgeT) {
  int idx = blockIdx.x * 256 + threadIdx.x;   // NB*NHW*8
  int cb = idx & 7, pxg = idx >> 3;
  int b = pxg >> 12, hw = pxg & 4095;
  int y = hw >> 6, x = hw & 63;
  int c0 = cb * 8;
  float acc[8] = {0.f, 0.f, 0.f, 0.f, 0.f, 0.f, 0.f, 0.f};
#pragma unroll
  for (int ky = 0; ky < 3; ky++) {
#pragma unroll
    for (int kx = 0; kx < 3; kx++) {
      int yy = y + ky - 1, xx = x + kx - 1;
      if (yy >= 0 && yy < 64 && xx >= 0 && xx < 64) {
        float sv = sm[b * NHW + yy * 64 + xx];
        short8 wv = ld8(ewT + (ky * 3 + kx) * 64 + c0);
#pragma unroll
        for (int j = 0; j < 8; j++) acc[j] += sv * bu2f((us)wv[j]);
      }
    }
  }
  short8 pk;
#pragma unroll
  for (int j = 0; j < 8; j++) pk[j] = (short)f2bu(acc[j]);
  *(short8*)(edgeT + (size_t)pxg * 64 + c0) = pk;
}

// ---------------- 8. offset conv as MFMA GEMM: K=9x64, N=32(18 used), act=shifted edgeT rows
__global__ __launch_bounds__(256) void k_off_g(const us* edgeT, const us* woff, fp ob,
                                               const float* thick, float* offb) {
  int wave = threadIdx.x >> 6, lane = threadIdx.x & 63;
  int quad = lane >> 4, l16 = lane & 15;
  int pxg0 = blockIdx.x * 64 + wave * 16;
  int b = pxg0 >> 12;
  int pxl = pxg0 + l16;
  int hwl = pxl & 4095;
  int yl = hwl >> 6, xl = hwl & 63;
  floatx4 acc[2];
  acc[0] = (floatx4){0.f, 0.f, 0.f, 0.f};
  acc[1] = (floatx4){0.f, 0.f, 0.f, 0.f};
  const short8 zz = {0, 0, 0, 0, 0, 0, 0, 0};
#pragma unroll
  for (int t = 0; t < 9; t++) {
    int yy = yl + t / 3 - 1, xx = xl + t % 3 - 1;
    bool valid = (yy >= 0 && yy < 64 && xx >= 0 && xx < 64);
    const us* arow = edgeT + ((size_t)(b * NHW + yy * 64 + xx)) * 64;
#pragma unroll
    for (int s = 0; s < 2; s++) {
      short8 act = valid ? ld8(arow + s * 32 + quad * 8) : zz;   // k_dw-style conditional row load
      int kk = t * 64 + s * 32 + quad * 8;
#pragma unroll
      for (int n = 0; n < 2; n++) {
        short8 wf = ld8(woff + (size_t)(n * 16 + l16) * 576 + kk);
        acc[n] = __builtin_amdgcn_mfma_f32_16x16x32_bf16(act, wf, acc[n], 0, 0, 0);
      }
    }
  }
#pragma unroll
  for (int n = 0; n < 2; n++)
#pragma unroll
    for (int r = 0; r < 4; r++) {
      int oc = n * 16 + l16;
      if (oc < 18) {
        int px = pxg0 + quad * 4 + r;
        int hw = px & 4095;
        float v = (acc[n][r] + ob[oc]) * (1.f + 16.f * thick[px]);
        offb[(size_t)(b * 18 + oc) * NHW + hw] = v;
      }
    }
}

// ---------------- 9. MFMA deformable conv (r10 structure; edge residual from edgeT rows)
__global__ __launch_bounds__(256) void k_deform(const float* su, const float* offb,
                                                const us* wbf, fp db,
                                                const us* edgeT, us* dbufT) {
  __shared__ __align__(16) us samT[4][16][72];
  int tid = threadIdx.x;
  int wave = tid >> 6, lane = tid & 63;
  int quad = lane >> 4, l16 = lane & 15;
  int b = blockIdx.x >> 6, row = blockIdx.x & 63;
  const float* sub = su + (size_t)b * 64 * NHW;

  int sp = lane & 15, sq = lane >> 4;
  int hw_s = row * 64 + wave * 16 + sp;
  int x_s = wave * 16 + sp;

  floatx4 acc[4];
#pragma unroll
  for (int a = 0; a < 4; a++) acc[a] = (floatx4){0.f, 0.f, 0.f, 0.f};

  for (int k = 0; k < 9; k++) {
    float dy = offb[((size_t)(b * 18 + 2 * k)) * NHW + hw_s];
    float dx = offb[((size_t)(b * 18 + 2 * k + 1)) * NHW + hw_s];
    float py = (float)(row + k / 3 - 1) + dy;
    float pxf = (float)(x_s + k % 3 - 1) + dx;
    float y0f = floorf(py), x0f = floorf(pxf);
    float wy = py - y0f, wx = pxf - x0f;
    int y0 = (int)y0f, x0 = (int)x0f;
    int y1 = y0 + 1, x1 = x0 + 1;
    float vy0 = (y0 >= 0 && y0 < 64) ? 1.f : 0.f;
    float vy1 = (y1 >= 0 && y1 < 64) ? 1.f : 0.f;
    float vx0 = (x0 >= 0 && x0 < 64) ? 1.f : 0.f;
    float vx1 = (x1 >= 0 && x1 < 64) ? 1.f : 0.f;
    float w00 = (1.f - wy) * (1.f - wx) * vy0 * vx0;
    float w01 = (1.f - wy) * wx * vy0 * vx1;
    float w10 = wy * (1.f - wx) * vy1 * vx0;
    float w11 = wy * wx * vy1 * vx1;
    int y0c = min(63, max(0, y0)), y1c = min(63, max(0, y1));
    int x0c = min(63, max(0, x0)), x1c = min(63, max(0, x1));
    int i00 = y0c * 64 + x0c, i01 = y0c * 64 + x1c;
    int i10 = y1c * 64 + x0c, i11 = y1c * 64 + x1c;

#pragma unroll
    for (int i = 0; i < 16; i += 2) {
      int c0 = sq * 16 + i;
      const float* s0 = sub + (size_t)c0 * NHW;
      const float* s1 = s0 + NHW;
      float v0 = w00 * s0[i00] + w01 * s0[i01] + w10 * s0[i10] + w11 * s0[i11];
      float v1 = w00 * s1[i00] + w01 * s1[i01] + w10 * s1[i10] + w11 * s1[i11];
      unsigned int pk = (unsigned int)f2bu(v0) | ((unsigned int)f2bu(v1) << 16);
      *(unsigned int*)&samT[wave][sp][c0] = pk;
    }

#pragma unroll
    for (int s = 0; s < 2; s++) {
      short8 bfrag = *(const short8*)&samT[wave][l16][s * 32 + quad * 8];
#pragma unroll
      for (int a = 0; a < 4; a++) {
        short8 afrag = ld8(wbf + ((size_t)(k * 64 + a * 16 + l16) * 64 + s * 32 + quad * 8));
        acc[a] = __builtin_amdgcn_mfma_f32_16x16x32_bf16(bfrag, afrag, acc[a], 0, 0, 0);
      }
    }
  }

#pragma unroll
  for (int a = 0; a < 4; a++)
#pragma unroll
    for (int r = 0; r < 4; r++) {
      int oc = a * 16 + l16;
      int pxr = row * 64 + wave * 16 + quad * 4 + r;
      size_t rowi = (size_t)(b * NHW) + pxr;
      float v = acc[a][r] + db[oc] + bu2f(edgeT[rowi * 64 + oc]);
      dbufT[rowi * 64 + oc] = f2bu(v);
    }
}

// ---------------- 10. down GEMM act-first -> ebufT px-major f32 (r11 verbatim)
__global__ __launch_bounds__(256) void k_down_g(const us* x2T, const us* dbufT, const us* wd, fp bias, float* ebufT) {
  int wave = threadIdx.x >> 6, lane = threadIdx.x & 63;
  int quad = lane >> 4, l16 = lane & 15;
  int pxg0 = blockIdx.x * 64 + wave * 16;
  floatx4 acc[4];
#pragma unroll
  for (int m = 0; m < 4; m++) acc[m] = (floatx4){0.f, 0.f, 0.f, 0.f};
  const us* xrow = x2T + (size_t)(pxg0 + l16) * 256 + quad * 8;
#pragma unroll
  for (int k0 = 0; k0 < 256; k0 += 32) {
    short8 act = ld8(xrow + k0);
#pragma unroll
    for (int m = 0; m < 4; m++) {
      short8 wf = ld8(wd + (size_t)(m * 16 + l16) * 320 + k0 + quad * 8);
      acc[m] = __builtin_amdgcn_mfma_f32_16x16x32_bf16(act, wf, acc[m], 0, 0, 0);
    }
  }
  const us* drow = dbufT + (size_t)(pxg0 + l16) * 64 + quad * 8;
#pragma unroll
  for (int k0 = 0; k0 < 64; k0 += 32) {
    short8 act = ld8(drow + k0);
#pragma unroll
    for (int m = 0; m < 4; m++) {
      short8 wf = ld8(wd + (size_t)(m * 16 + l16) * 320 + 256 + k0 + quad * 8);
      acc[m] = __builtin_amdgcn_mfma_f32_16x16x32_bf16(act, wf, acc[m], 0, 0, 0);
    }
  }
#pragma unroll
  for (int m = 0; m < 4; m++)
#pragma unroll
    for (int r = 0; r < 4; r++) {
      int px = pxg0 + quad * 4 + r;
      int oc = m * 16 + l16;
      ebufT[(size_t)px * 64 + oc] = acc[m][r] + bias[oc];
    }
}

// ---------------- 11. LayerNorm px-major (r11 verbatim)
__global__ __launch_bounds__(256) void k_ln(const float* eT, fp g, fp bt, us* hnT) {
  int idx = blockIdx.x * 256 + threadIdx.x;
  if (idx >= NB * NHW) return;
  const float* p = eT + (size_t)idx * 64;
  float v[64];
  float s = 0.f;
#pragma unroll
  for (int i = 0; i < 16; i++) {
    float4 t = ((const float4*)p)[i];
    v[i * 4] = t.x; v[i * 4 + 1] = t.y; v[i * 4 + 2] = t.z; v[i * 4 + 3] = t.w;
    s += t.x + t.y + t.z + t.w;
  }
  float mu = s * (1.f / 64.f);
  float q = 0.f;
#pragma unroll
  for (int c = 0; c < 64; c++) { float d = v[c] - mu; q += d * d; }
  float rstd = rsqrtf(q * (1.f / 64.f) + 1e-5f);
  us* o = hnT + (size_t)idx * 64;
#pragma unroll
  for (int j = 0; j < 8; j++) {
    short8 pk;
#pragma unroll
    for (int t = 0; t < 8; t++) {
      int c = j * 8 + t;
      pk[t] = (short)f2bu((v[c] - mu) * rstd * g[c] + bt[c]);
    }
    *(short8*)(o + j * 8) = pk;
  }
}

// ---------------- 12. mlp1 GEMM act-first (r11 verbatim)
__global__ __launch_bounds__(256) void k_mlp1_g(const us* hnT, const us* wm1, fp bias, us* h1T) {
  int wave = threadIdx.x >> 6, lane = threadIdx.x & 63;
  int quad = lane >> 4, l16 = lane & 15;
  int pxg0 = blockIdx.x * 64 + wave * 16;
  floatx4 acc[16];
#pragma unroll
  for (int m = 0; m < 16; m++) acc[m] = (floatx4){0.f, 0.f, 0.f, 0.f};
  const us* hrow = hnT + (size_t)(pxg0 + l16) * 64 + quad * 8;
#pragma unroll
  for (int k0 = 0; k0 < 64; k0 += 32) {
    short8 act = ld8(hrow + k0);
#pragma unroll
    for (int m = 0; m < 16; m++) {
      short8 wf = ld8(wm1 + (size_t)(m * 16 + l16) * 64 + k0 + quad * 8);
      acc[m] = __builtin_amdgcn_mfma_f32_16x16x32_bf16(act, wf, acc[m], 0, 0, 0);
    }
  }
#pragma unroll
  for (int m = 0; m < 16; m++)
#pragma unroll
    for (int r = 0; r < 4; r++) {
      int px = pxg0 + quad * 4 + r;
      int oc = m * 16 + l16;
      h1T[(size_t)px * 256 + oc] = f2bu(gelu_ex(acc[m][r] + bias[oc]));
    }
}

// ---------------- 13. depthwise 3x3 + GELU, px-major (r12 verbatim)
__global__ __launch_bounds__(256) void k_dw(const us* h1T, const us* wdwT, fp bias, us* h2T) {
  int idx = blockIdx.x * 256 + threadIdx.x;   // NB*NHW*32
  int cb = idx & 31, pxg = idx >> 5;
  int b = pxg >> 12, hw = pxg & 4095;
  int y = hw >> 6, x = hw & 63;
  int c0 = cb * 8;
  float4 b0 = *(const float4*)(bias + c0);
  float4 b1 = *(const float4*)(bias + c0 + 4);
  float acc[8] = {b0.x, b0.y, b0.z, b0.w, b1.x, b1.y, b1.z, b1.w};
#pragma unroll
  for (int ky = 0; ky < 3; ky++) {
#pragma unroll
    for (int kx = 0; kx < 3; kx++) {
      int tap = ky * 3 + kx;
      short8 wv = ld8(wdwT + tap * 256 + c0);
      int yy = y + ky - 1, xx = x + kx - 1;
      if (yy >= 0 && yy < 64 && xx >= 0 && xx < 64) {
        short8 vv = ld8(h1T + ((size_t)(b * NHW + yy * 64 + xx)) * 256 + c0);
#pragma unroll
        for (int j = 0; j < 8; j++)
          acc[j] += bu2f((us)vv[j]) * bu2f((us)wv[j]);
      }
    }
  }
  short8 pk;
#pragma unroll
  for (int j = 0; j < 8; j++) pk[j] = (short)f2bu(gelu_ex(acc[j]));
  *(short8*)(h2T + (size_t)pxg * 256 + c0) = pk;
}

// ---------------- 14. mlp2 GEMM act-first (r11 verbatim)
__global__ __launch_bounds__(256) void k_mlp2_g(const us* h2T, const us* wm2, fp bias, const float* ebufT, us* tbufT) {
  int wave = threadIdx.x >> 6, lane = threadIdx.x & 63;
  int quad = lane >> 4, l16 = lane & 15;
  int pxg0 = blockIdx.x * 64 + wave * 16;
  floatx4 acc[4];
#pragma unroll
  for (int m = 0; m < 4; m++) acc[m] = (floatx4){0.f, 0.f, 0.f, 0.f};
  const us* hrow = h2T + (size_t)(pxg0 + l16) * 256 + quad * 8;
#pragma unroll
  for (int k0 = 0; k0 < 256; k0 += 32) {
    short8 act = ld8(hrow + k0);
#pragma unroll
    for (int m = 0; m < 4; m++) {
      short8 wf = ld8(wm2 + (size_t)(m * 16 + l16) * 256 + k0 + quad * 8);
      acc[m] = __builtin_amdgcn_mfma_f32_16x16x32_bf16(act, wf, acc[m], 0, 0, 0);
    }
  }
#pragma unroll
  for (int m = 0; m < 4; m++)
#pragma unroll
    for (int r = 0; r < 4; r++) {
      int px = pxg0 + quad * 4 + r;
      int oc = m * 16 + l16;
      size_t oidx = (size_t)px * 64 + oc;
      tbufT[oidx] = f2bu(acc[m][r] + bias[oc] + ebufT[oidx]);
    }
}

// ---------------- 15. up GEMM W-first (r11 verbatim)
__global__ __launch_bounds__(256) void k_up_g(const us* tbufT, const us* wu, fp bias, float* out) {
  int wave = threadIdx.x >> 6, lane = threadIdx.x & 63;
  int quad = lane >> 4, l16 = lane & 15;
  int pxg0 = blockIdx.x * 64 + wave * 16;
  int b = pxg0 >> 12, hw0 = pxg0 & 4095;
  floatx4 acc[16];
#pragma unroll
  for (int m = 0; m < 16; m++) acc[m] = (floatx4){0.f, 0.f, 0.f, 0.f};
  const us* trow = tbufT + (size_t)(pxg0 + l16) * 64 + quad * 8;
#pragma unroll
  for (int k0 = 0; k0 < 64; k0 += 32) {
    short8 bf = ld8(trow + k0);
#pragma unroll
    for (int m = 0; m < 16; m++) {
      short8 af = ld8(wu + (size_t)(m * 16 + l16) * 64 + k0 + quad * 8);
      acc[m] = __builtin_amdgcn_mfma_f32_16x16x32_bf16(af, bf, acc[m], 0, 0, 0);
    }
  }
#pragma unroll
  for (int m = 0; m < 16; m++)
#pragma unroll
    for (int r = 0; r < 4; r++) {
      int oc = m * 16 + quad * 4 + r;
      out[(size_t)(b * 256 + oc) * NHW + hw0 + l16] = acc[m][r] + bias[oc];
    }
}

extern "C" void kernel_launch(void* const* d_in, const int* in_sizes, int n_in,
                              void* d_out, int out_size, void* d_ws, size_t ws_size,
                              hipStream_t stream) {
  fp x = (fp)d_in[0], skip = (fp)d_in[1], qkv_w = (fp)d_in[2], qkv_b = (fp)d_in[3],
     proj_w = (fp)d_in[4], proj_b = (fp)d_in[5], edge_w = (fp)d_in[6], thick_w = (fp)d_in[7],
     thick_b = (fp)d_in[8], off_w = (fp)d_in[9], off_b = (fp)d_in[10], deform_w = (fp)d_in[11],
     deform_b = (fp)d_in[12], ln_g = (fp)d_in[13], ln_b = (fp)d_in[14], mlp1_w = (fp)d_in[15],
     mlp1_b = (fp)d_in[16], dw_w = (fp)d_in[17], dw_b = (fp)d_in[18], mlp2_w = (fp)d_in[19],
     mlp2_b = (fp)d_in[20], down_w = (fp)d_in[21], down_b = (fp)d_in[22], up_w = (fp)d_in[23],
     up_b = (fp)d_in[24];

  float* ws = (float*)d_ws;
  // ---- layout; wc 99,136 shorts; ml 2*8*NBN f32; Opart x8 in dead mid region ----
  float* su    = ws + 0;              // f32 [0, 1048576)
  us* qkvb  = (us*)(ws + 1048576);    // bf16 [1048576, 1835008)
  us* avb   = (us*)(ws + 1835008);    // bf16 524,288 elems [1835008, 2097152)
  us* wc    = (us*)(ws + 2097152);    // bf16 99,136 elems  [2097152, 2146720)
  float* ml = ws + 2146720;           // f32 2*8*NBN = 262,144  [2146720, 2408864)
  us* kpx   = (us*)(ws + 2408864);    // bf16 K px-major [b*N][32]: 524,288 elems [2408864, 2671008)
  us* x2T   = (us*)(ws + 3145728);    // bf16 px-major [b*N][256]: [3145728, 5242880)
  us* edgeT = (us*)(ws + 5242880);    // bf16 px-major [b*N][64]: 524,288 slots of 1M region
  float* offb  = ws + 6291456;        // f32 [6291456, 6586368)
  float* sm    = ws + 6586368;        // f32 (dead after k_edge_px)
  float* thick = ws + 6602752;        // f32 (dead after k_off_g)
  us* dbufT = (us*)(ws + 6619136);    // bf16 px-major [b*N][64]: [6619136, 7143424)
  float* ebufT = ws + 7143424;        // f32 px-major [b*N][64]: [7143424, 8192000)
  // aliases of dead/late regions:
  us* xT   = x2T;                     // xT live #3..#7; proj_g updates in-place
  us* wq   = dbufT;                   // wq live #0..#4; dead before attn overwrites region
  us* wbf  = (us*)sm;                 // deform weights, written after k_off_g
  us* Opart = (us*)(ws + 5242880);    // attn bf16 partials x8: 4,194,304 shorts = [5242880, 7340032) f32;
                                      // region (edgeT/offb/sm/thick/dbufT) written only AFTER k_merge
  us* hnT  = qkvb;                    // qkvb dead after k_attn
  us* h1T  = x2T;                     // x2T dead after k_down_g
  us* h2T  = (us*)ws;                 // [0, 2097152) slots all dead by k_dw
  us* tbufT = edgeT;                  // edgeT dead after k_deform

  dim3 blk(256);
  k_wq<<<96, blk, 0, stream>>>(qkv_w, wq);
  k_wcast<<<388, blk, 0, stream>>>(proj_w, mlp1_w, down_w, mlp2_w, up_w, dw_w, edge_w, off_w, wc);
  k_upsample<<<(NB * 64 * NHW) / 256, blk, 0, stream>>>(skip, su);
  k_xpose<<<1024, blk, 0, stream>>>(x, xT);
  k_qkv_g<<<(NB * NHW) / 64, blk, 0, stream>>>(xT, wq, qkv_b, qkvb, kpx);
  k_attn<<<(NB * NHW / 64) * KSPLIT, blk, 0, stream>>>(qkvb, kpx, Opart, ml);
  k_merge<<<(NB * NHW * 32) / 256, blk, 0, stream>>>(Opart, ml, avb);
  k_proj_g<<<(NB * NHW) / 64, blk, 0, stream>>>(avb, xT, wc, proj_b, x2T);
  k_meanthick<<<(NB * NHW) / 256, blk, 0, stream>>>(su, thick_w, thick_b, sm, thick);
  k_edge_px<<<(NB * NHW * 8) / 256, blk, 0, stream>>>(sm, wc + 80128, edgeT);
  k_off_g<<<(NB * NHW) / 64, blk, 0, stream>>>(edgeT, wc + 80704, off_b, thick, offb);
  k_wprep<<<144, blk, 0, stream>>>(deform_w, wbf);
  k_deform<<<NB * 64, blk, 0, stream>>>(su, offb, wbf, deform_b, edgeT, dbufT);
  k_down_g<<<(NB * NHW) / 64, blk, 0, stream>>>(x2T, dbufT, wc + 24576, down_b, ebufT);
  k_ln<<<(NB * NHW) / 256, blk, 0, stream>>>(ebufT, ln_g, ln_b, hnT);
  k_mlp1_g<<<(NB * NHW) / 64, blk, 0, stream>>>(hnT, wc + 8192, mlp1_b, h1T);
  k_dw<<<(NB * NHW * 32) / 256, blk, 0, stream>>>(h1T, wc + 77824, dw_b, h2T);
  k_mlp2_g<<<(NB * NHW) / 64, blk, 0, stream>>>(h2T, wc + 45056, mlp2_b, ebufT, tbufT);
  k_up_g<<<(NB * NHW) / 64, blk, 0, stream>>>(tbufT, wc + 61440, up_b, (float*)d_out);
}

// Round 4
// 327.035 us; speedup vs baseline: 1.1302x; 1.1302x over previous
//
#include <hip/hip_runtime.h>
#include <hip/hip_bf16.h>
#include <math.h>

#define NB 4
#define NHW 4096
#define NBN (NB * NHW)
#define KSPLIT 8

typedef const float* fp;
typedef unsigned short us;
typedef __attribute__((ext_vector_type(8))) short short8;
typedef __attribute__((ext_vector_type(4))) short short4v;
typedef __attribute__((ext_vector_type(4))) float floatx4;
typedef __attribute__((ext_vector_type(2))) unsigned int uint2v;
typedef __attribute__((ext_vector_type(4))) unsigned int uint4v;

__device__ __forceinline__ float b2f(__hip_bfloat16 v) { return __bfloat162float(v); }
__device__ __forceinline__ __hip_bfloat16 f2b(float v) { return __float2bfloat16(v); }
__device__ __forceinline__ us f2bu(float f) {
  __hip_bfloat16 h = __float2bfloat16(f);
  return *reinterpret_cast<us*>(&h);
}
__device__ __forceinline__ float bu2f(us u) {
  __hip_bfloat16 h = *reinterpret_cast<__hip_bfloat16*>(&u);
  return __bfloat162float(h);
}
__device__ __forceinline__ float gelu_ex(float x) { return 0.5f * x * (1.0f + erff(x * 0.70710678118654752f)); }
__device__ __forceinline__ short8 ld8(const us* p) { return *(const short8*)p; }

// packed f32x2 -> bf16x2 (RNE), single instruction (T12; no builtin on gfx950)
__device__ __forceinline__ unsigned cvt_pk_bf16(float lo, float hi) {
  unsigned r;
  asm("v_cvt_pk_bf16_f32 %0, %1, %2" : "=v"(r) : "v"(lo), "v"(hi));
  return r;
}
// cross-quad reductions via permlane swaps (VALU-speed, no LDS/bpermute latency)
__device__ __forceinline__ float qmax4(float v) {
  uint2v p = __builtin_amdgcn_permlane16_swap(__float_as_uint(v), __float_as_uint(v), false, false);
  v = fmaxf(__uint_as_float(p.x), __uint_as_float(p.y));
  p = __builtin_amdgcn_permlane32_swap(__float_as_uint(v), __float_as_uint(v), false, false);
  return fmaxf(__uint_as_float(p.x), __uint_as_float(p.y));
}
__device__ __forceinline__ float qsum4(float v) {
  uint2v p = __builtin_amdgcn_permlane16_swap(__float_as_uint(v), __float_as_uint(v), false, false);
  v = __uint_as_float(p.x) + __uint_as_float(p.y);
  p = __builtin_amdgcn_permlane32_swap(__float_as_uint(v), __float_as_uint(v), false, false);
  return __uint_as_float(p.x) + __uint_as_float(p.y);
}

// ---------------- 0a. cast qkv weights f32 [96][256] -> bf16
__global__ __launch_bounds__(256) void k_wq(fp qw, us* wq) {
  int i = blockIdx.x * 256 + threadIdx.x;
  if (i >= 96 * 256) return;
  wq[i] = f2bu(qw[i]);
}

// ---------------- 0b. cast weights -> bf16 (offsets in shorts)
// proj @0, mlp1 @8192, down @24576, mlp2 @45056, up @61440, dwT[tap][ch] @77824,
// ewT[tap][oc] @80128, woff[32 pad][9*64] @80704; total 99136
__global__ __launch_bounds__(256) void k_wcast(fp pw, fp m1w, fp dnw, fp m2w, fp uw, fp dww,
                                               fp ew, fp ow, us* wc) {
  int i = blockIdx.x * 256 + threadIdx.x;
  if (i >= 99136) return;
  float v;
  if (i < 8192) v = pw[i];
  else if (i < 24576) v = m1w[i - 8192];
  else if (i < 45056) v = dnw[i - 24576];
  else if (i < 61440) v = m2w[i - 45056];
  else if (i < 77824) v = uw[i - 61440];
  else if (i < 80128) {
    int i2 = i - 77824;           // dwT: tap = i2>>8, ch = i2&255
    v = dww[(i2 & 255) * 9 + (i2 >> 8)];
  } else if (i < 80704) {
    int i2 = i - 80128;           // ewT: tap = i2>>6, oc = i2&63
    v = ew[(i2 & 63) * 9 + (i2 >> 6)];
  } else {
    int i2 = i - 80704;           // woff[oc][tap*64+c], oc padded to 32
    int oc = i2 / 576, rem = i2 % 576;
    int tap = rem >> 6, c = rem & 63;
    v = (oc < 18) ? ow[(oc * 64 + c) * 9 + tap] : 0.f;
  }
  wc[i] = f2bu(v);
}

// ---------------- 0c. deform weights: dw[oc][c][tap] -> wbf[tap][oc][c] bf16 (r8 verbatim)
__global__ __launch_bounds__(256) void k_wprep(fp dw, us* wbf) {
  int idx = blockIdx.x * 256 + threadIdx.x;
  if (idx >= 9 * 64 * 64) return;
  int c = idx & 63, oc = (idx >> 6) & 63, k = idx >> 12;
  wbf[idx] = f2bu(dw[(oc * 64 + c) * 9 + k]);
}

// ---------------- 1. bilinear upsample -> su f32 (r8 verbatim)
__global__ __launch_bounds__(256) void k_upsample(fp skip, float* su) {
  int idx = blockIdx.x * 256 + threadIdx.x;
  if (idx >= NB * 64 * NHW) return;
  int hw = idx & 4095, bc = idx >> 12;
  int y = hw >> 6, x = hw & 63;
  float fy = 0.5f * y - 0.25f, fx = 0.5f * x - 0.25f;
  float y0f = floorf(fy), x0f = floorf(fx);
  float wy = fy - y0f, wx = fx - x0f;
  int y0 = (int)y0f, x0 = (int)x0f;
  int y0c = min(31, max(0, y0)), y1c = min(31, max(0, y0 + 1));
  int x0c = min(31, max(0, x0)), x1c = min(31, max(0, x0 + 1));
  const float* p = skip + (size_t)bc * 1024;
  float v00 = p[y0c * 32 + x0c], v01 = p[y0c * 32 + x1c];
  float v10 = p[y1c * 32 + x0c], v11 = p[y1c * 32 + x1c];
  su[idx] = (1.f - wy) * ((1.f - wx) * v00 + wx * v01) + wy * ((1.f - wx) * v10 + wx * v11);
}

// ---------------- 2. transpose x f32 -> xT bf16 [b*4096][256] (r8 verbatim)
__global__ __launch_bounds__(256) void k_xpose(fp x, us* xT) {
  __shared__ float tile[64][65];
  int bid = blockIdx.x;
  int pt = bid & 63, ct = (bid >> 6) & 3, b = bid >> 8;
  int px0 = pt * 64, c0 = ct * 64;
  int tx = threadIdx.x & 63, ty = threadIdx.x >> 6;
  const float* src = x + ((size_t)(b * 256 + c0)) * NHW + px0;
#pragma unroll
  for (int i = 0; i < 16; i++) {
    int r = i * 4 + ty;
    tile[r][tx] = src[(size_t)r * NHW + tx];
  }
  __syncthreads();
  int cseg = threadIdx.x & 7, p0 = threadIdx.x >> 3;
#pragma unroll
  for (int h = 0; h < 2; h++) {
    int p = p0 + h * 32;
    short8 v;
#pragma unroll
    for (int j = 0; j < 8; j++) v[j] = (short)f2bu(tile[cseg * 8 + j][p]);
    *(short8*)&xT[((size_t)(b * NHW) + px0 + p) * 256 + c0 + cseg * 8] = v;
  }
}

// ---------------- 3. qkv GEMM -> Q,V ch-major bf16 [b][96][N]; K px-major kpx[b*N][32]
// Q scale folds 1/sqrt(32) * log2(e) so attention runs in exp2 domain.
__global__ __launch_bounds__(256) void k_qkv_g(const us* xT, const us* wq, fp bias, us* qkvb, us* kpx) {
  int wave = threadIdx.x >> 6, lane = threadIdx.x & 63;
  int quad = lane >> 4, l16 = lane & 15;
  int pxg0 = blockIdx.x * 64 + wave * 16;
  int b = pxg0 >> 12, hw0 = pxg0 & 4095;
  floatx4 acc[6];
#pragma unroll
  for (int m = 0; m < 6; m++) acc[m] = (floatx4){0.f, 0.f, 0.f, 0.f};
  const us* xrow = xT + (size_t)(pxg0 + l16) * 256 + quad * 8;
#pragma unroll
  for (int k0 = 0; k0 < 256; k0 += 32) {
    short8 bf = ld8(xrow + k0);
#pragma unroll
    for (int m = 0; m < 6; m++) {
      short8 af = ld8(wq + (size_t)(m * 16 + l16) * 256 + k0 + quad * 8);
      acc[m] = __builtin_amdgcn_mfma_f32_16x16x32_bf16(af, bf, acc[m], 0, 0, 0);
    }
  }
#pragma unroll
  for (int m = 0; m < 6; m++) {
    if (m == 2 || m == 3) {
      // K channels -> px-major, 4 consecutive oc per lane -> one b64 store
      short4v pkv;
#pragma unroll
      for (int r = 0; r < 4; r++) {
        int oc = m * 16 + quad * 4 + r;
        pkv[r] = (short)f2bu(acc[m][r] + bias[oc]);
      }
      *(short4v*)&kpx[((size_t)(b * NHW) + hw0 + l16) * 32 + (m - 2) * 16 + quad * 4] = pkv;
    } else {
#pragma unroll
      for (int r = 0; r < 4; r++) {
        int oc = m * 16 + quad * 4 + r;
        float v = acc[m][r] + bias[oc];
        if (oc < 32) v *= 0.25503485f;   // (1/sqrt(32)) * log2(e)
        qkvb[(size_t)(b * 96 + oc) * NHW + hw0 + l16] = f2bu(v);
      }
    }
  }
}

// ---------------- 4. LDS-free flash attention, SPLIT-K x8, swapped QK^T.
// Each lane owns one query (q = l16). S^T = mfma(K_px, Q); softmax reduce =
// max3-fused in-lane tree + permlane swaps; P packed via v_cvt_pk_bf16_f32;
// P^T in-register via permlane32/16_swap; O^T = mfma(V, P^T).
// launch_bounds (256,4): round-2-proven register budget (56 VGPR, no scratch);
// (256,8) spilled catastrophically (r3: 257 MB scratch traffic/dispatch).
__global__ __launch_bounds__(256, 4) void k_attn(const us* qkvb, const us* kpx, us* Opart, float* ml) {
  int tid = threadIdx.x;
  int wave = tid >> 6, lane = tid & 63;
  int quad = lane >> 4, l16 = lane & 15;
  int blk = blockIdx.x;
  int kh = blk & 7;
  int rest = blk >> 3;
  int b = rest >> 6;
  int qbase = (rest & 63) * 64 + wave * 16;
  const us* qp = qkvb + (size_t)b * 96 * NHW;
  const us* vp = qp + 64 * NHW;
  const us* kb_base = kpx + (size_t)b * NHW * 32;

  // Q fragment as B-operand: B[col=q=l16][k=ch=quad*8+j]
  short8 bq;
#pragma unroll
  for (int j = 0; j < 8; j++)
    bq[j] = (short)qp[(size_t)(quad * 8 + j) * NHW + qbase + l16];

  float m_r = -1e30f, l_r = 0.f;
  floatx4 o0 = {0.f, 0.f, 0.f, 0.f}, o1 = {0.f, 0.f, 0.f, 0.f};

  int kb0 = kh * 512;
  for (int kb = kb0; kb < kb0 + 512; kb += 128) {
    // S^T: sT[t][r] = S[key = kb + t*16 + quad*4 + r][q = l16]
    // K fragments loaded inline (no persistent prefetch buffer -> lower VGPR
    // pressure; L2-hit latency hidden by 8 blocks/CU of TLP).
    floatx4 sT[8];
    __builtin_amdgcn_s_setprio(1);
#pragma unroll
    for (int t = 0; t < 8; t++) {
      short8 ak = ld8(kb_base + (size_t)(kb + t * 16 + l16) * 32 + quad * 8);
      floatx4 z = {0.f, 0.f, 0.f, 0.f};
      sT[t] = __builtin_amdgcn_mfma_f32_16x16x32_bf16(ak, bq, z, 0, 0, 0);
    }
    __builtin_amdgcn_s_setprio(0);

    // running max: chained in-lane tree (fuses to v_max3) + 2 permlane swaps
    float tm[8];
#pragma unroll
    for (int t = 0; t < 8; t++)
      tm[t] = fmaxf(fmaxf(fmaxf(sT[t][0], sT[t][1]), sT[t][2]), sT[t][3]);
    float mx = fmaxf(fmaxf(fmaxf(tm[0], tm[1]), tm[2]), tm[3]);
    mx = fmaxf(fmaxf(fmaxf(fmaxf(mx, tm[4]), tm[5]), tm[6]), tm[7]);
    mx = qmax4(mx);
    float mnew = fmaxf(m_r, mx);
    float alpha = exp2f(m_r - mnew);
    m_r = mnew;

    // P = 2^(s - m), packed to bf16 pairs via v_cvt_pk_bf16_f32
    float rs0 = 0.f, rs1 = 0.f;
    unsigned pkw[8][2];
#pragma unroll
    for (int t = 0; t < 8; t++) {
      float p0 = exp2f(sT[t][0] - mnew);
      float p1 = exp2f(sT[t][1] - mnew);
      float p2 = exp2f(sT[t][2] - mnew);
      float p3 = exp2f(sT[t][3] - mnew);
      rs0 += p0 + p1;
      rs1 += p2 + p3;
      pkw[t][0] = cvt_pk_bf16(p0, p1);
      pkw[t][1] = cvt_pk_bf16(p2, p3);
    }
    float rs = qsum4(rs0 + rs1);
    l_r = l_r * alpha + rs;
#pragma unroll
    for (int r = 0; r < 4; r++) { o0[r] *= alpha; o1[r] *= alpha; }

    // PV: O^T += V * P^T. P^T redistributed across quads:
    // (w0,w2) = permlane16_swap(permlane32_swap(X0, Y0)); (w1,w3) likewise on (X1, Y1).
    __builtin_amdgcn_s_setprio(1);
#pragma unroll
    for (int cc = 0; cc < 4; cc++) {
      uint2v t1 = __builtin_amdgcn_permlane32_swap(pkw[2 * cc][0], pkw[2 * cc + 1][0], false, false);
      uint2v t2 = __builtin_amdgcn_permlane16_swap(t1.x, t1.y, false, false);
      uint2v t3 = __builtin_amdgcn_permlane32_swap(pkw[2 * cc][1], pkw[2 * cc + 1][1], false, false);
      uint2v t4 = __builtin_amdgcn_permlane16_swap(t3.x, t3.y, false, false);
      uint4v pw = {t2.x, t4.x, t2.y, t4.y};
      short8 pa = *(short8*)&pw;
      short8 av0 = ld8(vp + (size_t)l16 * NHW + kb + cc * 32 + quad * 8);
      short8 av1 = ld8(vp + (size_t)(l16 + 16) * NHW + kb + cc * 32 + quad * 8);
      o0 = __builtin_amdgcn_mfma_f32_16x16x32_bf16(av0, pa, o0, 0, 0, 0);
      o1 = __builtin_amdgcn_mfma_f32_16x16x32_bf16(av1, pa, o1, 0, 0, 0);
    }
    __builtin_amdgcn_s_setprio(0);
  }

  // epilogue: lane owns q = qbase + l16, channels quad*4+r (o0) and 16+quad*4+r (o1)
  int q = qbase + l16;
  size_t qg = (size_t)b * NHW + q;
  us* dst = Opart + ((size_t)kh * NBN + qg) * 32;
  short4v e0, e1;
#pragma unroll
  for (int r = 0; r < 4; r++) { e0[r] = (short)f2bu(o0[r]); e1[r] = (short)f2bu(o1[r]); }
  *(short4v*)(dst + quad * 4) = e0;
  *(short4v*)(dst + 16 + quad * 4) = e1;
  if (quad == 0) {
    ml[(size_t)kh * NBN + qg] = m_r;
    ml[(size_t)KSPLIT * NBN + (size_t)kh * NBN + qg] = l_r;
  }
}

// ---------------- 4b. merge 8 split-K partials -> avb px-major bf16 (exp2 domain)
__global__ __launch_bounds__(256) void k_merge(const us* Opart, const float* ml, us* avb) {
  int idx = blockIdx.x * 256 + threadIdx.x;
  int ch = idx & 31, qg = idx >> 5;
  float mk[KSPLIT];
  float m = -1e30f;
#pragma unroll
  for (int kh = 0; kh < KSPLIT; kh++) { mk[kh] = ml[kh * NBN + qg]; m = fmaxf(m, mk[kh]); }
  float l = 0.f, v = 0.f;
#pragma unroll
  for (int kh = 0; kh < KSPLIT; kh++) {
    float a = exp2f(mk[kh] - m);
    l += ml[KSPLIT * NBN + kh * NBN + qg] * a;
    v += bu2f(Opart[((size_t)(kh * NBN) + qg) * 32 + ch]) * a;
  }
  avb[idx] = f2bu(v / l);
}

// ---------------- 5. proj GEMM act-first (r10 verbatim)
__global__ __launch_bounds__(256) void k_proj_g(const us* avb, const us* xT, const us* wpj, fp bias, us* x2T) {
  int wave = threadIdx.x >> 6, lane = threadIdx.x & 63;
  int quad = lane >> 4, l16 = lane & 15;
  int pxg0 = blockIdx.x * 64 + wave * 16;
  short8 act = ld8(avb + (size_t)(pxg0 + l16) * 32 + quad * 8);
  floatx4 acc[16];
#pragma unroll
  for (int n = 0; n < 16; n++) {
    short8 wf = ld8(wpj + (size_t)(n * 16 + l16) * 32 + quad * 8);
    floatx4 z = {0.f, 0.f, 0.f, 0.f};
    acc[n] = __builtin_amdgcn_mfma_f32_16x16x32_bf16(act, wf, z, 0, 0, 0);
  }
#pragma unroll
  for (int n = 0; n < 16; n++)
#pragma unroll
    for (int r = 0; r < 4; r++) {
      int px = pxg0 + quad * 4 + r;
      int oc = n * 16 + l16;
      size_t oidx = (size_t)px * 256 + oc;
      x2T[oidx] = f2bu(acc[n][r] + bias[oc] + bu2f(xT[oidx]));
    }
}

// ---------------- 6. channel mean + thick (r8 verbatim)
__global__ __launch_bounds__(256) void k_meanthick(const float* su, fp tw, fp tb, float* sm, float* thick) {
  int idx = blockIdx.x * 256 + threadIdx.x;
  if (idx >= NB * NHW) return;
  int hw = idx & 4095, b = idx >> 12;
  const float* p = su + (size_t)b * 64 * NHW + hw;
  float s = 0.f, ts = 0.f;
#pragma unroll 8
  for (int c = 0; c < 64; c++) {
    float v = p[(size_t)c * NHW];
    s += v;
    ts += v * tw[c];
  }
  sm[idx] = s * (1.f / 64.f);
  float z = ts + tb[0];
  thick[idx] = 1.f / (1.f + __expf(-z));
}

// ---------------- 7. edge conv 3x3 px-major: thread=(px, 8-oc block) -> edgeT bf16 [b*N][64]
__global__ __launch_bounds__(256) void k_edge_px(const float* sm, const us* ewT, us* edgeT) {
  int idx = blockIdx.x * 256 + threadIdx.x;   // NB*NHW*8
  int cb = idx & 7, pxg = idx >> 3;
  int b = pxg >> 12, hw = pxg & 4095;
  int y = hw >> 6, x = hw & 63;
  int c0 = cb * 8;
  float acc[8] = {0.f, 0.f, 0.f, 0.f, 0.f, 0.f, 0.f, 0.f};
#pragma unroll
  for (int ky = 0; ky < 3; ky++) {
#pragma unroll
    for (int kx = 0; kx < 3; kx++) {
      int yy = y + ky - 1, xx = x + kx - 1;
      if (yy >= 0 && yy < 64 && xx >= 0 && xx < 64) {
        float sv = sm[b * NHW + yy * 64 + xx];
        short8 wv = ld8(ewT + (ky * 3 + kx) * 64 + c0);
#pragma unroll
        for (int j = 0; j < 8; j++) acc[j] += sv * bu2f((us)wv[j]);
      }
    }
  }
  short8 pk;
#pragma unroll
  for (int j = 0; j < 8; j++) pk[j] = (short)f2bu(acc[j]);
  *(short8*)(edgeT + (size_t)pxg * 64 + c0) = pk;
}

// ---------------- 8. offset conv as MFMA GEMM: K=9x64, N=32(18 used), act=shifted edgeT rows
__global__ __launch_bounds__(256) void k_off_g(const us* edgeT, const us* woff, fp ob,
                                               const float* thick, float* offb) {
  int wave = threadIdx.x >> 6, lane = threadIdx.x & 63;
  int quad = lane >> 4, l16 = lane & 15;
  int pxg0 = blockIdx.x * 64 + wave * 16;
  int b = pxg0 >> 12;
  int pxl = pxg0 + l16;
  int hwl = pxl & 4095;
  int yl = hwl >> 6, xl = hwl & 63;
  floatx4 acc[2];
  acc[0] = (floatx4){0.f, 0.f, 0.f, 0.f};
  acc[1] = (floatx4){0.f, 0.f, 0.f, 0.f};
  const short8 zz = {0, 0, 0, 0, 0, 0, 0, 0};
#pragma unroll
  for (int t = 0; t < 9; t++) {
    int yy = yl + t / 3 - 1, xx = xl + t % 3 - 1;
    bool valid = (yy >= 0 && yy < 64 && xx >= 0 && xx < 64);
    const us* arow = edgeT + ((size_t)(b * NHW + yy * 64 + xx)) * 64;
#pragma unroll
    for (int s = 0; s < 2; s++) {
      short8 act = valid ? ld8(arow + s * 32 + quad * 8) : zz;   // k_dw-style conditional row load
      int kk = t * 64 + s * 32 + quad * 8;
#pragma unroll
      for (int n = 0; n < 2; n++) {
        short8 wf = ld8(woff + (size_t)(n * 16 + l16) * 576 + kk);
        acc[n] = __builtin_amdgcn_mfma_f32_16x16x32_bf16(act, wf, acc[n], 0, 0, 0);
      }
    }
  }
#pragma unroll
  for (int n = 0; n < 2; n++)
#pragma unroll
    for (int r = 0; r < 4; r++) {
      int oc = n * 16 + l16;
      if (oc < 18) {
        int px = pxg0 + quad * 4 + r;
        int hw = px & 4095;
        float v = (acc[n][r] + ob[oc]) * (1.f + 16.f * thick[px]);
        offb[(size_t)(b * 18 + oc) * NHW + hw] = v;
      }
    }
}

// ---------------- 9. MFMA deformable conv (r10 structure; edge residual from edgeT rows)
__global__ __launch_bounds__(256) void k_deform(const float* su, const float* offb,
                                                const us* wbf, fp db,
                                                const us* edgeT, us* dbufT) {
  __shared__ __align__(16) us samT[4][16][72];
  int tid = threadIdx.x;
  int wave = tid >> 6, lane = tid & 63;
  int quad = lane >> 4, l16 = lane & 15;
  int b = blockIdx.x >> 6, row = blockIdx.x & 63;
  const float* sub = su + (size_t)b * 64 * NHW;

  int sp = lane & 15, sq = lane >> 4;
  int hw_s = row * 64 + wave * 16 + sp;
  int x_s = wave * 16 + sp;

  floatx4 acc[4];
#pragma unroll
  for (int a = 0; a < 4; a++) acc[a] = (floatx4){0.f, 0.f, 0.f, 0.f};

  for (int k = 0; k < 9; k++) {
    float dy = offb[((size_t)(b * 18 + 2 * k)) * NHW + hw_s];
    float dx = offb[((size_t)(b * 18 + 2 * k + 1)) * NHW + hw_s];
    float py = (float)(row + k / 3 - 1) + dy;
    float pxf = (float)(x_s + k % 3 - 1) + dx;
    float y0f = floorf(py), x0f = floorf(pxf);
    float wy = py - y0f, wx = pxf - x0f;
    int y0 = (int)y0f, x0 = (int)x0f;
    int y1 = y0 + 1, x1 = x0 + 1;
    float vy0 = (y0 >= 0 && y0 < 64) ? 1.f : 0.f;
    float vy1 = (y1 >= 0 && y1 < 64) ? 1.f : 0.f;
    float vx0 = (x0 >= 0 && x0 < 64) ? 1.f : 0.f;
    float vx1 = (x1 >= 0 && x1 < 64) ? 1.f : 0.f;
    float w00 = (1.f - wy) * (1.f - wx) * vy0 * vx0;
    float w01 = (1.f - wy) * wx * vy0 * vx1;
    float w10 = wy * (1.f - wx) * vy1 * vx0;
    float w11 = wy * wx * vy1 * vx1;
    int y0c = min(63, max(0, y0)), y1c = min(63, max(0, y1));
    int x0c = min(63, max(0, x0)), x1c = min(63, max(0, x1));
    int i00 = y0c * 64 + x0c, i01 = y0c * 64 + x1c;
    int i10 = y1c * 64 + x0c, i11 = y1c * 64 + x1c;

#pragma unroll
    for (int i = 0; i < 16; i += 2) {
      int c0 = sq * 16 + i;
      const float* s0 = sub + (size_t)c0 * NHW;
      const float* s1 = s0 + NHW;
      float v0 = w00 * s0[i00] + w01 * s0[i01] + w10 * s0[i10] + w11 * s0[i11];
      float v1 = w00 * s1[i00] + w01 * s1[i01] + w10 * s1[i10] + w11 * s1[i11];
      unsigned int pk = (unsigned int)f2bu(v0) | ((unsigned int)f2bu(v1) << 16);
      *(unsigned int*)&samT[wave][sp][c0] = pk;
    }

#pragma unroll
    for (int s = 0; s < 2; s++) {
      short8 bfrag = *(const short8*)&samT[wave][l16][s * 32 + quad * 8];
#pragma unroll
      for (int a = 0; a < 4; a++) {
        short8 afrag = ld8(wbf + ((size_t)(k * 64 + a * 16 + l16) * 64 + s * 32 + quad * 8));
        acc[a] = __builtin_amdgcn_mfma_f32_16x16x32_bf16(bfrag, afrag, acc[a], 0, 0, 0);
      }
    }
  }

#pragma unroll
  for (int a = 0; a < 4; a++)
#pragma unroll
    for (int r = 0; r < 4; r++) {
      int oc = a * 16 + l16;
      int pxr = row * 64 + wave * 16 + quad * 4 + r;
      size_t rowi = (size_t)(b * NHW) + pxr;
      float v = acc[a][r] + db[oc] + bu2f(edgeT[rowi * 64 + oc]);
      dbufT[rowi * 64 + oc] = f2bu(v);
    }
}

// ---------------- 10. down GEMM act-first -> ebufT px-major f32 (r11 verbatim)
__global__ __launch_bounds__(256) void k_down_g(const us* x2T, const us* dbufT, const us* wd, fp bias, float* ebufT) {
  int wave = threadIdx.x >> 6, lane = threadIdx.x & 63;
  int quad = lane >> 4, l16 = lane & 15;
  int pxg0 = blockIdx.x * 64 + wave * 16;
  floatx4 acc[4];
#pragma unroll
  for (int m = 0; m < 4; m++) acc[m] = (floatx4){0.f, 0.f, 0.f, 0.f};
  const us* xrow = x2T + (size_t)(pxg0 + l16) * 256 + quad * 8;
#pragma unroll
  for (int k0 = 0; k0 < 256; k0 += 32) {
    short8 act = ld8(xrow + k0);
#pragma unroll
    for (int m = 0; m < 4; m++) {
      short8 wf = ld8(wd + (size_t)(m * 16 + l16) * 320 + k0 + quad * 8);
      acc[m] = __builtin_amdgcn_mfma_f32_16x16x32_bf16(act, wf, acc[m], 0, 0, 0);
    }
  }
  const us* drow = dbufT + (size_t)(pxg0 + l16) * 64 + quad * 8;
#pragma unroll
  for (int k0 = 0; k0 < 64; k0 += 32) {
    short8 act = ld8(drow + k0);
#pragma unroll
    for (int m = 0; m < 4; m++) {
      short8 wf = ld8(wd + (size_t)(m * 16 + l16) * 320 + 256 + k0 + quad * 8);
      acc[m] = __builtin_amdgcn_mfma_f32_16x16x32_bf16(act, wf, acc[m], 0, 0, 0);
    }
  }
#pragma unroll
  for (int m = 0; m < 4; m++)
#pragma unroll
    for (int r = 0; r < 4; r++) {
      int px = pxg0 + quad * 4 + r;
      int oc = m * 16 + l16;
      ebufT[(size_t)px * 64 + oc] = acc[m][r] + bias[oc];
    }
}

// ---------------- 11. LayerNorm px-major (r11 verbatim)
__global__ __launch_bounds__(256) void k_ln(const float* eT, fp g, fp bt, us* hnT) {
  int idx = blockIdx.x * 256 + threadIdx.x;
  if (idx >= NB * NHW) return;
  const float* p = eT + (size_t)idx * 64;
  float v[64];
  float s = 0.f;
#pragma unroll
  for (int i = 0; i < 16; i++) {
    float4 t = ((const float4*)p)[i];
    v[i * 4] = t.x; v[i * 4 + 1] = t.y; v[i * 4 + 2] = t.z; v[i * 4 + 3] = t.w;
    s += t.x + t.y + t.z + t.w;
  }
  float mu = s * (1.f / 64.f);
  float q = 0.f;
#pragma unroll
  for (int c = 0; c < 64; c++) { float d = v[c] - mu; q += d * d; }
  float rstd = rsqrtf(q * (1.f / 64.f) + 1e-5f);
  us* o = hnT + (size_t)idx * 64;
#pragma unroll
  for (int j = 0; j < 8; j++) {
    short8 pk;
#pragma unroll
    for (int t = 0; t < 8; t++) {
      int c = j * 8 + t;
      pk[t] = (short)f2bu((v[c] - mu) * rstd * g[c] + bt[c]);
    }
    *(short8*)(o + j * 8) = pk;
  }
}

// ---------------- 12. mlp1 GEMM act-first (r11 verbatim)
__global__ __launch_bounds__(256) void k_mlp1_g(const us* hnT, const us* wm1, fp bias, us* h1T) {
  int wave = threadIdx.x >> 6, lane = threadIdx.x & 63;
  int quad = lane >> 4, l16 = lane & 15;
  int pxg0 = blockIdx.x * 64 + wave * 16;
  floatx4 acc[16];
#pragma unroll
  for (int m = 0; m < 16; m++) acc[m] = (floatx4){0.f, 0.f, 0.f, 0.f};
  const us* hrow = hnT + (size_t)(pxg0 + l16) * 64 + quad * 8;
#pragma unroll
  for (int k0 = 0; k0 < 64; k0 += 32) {
    short8 act = ld8(hrow + k0);
#pragma unroll
    for (int m = 0; m < 16; m++) {
      short8 wf = ld8(wm1 + (size_t)(m * 16 + l16) * 64 + k0 + quad * 8);
      acc[m] = __builtin_amdgcn_mfma_f32_16x16x32_bf16(act, wf, acc[m], 0, 0, 0);
    }
  }
#pragma unroll
  for (int m = 0; m < 16; m++)
#pragma unroll
    for (int r = 0; r < 4; r++) {
      int px = pxg0 + quad * 4 + r;
      int oc = m * 16 + l16;
      h1T[(size_t)px * 256 + oc] = f2bu(gelu_ex(acc[m][r] + bias[oc]));
    }
}

// ---------------- 13. depthwise 3x3 + GELU, px-major (r12 verbatim)
__global__ __launch_bounds__(256) void k_dw(const us* h1T, const us* wdwT, fp bias, us* h2T) {
  int idx = blockIdx.x * 256 + threadIdx.x;   // NB*NHW*32
  int cb = idx & 31, pxg = idx >> 5;
  int b = pxg >> 12, hw = pxg & 4095;
  int y = hw >> 6, x = hw & 63;
  int c0 = cb * 8;
  float4 b0 = *(const float4*)(bias + c0);
  float4 b1 = *(const float4*)(bias + c0 + 4);
  float acc[8] = {b0.x, b0.y, b0.z, b0.w, b1.x, b1.y, b1.z, b1.w};
#pragma unroll
  for (int ky = 0; ky < 3; ky++) {
#pragma unroll
    for (int kx = 0; kx < 3; kx++) {
      int tap = ky * 3 + kx;
      short8 wv = ld8(wdwT + tap * 256 + c0);
      int yy = y + ky - 1, xx = x + kx - 1;
      if (yy >= 0 && yy < 64 && xx >= 0 && xx < 64) {
        short8 vv = ld8(h1T + ((size_t)(b * NHW + yy * 64 + xx)) * 256 + c0);
#pragma unroll
        for (int j = 0; j < 8; j++)
          acc[j] += bu2f((us)vv[j]) * bu2f((us)wv[j]);
      }
    }
  }
  short8 pk;
#pragma unroll
  for (int j = 0; j < 8; j++) pk[j] = (short)f2bu(gelu_ex(acc[j]));
  *(short8*)(h2T + (size_t)pxg * 256 + c0) = pk;
}

// ---------------- 14. mlp2 GEMM act-first (r11 verbatim)
__global__ __launch_bounds__(256) void k_mlp2_g(const us* h2T, const us* wm2, fp bias, const float* ebufT, us* tbufT) {
  int wave = threadIdx.x >> 6, lane = threadIdx.x & 63;
  int quad = lane >> 4, l16 = lane & 15;
  int pxg0 = blockIdx.x * 64 + wave * 16;
  floatx4 acc[4];
#pragma unroll
  for (int m = 0; m < 4; m++) acc[m] = (floatx4){0.f, 0.f, 0.f, 0.f};
  const us* hrow = h2T + (size_t)(pxg0 + l16) * 256 + quad * 8;
#pragma unroll
  for (int k0 = 0; k0 < 256; k0 += 32) {
    short8 act = ld8(hrow + k0);
#pragma unroll
    for (int m = 0; m < 4; m++) {
      short8 wf = ld8(wm2 + (size_t)(m * 16 + l16) * 256 + k0 + quad * 8);
      acc[m] = __builtin_amdgcn_mfma_f32_16x16x32_bf16(act, wf, acc[m], 0, 0, 0);
    }
  }
#pragma unroll
  for (int m = 0; m < 4; m++)
#pragma unroll
    for (int r = 0; r < 4; r++) {
      int px = pxg0 + quad * 4 + r;
      int oc = m * 16 + l16;
      size_t oidx = (size_t)px * 64 + oc;
      tbufT[oidx] = f2bu(acc[m][r] + bias[oc] + ebufT[oidx]);
    }
}

// ---------------- 15. up GEMM W-first (r11 verbatim)
__global__ __launch_bounds__(256) void k_up_g(const us* tbufT, const us* wu, fp bias, float* out) {
  int wave = threadIdx.x >> 6, lane = threadIdx.x & 63;
  int quad = lane >> 4, l16 = lane & 15;
  int pxg0 = blockIdx.x * 64 + wave * 16;
  int b = pxg0 >> 12, hw0 = pxg0 & 4095;
  floatx4 acc[16];
#pragma unroll
  for (int m = 0; m < 16; m++) acc[m] = (floatx4){0.f, 0.f, 0.f, 0.f};
  const us* trow = tbufT + (size_t)(pxg0 + l16) * 64 + quad * 8;
#pragma unroll
  for (int k0 = 0; k0 < 64; k0 += 32) {
    short8 bf = ld8(trow + k0);
#pragma unroll
    for (int m = 0; m < 16; m++) {
      short8 af = ld8(wu + (size_t)(m * 16 + l16) * 64 + k0 + quad * 8);
      acc[m] = __builtin_amdgcn_mfma_f32_16x16x32_bf16(af, bf, acc[m], 0, 0, 0);
    }
  }
#pragma unroll
  for (int m = 0; m < 16; m++)
#pragma unroll
    for (int r = 0; r < 4; r++) {
      int oc = m * 16 + quad * 4 + r;
      out[(size_t)(b * 256 + oc) * NHW + hw0 + l16] = acc[m][r] + bias[oc];
    }
}

extern "C" void kernel_launch(void* const* d_in, const int* in_sizes, int n_in,
                              void* d_out, int out_size, void* d_ws, size_t ws_size,
                              hipStream_t stream) {
  fp x = (fp)d_in[0], skip = (fp)d_in[1], qkv_w = (fp)d_in[2], qkv_b = (fp)d_in[3],
     proj_w = (fp)d_in[4], proj_b = (fp)d_in[5], edge_w = (fp)d_in[6], thick_w = (fp)d_in[7],
     thick_b = (fp)d_in[8], off_w = (fp)d_in[9], off_b = (fp)d_in[10], deform_w = (fp)d_in[11],
     deform_b = (fp)d_in[12], ln_g = (fp)d_in[13], ln_b = (fp)d_in[14], mlp1_w = (fp)d_in[15],
     mlp1_b = (fp)d_in[16], dw_w = (fp)d_in[17], dw_b = (fp)d_in[18], mlp2_w = (fp)d_in[19],
     mlp2_b = (fp)d_in[20], down_w = (fp)d_in[21], down_b = (fp)d_in[22], up_w = (fp)d_in[23],
     up_b = (fp)d_in[24];

  float* ws = (float*)d_ws;
  // ---- layout; wc 99,136 shorts; ml 2*8*NBN f32; Opart x8 in dead mid region ----
  float* su    = ws + 0;              // f32 [0, 1048576)
  us* qkvb  = (us*)(ws + 1048576);    // bf16 [1048576, 1835008)
  us* avb   = (us*)(ws + 1835008);    // bf16 524,288 elems [1835008, 2097152)
  us* wc    = (us*)(ws + 2097152);    // bf16 99,136 elems  [2097152, 2146720)
  float* ml = ws + 2146720;           // f32 2*8*NBN = 262,144  [2146720, 2408864)
  us* kpx   = (us*)(ws + 2408864);    // bf16 K px-major [b*N][32]: 524,288 elems [2408864, 2671008)
  us* x2T   = (us*)(ws + 3145728);    // bf16 px-major [b*N][256]: [3145728, 5242880)
  us* edgeT = (us*)(ws + 5242880);    // bf16 px-major [b*N][64]: 524,288 slots of 1M region
  float* offb  = ws + 6291456;        // f32 [6291456, 6586368)
  float* sm    = ws + 6586368;        // f32 (dead after k_edge_px)
  float* thick = ws + 6602752;        // f32 (dead after k_off_g)
  us* dbufT = (us*)(ws + 6619136);    // bf16 px-major [b*N][64]: [6619136, 7143424)
  float* ebufT = ws + 7143424;        // f32 px-major [b*N][64]: [7143424, 8192000)
  // aliases of dead/late regions:
  us* xT   = x2T;                     // xT live #3..#7; proj_g updates in-place
  us* wq   = dbufT;                   // wq live #0..#4; dead before attn overwrites region
  us* wbf  = (us*)sm;                 // deform weights, written after k_off_g
  us* Opart = (us*)(ws + 5242880);    // attn bf16 partials x8: 4,194,304 shorts = [5242880, 7340032) f32;
                                      // region (edgeT/offb/sm/thick/dbufT) written only AFTER k_merge
  us* hnT  = qkvb;                    // qkvb dead after k_attn
  us* h1T  = x2T;                     // x2T dead after k_down_g
  us* h2T  = (us*)ws;                 // [0, 2097152) slots all dead by k_dw
  us* tbufT = edgeT;                  // edgeT dead after k_deform

  dim3 blk(256);
  k_wq<<<96, blk, 0, stream>>>(qkv_w, wq);
  k_wcast<<<388, blk, 0, stream>>>(proj_w, mlp1_w, down_w, mlp2_w, up_w, dw_w, edge_w, off_w, wc);
  k_upsample<<<(NB * 64 * NHW) / 256, blk, 0, stream>>>(skip, su);
  k_xpose<<<1024, blk, 0, stream>>>(x, xT);
  k_qkv_g<<<(NB * NHW) / 64, blk, 0, stream>>>(xT, wq, qkv_b, qkvb, kpx);
  k_attn<<<(NB * NHW / 64) * KSPLIT, blk, 0, stream>>>(qkvb, kpx, Opart, ml);
  k_merge<<<(NB * NHW * 32) / 256, blk, 0, stream>>>(Opart, ml, avb);
  k_proj_g<<<(NB * NHW) / 64, blk, 0, stream>>>(avb, xT, wc, proj_b, x2T);
  k_meanthick<<<(NB * NHW) / 256, blk, 0, stream>>>(su, thick_w, thick_b, sm, thick);
  k_edge_px<<<(NB * NHW * 8) / 256, blk, 0, stream>>>(sm, wc + 80128, edgeT);
  k_off_g<<<(NB * NHW) / 64, blk, 0, stream>>>(edgeT, wc + 80704, off_b, thick, offb);
  k_wprep<<<144, blk, 0, stream>>>(deform_w, wbf);
  k_deform<<<NB * 64, blk, 0, stream>>>(su, offb, wbf, deform_b, edgeT, dbufT);
  k_down_g<<<(NB * NHW) / 64, blk, 0, stream>>>(x2T, dbufT, wc + 24576, down_b, ebufT);
  k_ln<<<(NB * NHW) / 256, blk, 0, stream>>>(ebufT, ln_g, ln_b, hnT);
  k_mlp1_g<<<(NB * NHW) / 64, blk, 0, stream>>>(hnT, wc + 8192, mlp1_b, h1T);
  k_dw<<<(NB * NHW * 32) / 256, blk, 0, stream>>>(h1T, wc + 77824, dw_b, h2T);
  k_mlp2_g<<<(NB * NHW) / 64, blk, 0, stream>>>(h2T, wc + 45056, mlp2_b, ebufT, tbufT);
  k_up_g<<<(NB * NHW) / 64, blk, 0, stream>>>(tbufT, wc + 61440, up_b, (float*)d_out);
}

// Round 6
// 301.402 us; speedup vs baseline: 1.2263x; 1.0850x over previous
//
#include <hip/hip_runtime.h>
#include <hip/hip_bf16.h>
#include <math.h>

#define NB 4
#define NHW 4096
#define NBN (NB * NHW)
#define KSPLIT 4

typedef const float* fp;
typedef unsigned short us;
typedef __attribute__((ext_vector_type(8))) short short8;
typedef __attribute__((ext_vector_type(4))) short short4v;
typedef __attribute__((ext_vector_type(4))) float floatx4;
typedef __attribute__((ext_vector_type(2))) unsigned int uint2v;
typedef __attribute__((ext_vector_type(4))) unsigned int uint4v;

__device__ __forceinline__ float b2f(__hip_bfloat16 v) { return __bfloat162float(v); }
__device__ __forceinline__ __hip_bfloat16 f2b(float v) { return __float2bfloat16(v); }
__device__ __forceinline__ us f2bu(float f) {
  __hip_bfloat16 h = __float2bfloat16(f);
  return *reinterpret_cast<us*>(&h);
}
__device__ __forceinline__ float bu2f(us u) {
  __hip_bfloat16 h = *reinterpret_cast<__hip_bfloat16*>(&u);
  return __bfloat162float(h);
}
__device__ __forceinline__ float gelu_ex(float x) { return 0.5f * x * (1.0f + erff(x * 0.70710678118654752f)); }
__device__ __forceinline__ short8 ld8(const us* p) { return *(const short8*)p; }

// packed f32x2 -> bf16x2 (RNE), single instruction (T12; no builtin on gfx950)
__device__ __forceinline__ unsigned cvt_pk_bf16(float lo, float hi) {
  unsigned r;
  asm("v_cvt_pk_bf16_f32 %0, %1, %2" : "=v"(r) : "v"(lo), "v"(hi));
  return r;
}
// cross-quad reductions via permlane swaps (VALU-speed, no LDS/bpermute latency)
__device__ __forceinline__ float qmax4(float v) {
  uint2v p = __builtin_amdgcn_permlane16_swap(__float_as_uint(v), __float_as_uint(v), false, false);
  v = fmaxf(__uint_as_float(p.x), __uint_as_float(p.y));
  p = __builtin_amdgcn_permlane32_swap(__float_as_uint(v), __float_as_uint(v), false, false);
  return fmaxf(__uint_as_float(p.x), __uint_as_float(p.y));
}
__device__ __forceinline__ float qsum4(float v) {
  uint2v p = __builtin_amdgcn_permlane16_swap(__float_as_uint(v), __float_as_uint(v), false, false);
  v = __uint_as_float(p.x) + __uint_as_float(p.y);
  p = __builtin_amdgcn_permlane32_swap(__float_as_uint(v), __float_as_uint(v), false, false);
  return __uint_as_float(p.x) + __uint_as_float(p.y);
}

// ---------------- 0a. cast qkv weights f32 [96][256] -> bf16
__global__ __launch_bounds__(256) void k_wq(fp qw, us* wq) {
  int i = blockIdx.x * 256 + threadIdx.x;
  if (i >= 96 * 256) return;
  wq[i] = f2bu(qw[i]);
}

// ---------------- 0b. cast weights -> bf16 (offsets in shorts)
// proj @0, mlp1 @8192, down @24576, mlp2 @45056, up @61440, dwT[tap][ch] @77824,
// ewT[tap][oc] @80128, woff[32 pad][9*64] @80704; total 99136
__global__ __launch_bounds__(256) void k_wcast(fp pw, fp m1w, fp dnw, fp m2w, fp uw, fp dww,
                                               fp ew, fp ow, us* wc) {
  int i = blockIdx.x * 256 + threadIdx.x;
  if (i >= 99136) return;
  float v;
  if (i < 8192) v = pw[i];
  else if (i < 24576) v = m1w[i - 8192];
  else if (i < 45056) v = dnw[i - 24576];
  else if (i < 61440) v = m2w[i - 45056];
  else if (i < 77824) v = uw[i - 61440];
  else if (i < 80128) {
    int i2 = i - 77824;           // dwT: tap = i2>>8, ch = i2&255
    v = dww[(i2 & 255) * 9 + (i2 >> 8)];
  } else if (i < 80704) {
    int i2 = i - 80128;           // ewT: tap = i2>>6, oc = i2&63
    v = ew[(i2 & 63) * 9 + (i2 >> 6)];
  } else {
    int i2 = i - 80704;           // woff[oc][tap*64+c], oc padded to 32
    int oc = i2 / 576, rem = i2 % 576;
    int tap = rem >> 6, c = rem & 63;
    v = (oc < 18) ? ow[(oc * 64 + c) * 9 + tap] : 0.f;
  }
  wc[i] = f2bu(v);
}

// ---------------- 0c. deform weights: dw[oc][c][tap] -> wbf[tap][oc][c] bf16 (r8 verbatim)
__global__ __launch_bounds__(256) void k_wprep(fp dw, us* wbf) {
  int idx = blockIdx.x * 256 + threadIdx.x;
  if (idx >= 9 * 64 * 64) return;
  int c = idx & 63, oc = (idx >> 6) & 63, k = idx >> 12;
  wbf[idx] = f2bu(dw[(oc * 64 + c) * 9 + k]);
}

// ---------------- 1. bilinear upsample -> su f32 (r8 verbatim)
__global__ __launch_bounds__(256) void k_upsample(fp skip, float* su) {
  int idx = blockIdx.x * 256 + threadIdx.x;
  if (idx >= NB * 64 * NHW) return;
  int hw = idx & 4095, bc = idx >> 12;
  int y = hw >> 6, x = hw & 63;
  float fy = 0.5f * y - 0.25f, fx = 0.5f * x - 0.25f;
  float y0f = floorf(fy), x0f = floorf(fx);
  float wy = fy - y0f, wx = fx - x0f;
  int y0 = (int)y0f, x0 = (int)x0f;
  int y0c = min(31, max(0, y0)), y1c = min(31, max(0, y0 + 1));
  int x0c = min(31, max(0, x0)), x1c = min(31, max(0, x0 + 1));
  const float* p = skip + (size_t)bc * 1024;
  float v00 = p[y0c * 32 + x0c], v01 = p[y0c * 32 + x1c];
  float v10 = p[y1c * 32 + x0c], v11 = p[y1c * 32 + x1c];
  su[idx] = (1.f - wy) * ((1.f - wx) * v00 + wx * v01) + wy * ((1.f - wx) * v10 + wx * v11);
}

// ---------------- 2. transpose x f32 -> xT bf16 [b*4096][256] (r8 verbatim)
__global__ __launch_bounds__(256) void k_xpose(fp x, us* xT) {
  __shared__ float tile[64][65];
  int bid = blockIdx.x;
  int pt = bid & 63, ct = (bid >> 6) & 3, b = bid >> 8;
  int px0 = pt * 64, c0 = ct * 64;
  int tx = threadIdx.x & 63, ty = threadIdx.x >> 6;
  const float* src = x + ((size_t)(b * 256 + c0)) * NHW + px0;
#pragma unroll
  for (int i = 0; i < 16; i++) {
    int r = i * 4 + ty;
    tile[r][tx] = src[(size_t)r * NHW + tx];
  }
  __syncthreads();
  int cseg = threadIdx.x & 7, p0 = threadIdx.x >> 3;
#pragma unroll
  for (int h = 0; h < 2; h++) {
    int p = p0 + h * 32;
    short8 v;
#pragma unroll
    for (int j = 0; j < 8; j++) v[j] = (short)f2bu(tile[cseg * 8 + j][p]);
    *(short8*)&xT[((size_t)(b * NHW) + px0 + p) * 256 + c0 + cseg * 8] = v;
  }
}

// ---------------- 3. qkv GEMM -> Q ch-major bf16 [b][32][N]; K px-major kpx[b*N][32];
// V blocked vblk[(b*N+key)/32][ch][key%32] (lane-contiguous PV fragments).
// Q scale folds 1/sqrt(32) * log2(e) so attention runs in exp2 domain.
__global__ __launch_bounds__(256) void k_qkv_g(const us* xT, const us* wq, fp bias, us* qkvb, us* kpx, us* vblk) {
  int wave = threadIdx.x >> 6, lane = threadIdx.x & 63;
  int quad = lane >> 4, l16 = lane & 15;
  int pxg0 = blockIdx.x * 64 + wave * 16;
  int b = pxg0 >> 12, hw0 = pxg0 & 4095;
  floatx4 acc[6];
#pragma unroll
  for (int m = 0; m < 6; m++) acc[m] = (floatx4){0.f, 0.f, 0.f, 0.f};
  const us* xrow = xT + (size_t)(pxg0 + l16) * 256 + quad * 8;
#pragma unroll
  for (int k0 = 0; k0 < 256; k0 += 32) {
    short8 bf = ld8(xrow + k0);
#pragma unroll
    for (int m = 0; m < 6; m++) {
      short8 af = ld8(wq + (size_t)(m * 16 + l16) * 256 + k0 + quad * 8);
      acc[m] = __builtin_amdgcn_mfma_f32_16x16x32_bf16(af, bf, acc[m], 0, 0, 0);
    }
  }
#pragma unroll
  for (int m = 0; m < 6; m++) {
    if (m == 2 || m == 3) {
      // K channels -> px-major, 4 consecutive oc per lane -> one b64 store
      short4v pkv;
#pragma unroll
      for (int r = 0; r < 4; r++) {
        int oc = m * 16 + quad * 4 + r;
        pkv[r] = (short)f2bu(acc[m][r] + bias[oc]);
      }
      *(short4v*)&kpx[((size_t)(b * NHW) + hw0 + l16) * 32 + (m - 2) * 16 + quad * 4] = pkv;
    } else if (m >= 4) {
      // V -> blocked [key/32][ch][key%32]
      int key = hw0 + l16;
      size_t base = ((size_t)(b * NHW + key) >> 5) * 1024 + (size_t)(key & 31);
#pragma unroll
      for (int r = 0; r < 4; r++) {
        int ch = (m - 4) * 16 + quad * 4 + r;
        vblk[base + (size_t)ch * 32] = f2bu(acc[m][r] + bias[64 + ch]);
      }
    } else {
#pragma unroll
      for (int r = 0; r < 4; r++) {
        int oc = m * 16 + quad * 4 + r;
        float v = (acc[m][r] + bias[oc]) * 0.25503485f;   // (1/sqrt(32)) * log2(e)
        qkvb[(size_t)(b * 32 + oc) * NHW + hw0 + l16] = f2bu(v);
      }
    }
  }
}

// ---------------- 4. LDS-free flash attention, SPLIT-K x4, swapped QK^T.
// Each lane owns one query (q = l16). S^T = mfma(K_px, Q); softmax reduce =
// max3-fused in-lane tree + permlane swaps; P packed via v_cvt_pk_bf16_f32;
// P^T in-register via permlane32/16_swap; O^T = mfma(V_blk, P^T).
// K prefetched across tiles (r2-proven); V fragments lane-contiguous via vblk.
__global__ __launch_bounds__(256, 4) void k_attn(const us* qkvb, const us* kpx, const us* vblk,
                                                 us* Opart, float* ml) {
  int tid = threadIdx.x;
  int wave = tid >> 6, lane = tid & 63;
  int quad = lane >> 4, l16 = lane & 15;
  int blk = blockIdx.x;
  int kh = blk & 3;
  int rest = blk >> 2;
  int b = rest >> 6;
  int qbase = (rest & 63) * 64 + wave * 16;
  const us* qp = qkvb + (size_t)b * 32 * NHW;
  const us* kb_base = kpx + (size_t)b * NHW * 32;

  // Q fragment as B-operand: B[col=q=l16][k=ch=quad*8+j]
  short8 bq;
#pragma unroll
  for (int j = 0; j < 8; j++)
    bq[j] = (short)qp[(size_t)(quad * 8 + j) * NHW + qbase + l16];

  float m_r = -1e30f, l_r = 0.f;
  floatx4 o0 = {0.f, 0.f, 0.f, 0.f}, o1 = {0.f, 0.f, 0.f, 0.f};

  int kb0 = kh * 1024;
  // prefetch first K tile: A[row=key=l16][k=ch]
  short8 akf[8];
#pragma unroll
  for (int t = 0; t < 8; t++)
    akf[t] = ld8(kb_base + (size_t)(kb0 + t * 16 + l16) * 32 + quad * 8);

  for (int kb = kb0; kb < kb0 + 1024; kb += 128) {
    // S^T: sT[t][r] = S[key = kb + t*16 + quad*4 + r][q = l16]
    floatx4 sT[8];
    __builtin_amdgcn_s_setprio(1);
#pragma unroll
    for (int t = 0; t < 8; t++) {
      floatx4 z = {0.f, 0.f, 0.f, 0.f};
      sT[t] = __builtin_amdgcn_mfma_f32_16x16x32_bf16(akf[t], bq, z, 0, 0, 0);
    }
    __builtin_amdgcn_s_setprio(0);

    // prefetch next K tile under the softmax VALU work
    int kbn = (kb + 128 < kb0 + 1024) ? kb + 128 : kb0;
#pragma unroll
    for (int t = 0; t < 8; t++)
      akf[t] = ld8(kb_base + (size_t)(kbn + t * 16 + l16) * 32 + quad * 8);

    // running max: chained in-lane tree (fuses to v_max3) + 2 permlane swaps
    float tm[8];
#pragma unroll
    for (int t = 0; t < 8; t++)
      tm[t] = fmaxf(fmaxf(fmaxf(sT[t][0], sT[t][1]), sT[t][2]), sT[t][3]);
    float mx = fmaxf(fmaxf(fmaxf(tm[0], tm[1]), tm[2]), tm[3]);
    mx = fmaxf(fmaxf(fmaxf(fmaxf(mx, tm[4]), tm[5]), tm[6]), tm[7]);
    mx = qmax4(mx);
    float mnew = fmaxf(m_r, mx);
    float alpha = exp2f(m_r - mnew);
    m_r = mnew;

    // P = 2^(s - m), packed to bf16 pairs via v_cvt_pk_bf16_f32
    float rs0 = 0.f, rs1 = 0.f;
    unsigned pkw[8][2];
#pragma unroll
    for (int t = 0; t < 8; t++) {
      float p0 = exp2f(sT[t][0] - mnew);
      float p1 = exp2f(sT[t][1] - mnew);
      float p2 = exp2f(sT[t][2] - mnew);
      float p3 = exp2f(sT[t][3] - mnew);
      rs0 += p0 + p1;
      rs1 += p2 + p3;
      pkw[t][0] = cvt_pk_bf16(p0, p1);
      pkw[t][1] = cvt_pk_bf16(p2, p3);
    }
    float rs = qsum4(rs0 + rs1);
    l_r = l_r * alpha + rs;
#pragma unroll
    for (int r = 0; r < 4; r++) { o0[r] *= alpha; o1[r] *= alpha; }

    // PV: O^T += V * P^T. V fragments from vblk: base + ch*32 + keyoff, lane-contiguous 1KB.
    __builtin_amdgcn_s_setprio(1);
#pragma unroll
    for (int cc = 0; cc < 4; cc++) {
      uint2v t1 = __builtin_amdgcn_permlane32_swap(pkw[2 * cc][0], pkw[2 * cc + 1][0], false, false);
      uint2v t2 = __builtin_amdgcn_permlane16_swap(t1.x, t1.y, false, false);
      uint2v t3 = __builtin_amdgcn_permlane32_swap(pkw[2 * cc][1], pkw[2 * cc + 1][1], false, false);
      uint2v t4 = __builtin_amdgcn_permlane16_swap(t3.x, t3.y, false, false);
      uint4v pw = {t2.x, t4.x, t2.y, t4.y};
      short8 pa = *(short8*)&pw;
      const us* vb = vblk + ((size_t)(b * NHW + kb + cc * 32) >> 5) * 1024 + quad * 8;
      short8 av0 = ld8(vb + (size_t)l16 * 32);
      short8 av1 = ld8(vb + (size_t)(l16 + 16) * 32);
      o0 = __builtin_amdgcn_mfma_f32_16x16x32_bf16(av0, pa, o0, 0, 0, 0);
      o1 = __builtin_amdgcn_mfma_f32_16x16x32_bf16(av1, pa, o1, 0, 0, 0);
    }
    __builtin_amdgcn_s_setprio(0);
  }

  // epilogue: lane owns q = qbase + l16, channels quad*4+r (o0) and 16+quad*4+r (o1)
  int q = qbase + l16;
  size_t qg = (size_t)b * NHW + q;
  us* dst = Opart + ((size_t)kh * NBN + qg) * 32;
  short4v e0, e1;
#pragma unroll
  for (int r = 0; r < 4; r++) { e0[r] = (short)f2bu(o0[r]); e1[r] = (short)f2bu(o1[r]); }
  *(short4v*)(dst + quad * 4) = e0;
  *(short4v*)(dst + 16 + quad * 4) = e1;
  if (quad == 0) {
    ml[(size_t)kh * NBN + qg] = m_r;
    ml[(size_t)KSPLIT * NBN + (size_t)kh * NBN + qg] = l_r;
  }
}

// ---------------- 4b. merge 4 split-K partials -> avb px-major bf16 (exp2 domain)
__global__ __launch_bounds__(256) void k_merge(const us* Opart, const float* ml, us* avb) {
  int idx = blockIdx.x * 256 + threadIdx.x;
  int ch = idx & 31, qg = idx >> 5;
  float mk[KSPLIT];
  float m = -1e30f;
#pragma unroll
  for (int kh = 0; kh < KSPLIT; kh++) { mk[kh] = ml[kh * NBN + qg]; m = fmaxf(m, mk[kh]); }
  float l = 0.f, v = 0.f;
#pragma unroll
  for (int kh = 0; kh < KSPLIT; kh++) {
    float a = exp2f(mk[kh] - m);
    l += ml[KSPLIT * NBN + kh * NBN + qg] * a;
    v += bu2f(Opart[((size_t)(kh * NBN) + qg) * 32 + ch]) * a;
  }
  avb[idx] = f2bu(v / l);
}

// ---------------- 5. proj GEMM act-first (r10 verbatim)
__global__ __launch_bounds__(256) void k_proj_g(const us* avb, const us* xT, const us* wpj, fp bias, us* x2T) {
  int wave = threadIdx.x >> 6, lane = threadIdx.x & 63;
  int quad = lane >> 4, l16 = lane & 15;
  int pxg0 = blockIdx.x * 64 + wave * 16;
  short8 act = ld8(avb + (size_t)(pxg0 + l16) * 32 + quad * 8);
  floatx4 acc[16];
#pragma unroll
  for (int n = 0; n < 16; n++) {
    short8 wf = ld8(wpj + (size_t)(n * 16 + l16) * 32 + quad * 8);
    floatx4 z = {0.f, 0.f, 0.f, 0.f};
    acc[n] = __builtin_amdgcn_mfma_f32_16x16x32_bf16(act, wf, z, 0, 0, 0);
  }
#pragma unroll
  for (int n = 0; n < 16; n++)
#pragma unroll
    for (int r = 0; r < 4; r++) {
      int px = pxg0 + quad * 4 + r;
      int oc = n * 16 + l16;
      size_t oidx = (size_t)px * 256 + oc;
      x2T[oidx] = f2bu(acc[n][r] + bias[oc] + bu2f(xT[oidx]));
    }
}

// ---------------- 6. channel mean + thick (r8 verbatim)
__global__ __launch_bounds__(256) void k_meanthick(const float* su, fp tw, fp tb, float* sm, float* thick) {
  int idx = blockIdx.x * 256 + threadIdx.x;
  if (idx >= NB * NHW) return;
  int hw = idx & 4095, b = idx >> 12;
  const float* p = su + (size_t)b * 64 * NHW + hw;
  float s = 0.f, ts = 0.f;
#pragma unroll 8
  for (int c = 0; c < 64; c++) {
    float v = p[(size_t)c * NHW];
    s += v;
    ts += v * tw[c];
  }
  sm[idx] = s * (1.f / 64.f);
  float z = ts + tb[0];
  thick[idx] = 1.f / (1.f + __expf(-z));
}

// ---------------- 7. edge conv 3x3 px-major: thread=(px, 8-oc block) -> edgeT bf16 [b*N][64]
__global__ __launch_bounds__(256) void k_edge_px(const float* sm, const us* ewT, us* edgeT) {
  int idx = blockIdx.x * 256 + threadIdx.x;   // NB*NHW*8
  int cb = idx & 7, pxg = idx >> 3;
  int b = pxg >> 12, hw = pxg & 4095;
  int y = hw >> 6, x = hw & 63;
  int c0 = cb * 8;
  float acc[8] = {0.f, 0.f, 0.f, 0.f, 0.f, 0.f, 0.f, 0.f};
#pragma unroll
  for (int ky = 0; ky < 3; ky++) {
#pragma unroll
    for (int kx = 0; kx < 3; kx++) {
      int yy = y + ky - 1, xx = x + kx - 1;
      if (yy >= 0 && yy < 64 && xx >= 0 && xx < 64) {
        float sv = sm[b * NHW + yy * 64 + xx];
        short8 wv = ld8(ewT + (ky * 3 + kx) * 64 + c0);
#pragma unroll
        for (int j = 0; j < 8; j++) acc[j] += sv * bu2f((us)wv[j]);
      }
    }
  }
  short8 pk;
#pragma unroll
  for (int j = 0; j < 8; j++) pk[j] = (short)f2bu(acc[j]);
  *(short8*)(edgeT + (size_t)pxg * 64 + c0) = pk;
}

// ---------------- 8. offset conv as MFMA GEMM: K=9x64, N=32(18 used), act=shifted edgeT rows
__global__ __launch_bounds__(256) void k_off_g(const us* edgeT, const us* woff, fp ob,
                                               const float* thick, float* offb) {
  int wave = threadIdx.x >> 6, lane = threadIdx.x & 63;
  int quad = lane >> 4, l16 = lane & 15;
  int pxg0 = blockIdx.x * 64 + wave * 16;
  int b = pxg0 >> 12;
  int pxl = pxg0 + l16;
  int hwl = pxl & 4095;
  int yl = hwl >> 6, xl = hwl & 63;
  floatx4 acc[2];
  acc[0] = (floatx4){0.f, 0.f, 0.f, 0.f};
  acc[1] = (floatx4){0.f, 0.f, 0.f, 0.f};
  const short8 zz = {0, 0, 0, 0, 0, 0, 0, 0};
#pragma unroll
  for (int t = 0; t < 9; t++) {
    int yy = yl + t / 3 - 1, xx = xl + t % 3 - 1;
    bool valid = (yy >= 0 && yy < 64 && xx >= 0 && xx < 64);
    const us* arow = edgeT + ((size_t)(b * NHW + yy * 64 + xx)) * 64;
#pragma unroll
    for (int s = 0; s < 2; s++) {
      short8 act = valid ? ld8(arow + s * 32 + quad * 8) : zz;   // k_dw-style conditional row load
      int kk = t * 64 + s * 32 + quad * 8;
#pragma unroll
      for (int n = 0; n < 2; n++) {
        short8 wf = ld8(woff + (size_t)(n * 16 + l16) * 576 + kk);
        acc[n] = __builtin_amdgcn_mfma_f32_16x16x32_bf16(act, wf, acc[n], 0, 0, 0);
      }
    }
  }
#pragma unroll
  for (int n = 0; n < 2; n++)
#pragma unroll
    for (int r = 0; r < 4; r++) {
      int oc = n * 16 + l16;
      if (oc < 18) {
        int px = pxg0 + quad * 4 + r;
        int hw = px & 4095;
        float v = (acc[n][r] + ob[oc]) * (1.f + 16.f * thick[px]);
        offb[(size_t)(b * 18 + oc) * NHW + hw] = v;
      }
    }
}

// ---------------- 9. MFMA deformable conv (r10 structure; edge residual from edgeT rows)
__global__ __launch_bounds__(256) void k_deform(const float* su, const float* offb,
                                                const us* wbf, fp db,
                                                const us* edgeT, us* dbufT) {
  __shared__ __align__(16) us samT[4][16][72];
  int tid = threadIdx.x;
  int wave = tid >> 6, lane = tid & 63;
  int quad = lane >> 4, l16 = lane & 15;
  int b = blockIdx.x >> 6, row = blockIdx.x & 63;
  const float* sub = su + (size_t)b * 64 * NHW;

  int sp = lane & 15, sq = lane >> 4;
  int hw_s = row * 64 + wave * 16 + sp;
  int x_s = wave * 16 + sp;

  floatx4 acc[4];
#pragma unroll
  for (int a = 0; a < 4; a++) acc[a] = (floatx4){0.f, 0.f, 0.f, 0.f};

  for (int k = 0; k < 9; k++) {
    float dy = offb[((size_t)(b * 18 + 2 * k)) * NHW + hw_s];
    float dx = offb[((size_t)(b * 18 + 2 * k + 1)) * NHW + hw_s];
    float py = (float)(row + k / 3 - 1) + dy;
    float pxf = (float)(x_s + k % 3 - 1) + dx;
    float y0f = floorf(py), x0f = floorf(pxf);
    float wy = py - y0f, wx = pxf - x0f;
    int y0 = (int)y0f, x0 = (int)x0f;
    int y1 = y0 + 1, x1 = x0 + 1;
    float vy0 = (y0 >= 0 && y0 < 64) ? 1.f : 0.f;
    float vy1 = (y1 >= 0 && y1 < 64) ? 1.f : 0.f;
    float vx0 = (x0 >= 0 && x0 < 64) ? 1.f : 0.f;
    float vx1 = (x1 >= 0 && x1 < 64) ? 1.f : 0.f;
    float w00 = (1.f - wy) * (1.f - wx) * vy0 * vx0;
    float w01 = (1.f - wy) * wx * vy0 * vx1;
    float w10 = wy * (1.f - wx) * vy1 * vx0;
    float w11 = wy * wx * vy1 * vx1;
    int y0c = min(63, max(0, y0)), y1c = min(63, max(0, y1));
    int x0c = min(63, max(0, x0)), x1c = min(63, max(0, x1));
    int i00 = y0c * 64 + x0c, i01 = y0c * 64 + x1c;
    int i10 = y1c * 64 + x0c, i11 = y1c * 64 + x1c;

#pragma unroll
    for (int i = 0; i < 16; i += 2) {
      int c0 = sq * 16 + i;
      const float* s0 = sub + (size_t)c0 * NHW;
      const float* s1 = s0 + NHW;
      float v0 = w00 * s0[i00] + w01 * s0[i01] + w10 * s0[i10] + w11 * s0[i11];
      float v1 = w00 * s1[i00] + w01 * s1[i01] + w10 * s1[i10] + w11 * s1[i11];
      unsigned int pk = (unsigned int)f2bu(v0) | ((unsigned int)f2bu(v1) << 16);
      *(unsigned int*)&samT[wave][sp][c0] = pk;
    }

#pragma unroll
    for (int s = 0; s < 2; s++) {
      short8 bfrag = *(const short8*)&samT[wave][l16][s * 32 + quad * 8];
#pragma unroll
      for (int a = 0; a < 4; a++) {
        short8 afrag = ld8(wbf + ((size_t)(k * 64 + a * 16 + l16) * 64 + s * 32 + quad * 8));
        acc[a] = __builtin_amdgcn_mfma_f32_16x16x32_bf16(bfrag, afrag, acc[a], 0, 0, 0);
      }
    }
  }

#pragma unroll
  for (int a = 0; a < 4; a++)
#pragma unroll
    for (int r = 0; r < 4; r++) {
      int oc = a * 16 + l16;
      int pxr = row * 64 + wave * 16 + quad * 4 + r;
      size_t rowi = (size_t)(b * NHW) + pxr;
      float v = acc[a][r] + db[oc] + bu2f(edgeT[rowi * 64 + oc]);
      dbufT[rowi * 64 + oc] = f2bu(v);
    }
}

// ---------------- 10. down GEMM act-first -> ebufT px-major f32 (r11 verbatim)
__global__ __launch_bounds__(256) void k_down_g(const us* x2T, const us* dbufT, const us* wd, fp bias, float* ebufT) {
  int wave = threadIdx.x >> 6, lane = threadIdx.x & 63;
  int quad = lane >> 4, l16 = lane & 15;
  int pxg0 = blockIdx.x * 64 + wave * 16;
  floatx4 acc[4];
#pragma unroll
  for (int m = 0; m < 4; m++) acc[m] = (floatx4){0.f, 0.f, 0.f, 0.f};
  const us* xrow = x2T + (size_t)(pxg0 + l16) * 256 + quad * 8;
#pragma unroll
  for (int k0 = 0; k0 < 256; k0 += 32) {
    short8 act = ld8(xrow + k0);
#pragma unroll
    for (int m = 0; m < 4; m++) {
      short8 wf = ld8(wd + (size_t)(m * 16 + l16) * 320 + k0 + quad * 8);
      acc[m] = __builtin_amdgcn_mfma_f32_16x16x32_bf16(act, wf, acc[m], 0, 0, 0);
    }
  }
  const us* drow = dbufT + (size_t)(pxg0 + l16) * 64 + quad * 8;
#pragma unroll
  for (int k0 = 0; k0 < 64; k0 += 32) {
    short8 act = ld8(drow + k0);
#pragma unroll
    for (int m = 0; m < 4; m++) {
      short8 wf = ld8(wd + (size_t)(m * 16 + l16) * 320 + 256 + k0 + quad * 8);
      acc[m] = __builtin_amdgcn_mfma_f32_16x16x32_bf16(act, wf, acc[m], 0, 0, 0);
    }
  }
#pragma unroll
  for (int m = 0; m < 4; m++)
#pragma unroll
    for (int r = 0; r < 4; r++) {
      int px = pxg0 + quad * 4 + r;
      int oc = m * 16 + l16;
      ebufT[(size_t)px * 64 + oc] = acc[m][r] + bias[oc];
    }
}

// ---------------- 11. LayerNorm px-major (r11 verbatim)
__global__ __launch_bounds__(256) void k_ln(const float* eT, fp g, fp bt, us* hnT) {
  int idx = blockIdx.x * 256 + threadIdx.x;
  if (idx >= NB * NHW) return;
  const float* p = eT + (size_t)idx * 64;
  float v[64];
  float s = 0.f;
#pragma unroll
  for (int i = 0; i < 16; i++) {
    float4 t = ((const float4*)p)[i];
    v[i * 4] = t.x; v[i * 4 + 1] = t.y; v[i * 4 + 2] = t.z; v[i * 4 + 3] = t.w;
    s += t.x + t.y + t.z + t.w;
  }
  float mu = s * (1.f / 64.f);
  float q = 0.f;
#pragma unroll
  for (int c = 0; c < 64; c++) { float d = v[c] - mu; q += d * d; }
  float rstd = rsqrtf(q * (1.f / 64.f) + 1e-5f);
  us* o = hnT + (size_t)idx * 64;
#pragma unroll
  for (int j = 0; j < 8; j++) {
    short8 pk;
#pragma unroll
    for (int t = 0; t < 8; t++) {
      int c = j * 8 + t;
      pk[t] = (short)f2bu((v[c] - mu) * rstd * g[c] + bt[c]);
    }
    *(short8*)(o + j * 8) = pk;
  }
}

// ---------------- 12. mlp1 GEMM act-first (r11 verbatim)
__global__ __launch_bounds__(256) void k_mlp1_g(const us* hnT, const us* wm1, fp bias, us* h1T) {
  int wave = threadIdx.x >> 6, lane = threadIdx.x & 63;
  int quad = lane >> 4, l16 = lane & 15;
  int pxg0 = blockIdx.x * 64 + wave * 16;
  floatx4 acc[16];
#pragma unroll
  for (int m = 0; m < 16; m++) acc[m] = (floatx4){0.f, 0.f, 0.f, 0.f};
  const us* hrow = hnT + (size_t)(pxg0 + l16) * 64 + quad * 8;
#pragma unroll
  for (int k0 = 0; k0 < 64; k0 += 32) {
    short8 act = ld8(hrow + k0);
#pragma unroll
    for (int m = 0; m < 16; m++) {
      short8 wf = ld8(wm1 + (size_t)(m * 16 + l16) * 64 + k0 + quad * 8);
      acc[m] = __builtin_amdgcn_mfma_f32_16x16x32_bf16(act, wf, acc[m], 0, 0, 0);
    }
  }
#pragma unroll
  for (int m = 0; m < 16; m++)
#pragma unroll
    for (int r = 0; r < 4; r++) {
      int px = pxg0 + quad * 4 + r;
      int oc = m * 16 + l16;
      h1T[(size_t)px * 256 + oc] = f2bu(gelu_ex(acc[m][r] + bias[oc]));
    }
}

// ---------------- 13. depthwise 3x3 + GELU, px-major (r12 verbatim)
__global__ __launch_bounds__(256) void k_dw(const us* h1T, const us* wdwT, fp bias, us* h2T) {
  int idx = blockIdx.x * 256 + threadIdx.x;   // NB*NHW*32
  int cb = idx & 31, pxg = idx >> 5;
  int b = pxg >> 12, hw = pxg & 4095;
  int y = hw >> 6, x = hw & 63;
  int c0 = cb * 8;
  float4 b0 = *(const float4*)(bias + c0);
  float4 b1 = *(const float4*)(bias + c0 + 4);
  float acc[8] = {b0.x, b0.y, b0.z, b0.w, b1.x, b1.y, b1.z, b1.w};
#pragma unroll
  for (int ky = 0; ky < 3; ky++) {
#pragma unroll
    for (int kx = 0; kx < 3; kx++) {
      int tap = ky * 3 + kx;
      short8 wv = ld8(wdwT + tap * 256 + c0);
      int yy = y + ky - 1, xx = x + kx - 1;
      if (yy >= 0 && yy < 64 && xx >= 0 && xx < 64) {
        short8 vv = ld8(h1T + ((size_t)(b * NHW + yy * 64 + xx)) * 256 + c0);
#pragma unroll
        for (int j = 0; j < 8; j++)
          acc[j] += bu2f((us)vv[j]) * bu2f((us)wv[j]);
      }
    }
  }
  short8 pk;
#pragma unroll
  for (int j = 0; j < 8; j++) pk[j] = (short)f2bu(gelu_ex(acc[j]));
  *(short8*)(h2T + (size_t)pxg * 256 + c0) = pk;
}

// ---------------- 14. mlp2 GEMM act-first (r11 verbatim)
__global__ __launch_bounds__(256) void k_mlp2_g(const us* h2T, const us* wm2, fp bias, const float* ebufT, us* tbufT) {
  int wave = threadIdx.x >> 6, lane = threadIdx.x & 63;
  int quad = lane >> 4, l16 = lane & 15;
  int pxg0 = blockIdx.x * 64 + wave * 16;
  floatx4 acc[4];
#pragma unroll
  for (int m = 0; m < 4; m++) acc[m] = (floatx4){0.f, 0.f, 0.f, 0.f};
  const us* hrow = h2T + (size_t)(pxg0 + l16) * 256 + quad * 8;
#pragma unroll
  for (int k0 = 0; k0 < 256; k0 += 32) {
    short8 act = ld8(hrow + k0);
#pragma unroll
    for (int m = 0; m < 4; m++) {
      short8 wf = ld8(wm2 + (size_t)(m * 16 + l16) * 256 + k0 + quad * 8);
      acc[m] = __builtin_amdgcn_mfma_f32_16x16x32_bf16(act, wf, acc[m], 0, 0, 0);
    }
  }
#pragma unroll
  for (int m = 0; m < 4; m++)
#pragma unroll
    for (int r = 0; r < 4; r++) {
      int px = pxg0 + quad * 4 + r;
      int oc = m * 16 + l16;
      size_t oidx = (size_t)px * 64 + oc;
      tbufT[oidx] = f2bu(acc[m][r] + bias[oc] + ebufT[oidx]);
    }
}

// ---------------- 15. up GEMM W-first (r11 verbatim)
__global__ __launch_bounds__(256) void k_up_g(const us* tbufT, const us* wu, fp bias, float* out) {
  int wave = threadIdx.x >> 6, lane = threadIdx.x & 63;
  int quad = lane >> 4, l16 = lane & 15;
  int pxg0 = blockIdx.x * 64 + wave * 16;
  int b = pxg0 >> 12, hw0 = pxg0 & 4095;
  floatx4 acc[16];
#pragma unroll
  for (int m = 0; m < 16; m++) acc[m] = (floatx4){0.f, 0.f, 0.f, 0.f};
  const us* trow = tbufT + (size_t)(pxg0 + l16) * 64 + quad * 8;
#pragma unroll
  for (int k0 = 0; k0 < 64; k0 += 32) {
    short8 bf = ld8(trow + k0);
#pragma unroll
    for (int m = 0; m < 16; m++) {
      short8 af = ld8(wu + (size_t)(m * 16 + l16) * 64 + k0 + quad * 8);
      acc[m] = __builtin_amdgcn_mfma_f32_16x16x32_bf16(af, bf, acc[m], 0, 0, 0);
    }
  }
#pragma unroll
  for (int m = 0; m < 16; m++)
#pragma unroll
    for (int r = 0; r < 4; r++) {
      int oc = m * 16 + quad * 4 + r;
      out[(size_t)(b * 256 + oc) * NHW + hw0 + l16] = acc[m][r] + bias[oc];
    }
}

extern "C" void kernel_launch(void* const* d_in, const int* in_sizes, int n_in,
                              void* d_out, int out_size, void* d_ws, size_t ws_size,
                              hipStream_t stream) {
  fp x = (fp)d_in[0], skip = (fp)d_in[1], qkv_w = (fp)d_in[2], qkv_b = (fp)d_in[3],
     proj_w = (fp)d_in[4], proj_b = (fp)d_in[5], edge_w = (fp)d_in[6], thick_w = (fp)d_in[7],
     thick_b = (fp)d_in[8], off_w = (fp)d_in[9], off_b = (fp)d_in[10], deform_w = (fp)d_in[11],
     deform_b = (fp)d_in[12], ln_g = (fp)d_in[13], ln_b = (fp)d_in[14], mlp1_w = (fp)d_in[15],
     mlp1_b = (fp)d_in[16], dw_w = (fp)d_in[17], dw_b = (fp)d_in[18], mlp2_w = (fp)d_in[19],
     mlp2_b = (fp)d_in[20], down_w = (fp)d_in[21], down_b = (fp)d_in[22], up_w = (fp)d_in[23],
     up_b = (fp)d_in[24];

  float* ws = (float*)d_ws;
  // ---- layout; wc 99,136 shorts; ml 2*4*NBN f32; kpx + vblk in free gap ----
  float* su    = ws + 0;              // f32 [0, 1048576)
  us* qkvb  = (us*)(ws + 1048576);    // bf16 Q-only [b][32][N] (region sized for more) [1048576, 1835008)
  us* avb   = (us*)(ws + 1835008);    // bf16 524,288 elems [1835008, 2097152)
  us* wc    = (us*)(ws + 2097152);    // bf16 99,136 elems  [2097152, 2146720)
  float* ml = ws + 2146720;           // f32 2*4*NBN = 131,072  [2146720, 2277792)
  us* kpx   = (us*)(ws + 2277792);    // bf16 K px-major [b*N][32]: 524,288 elems [2277792, 2539936)
  us* vblk  = (us*)(ws + 2539936);    // bf16 V blocked [(b*N)/32][32ch][32key]: 524,288 elems [2539936, 2802080)
  us* x2T   = (us*)(ws + 3145728);    // bf16 px-major [b*N][256]: [3145728, 5242880)
  us* edgeT = (us*)(ws + 5242880);    // bf16 px-major [b*N][64]: 524,288 slots of 1M region
  float* offb  = ws + 6291456;        // f32 [6291456, 6586368)
  float* sm    = ws + 6586368;        // f32 (dead after k_edge_px)
  float* thick = ws + 6602752;        // f32 (dead after k_off_g)
  us* dbufT = (us*)(ws + 6619136);    // bf16 px-major [b*N][64]: [6619136, 7143424)
  float* ebufT = ws + 7143424;        // f32 px-major [b*N][64]: [7143424, 8192000)
  // aliases of dead/late regions:
  us* xT   = x2T;                     // xT live #3..#7; proj_g updates in-place
  us* wq   = dbufT;                   // wq live #0..#4; dbufT written later — disjoint
  us* wbf  = (us*)sm;                 // deform weights, written after k_off_g
  us* Opart = (us*)ebufT;             // attn bf16 partials x4: 2,097,152 shorts = exact region
  us* hnT  = qkvb;                    // qkvb dead after k_attn
  us* h1T  = x2T;                     // x2T dead after k_down_g
  us* h2T  = (us*)ws;                 // [0, 2097152) slots all dead by k_dw
  us* tbufT = edgeT;                  // edgeT dead after k_deform

  dim3 blk(256);
  k_wq<<<96, blk, 0, stream>>>(qkv_w, wq);
  k_wcast<<<388, blk, 0, stream>>>(proj_w, mlp1_w, down_w, mlp2_w, up_w, dw_w, edge_w, off_w, wc);
  k_upsample<<<(NB * 64 * NHW) / 256, blk, 0, stream>>>(skip, su);
  k_xpose<<<1024, blk, 0, stream>>>(x, xT);
  k_qkv_g<<<(NB * NHW) / 64, blk, 0, stream>>>(xT, wq, qkv_b, qkvb, kpx, vblk);
  k_attn<<<(NB * NHW / 64) * KSPLIT, blk, 0, stream>>>(qkvb, kpx, vblk, Opart, ml);
  k_merge<<<(NB * NHW * 32) / 256, blk, 0, stream>>>(Opart, ml, avb);
  k_proj_g<<<(NB * NHW) / 64, blk, 0, stream>>>(avb, xT, wc, proj_b, x2T);
  k_meanthick<<<(NB * NHW) / 256, blk, 0, stream>>>(su, thick_w, thick_b, sm, thick);
  k_edge_px<<<(NB * NHW * 8) / 256, blk, 0, stream>>>(sm, wc + 80128, edgeT);
  k_off_g<<<(NB * NHW) / 64, blk, 0, stream>>>(edgeT, wc + 80704, off_b, thick, offb);
  k_wprep<<<144, blk, 0, stream>>>(deform_w, wbf);
  k_deform<<<NB * 64, blk, 0, stream>>>(su, offb, wbf, deform_b, edgeT, dbufT);
  k_down_g<<<(NB * NHW) / 64, blk, 0, stream>>>(x2T, dbufT, wc + 24576, down_b, ebufT);
  k_ln<<<(NB * NHW) / 256, blk, 0, stream>>>(ebufT, ln_g, ln_b, hnT);
  k_mlp1_g<<<(NB * NHW) / 64, blk, 0, stream>>>(hnT, wc + 8192, mlp1_b, h1T);
  k_dw<<<(NB * NHW * 32) / 256, blk, 0, stream>>>(h1T, wc + 77824, dw_b, h2T);
  k_mlp2_g<<<(NB * NHW) / 64, blk, 0, stream>>>(h2T, wc + 45056, mlp2_b, ebufT, tbufT);
  k_up_g<<<(NB * NHW) / 64, blk, 0, stream>>>(tbufT, wc + 61440, up_b, (float*)d_out);
}

// Round 9
// 292.275 us; speedup vs baseline: 1.2646x; 1.0312x over previous
//
#include <hip/hip_runtime.h>
#include <hip/hip_bf16.h>
#include <math.h>

#define NB 4
#define NHW 4096
#define NBN (NB * NHW)
#define KSPLIT 4

typedef const float* fp;
typedef unsigned short us;
typedef __attribute__((ext_vector_type(8))) short short8;
typedef __attribute__((ext_vector_type(4))) short short4v;
typedef __attribute__((ext_vector_type(4))) float floatx4;
typedef __attribute__((ext_vector_type(2))) unsigned int uint2v;
typedef __attribute__((ext_vector_type(4))) unsigned int uint4v;

__device__ __forceinline__ float b2f(__hip_bfloat16 v) { return __bfloat162float(v); }
__device__ __forceinline__ __hip_bfloat16 f2b(float v) { return __float2bfloat16(v); }
__device__ __forceinline__ us f2bu(float f) {
  __hip_bfloat16 h = __float2bfloat16(f);
  return *reinterpret_cast<us*>(&h);
}
__device__ __forceinline__ float bu2f(us u) {
  __hip_bfloat16 h = *reinterpret_cast<__hip_bfloat16*>(&u);
  return __bfloat162float(h);
}
__device__ __forceinline__ float gelu_ex(float x) { return 0.5f * x * (1.0f + erff(x * 0.70710678118654752f)); }
__device__ __forceinline__ short8 ld8(const us* p) { return *(const short8*)p; }

// packed f32x2 -> bf16x2 (RNE), single instruction (T12; no builtin on gfx950)
__device__ __forceinline__ unsigned cvt_pk_bf16(float lo, float hi) {
  unsigned r;
  asm("v_cvt_pk_bf16_f32 %0, %1, %2" : "=v"(r) : "v"(lo), "v"(hi));
  return r;
}
// cross-quad reductions via permlane swaps (VALU-speed, no LDS/bpermute latency)
__device__ __forceinline__ float qmax4(float v) {
  uint2v p = __builtin_amdgcn_permlane16_swap(__float_as_uint(v), __float_as_uint(v), false, false);
  v = fmaxf(__uint_as_float(p.x), __uint_as_float(p.y));
  p = __builtin_amdgcn_permlane32_swap(__float_as_uint(v), __float_as_uint(v), false, false);
  return fmaxf(__uint_as_float(p.x), __uint_as_float(p.y));
}
__device__ __forceinline__ float qsum4(float v) {
  uint2v p = __builtin_amdgcn_permlane16_swap(__float_as_uint(v), __float_as_uint(v), false, false);
  v = __uint_as_float(p.x) + __uint_as_float(p.y);
  p = __builtin_amdgcn_permlane32_swap(__float_as_uint(v), __float_as_uint(v), false, false);
  return __uint_as_float(p.x) + __uint_as_float(p.y);
}

// ---------------- 0. fused weight prep: wq (24576) | wc (99136) | wbf (36864), one launch
// wc offsets (shorts): proj @0, mlp1 @8192, down @24576, mlp2 @45056, up @61440,
// dwT[tap][ch] @77824, ewT[tap][oc] @80128, woff[32 pad][9*64] @80704
__global__ __launch_bounds__(256) void k_wall(fp qw, fp pw, fp m1w, fp dnw, fp m2w, fp uw,
                                              fp dww, fp ew, fp ow, fp dfw,
                                              us* wq, us* wc, us* wbf) {
  int i = blockIdx.x * 256 + threadIdx.x;
  if (i < 24576) { wq[i] = f2bu(qw[i]); return; }
  i -= 24576;
  if (i < 99136) {
    float v;
    if (i < 8192) v = pw[i];
    else if (i < 24576) v = m1w[i - 8192];
    else if (i < 45056) v = dnw[i - 24576];
    else if (i < 61440) v = m2w[i - 45056];
    else if (i < 77824) v = uw[i - 61440];
    else if (i < 80128) {
      int i2 = i - 77824;           // dwT: tap = i2>>8, ch = i2&255
      v = dww[(i2 & 255) * 9 + (i2 >> 8)];
    } else if (i < 80704) {
      int i2 = i - 80128;           // ewT: tap = i2>>6, oc = i2&63
      v = ew[(i2 & 63) * 9 + (i2 >> 6)];
    } else {
      int i2 = i - 80704;           // woff[oc][tap*64+c], oc padded to 32
      int oc = i2 / 576, rem = i2 % 576;
      int tap = rem >> 6, c = rem & 63;
      v = (oc < 18) ? ow[(oc * 64 + c) * 9 + tap] : 0.f;
    }
    wc[i] = f2bu(v);
    return;
  }
  i -= 99136;
  if (i >= 9 * 64 * 64) return;
  int c = i & 63, oc = (i >> 6) & 63, k = i >> 12;
  wbf[i] = f2bu(dfw[(oc * 64 + c) * 9 + k]);
}

// ---------------- 1. bilinear upsample -> su f32 (r8 verbatim)
__global__ __launch_bounds__(256) void k_upsample(fp skip, float* su) {
  int idx = blockIdx.x * 256 + threadIdx.x;
  if (idx >= NB * 64 * NHW) return;
  int hw = idx & 4095, bc = idx >> 12;
  int y = hw >> 6, x = hw & 63;
  float fy = 0.5f * y - 0.25f, fx = 0.5f * x - 0.25f;
  float y0f = floorf(fy), x0f = floorf(fx);
  float wy = fy - y0f, wx = fx - x0f;
  int y0 = (int)y0f, x0 = (int)x0f;
  int y0c = min(31, max(0, y0)), y1c = min(31, max(0, y0 + 1));
  int x0c = min(31, max(0, x0)), x1c = min(31, max(0, x0 + 1));
  const float* p = skip + (size_t)bc * 1024;
  float v00 = p[y0c * 32 + x0c], v01 = p[y0c * 32 + x1c];
  float v10 = p[y1c * 32 + x0c], v11 = p[y1c * 32 + x1c];
  su[idx] = (1.f - wy) * ((1.f - wx) * v00 + wx * v01) + wy * ((1.f - wx) * v10 + wx * v11);
}

// ---------------- 2. transpose x f32 -> xT bf16 [b*4096][256] (r8 verbatim)
__global__ __launch_bounds__(256) void k_xpose(fp x, us* xT) {
  __shared__ float tile[64][65];
  int bid = blockIdx.x;
  int pt = bid & 63, ct = (bid >> 6) & 3, b = bid >> 8;
  int px0 = pt * 64, c0 = ct * 64;
  int tx = threadIdx.x & 63, ty = threadIdx.x >> 6;
  const float* src = x + ((size_t)(b * 256 + c0)) * NHW + px0;
#pragma unroll
  for (int i = 0; i < 16; i++) {
    int r = i * 4 + ty;
    tile[r][tx] = src[(size_t)r * NHW + tx];
  }
  __syncthreads();
  int cseg = threadIdx.x & 7, p0 = threadIdx.x >> 3;
#pragma unroll
  for (int h = 0; h < 2; h++) {
    int p = p0 + h * 32;
    short8 v;
#pragma unroll
    for (int j = 0; j < 8; j++) v[j] = (short)f2bu(tile[cseg * 8 + j][p]);
    *(short8*)&xT[((size_t)(b * NHW) + px0 + p) * 256 + c0 + cseg * 8] = v;
  }
}

// ---------------- 3. qkv GEMM -> Q ch-major bf16 [b][32][N]; K px-major kpx[b*N][32];
// V blocked vblk[(b*N+key)/32][ch][key%32] (lane-contiguous PV fragments).
// Q scale folds 1/sqrt(32) * log2(e) so attention runs in exp2 domain.
__global__ __launch_bounds__(256) void k_qkv_g(const us* xT, const us* wq, fp bias, us* qkvb, us* kpx, us* vblk) {
  int wave = threadIdx.x >> 6, lane = threadIdx.x & 63;
  int quad = lane >> 4, l16 = lane & 15;
  int pxg0 = blockIdx.x * 64 + wave * 16;
  int b = pxg0 >> 12, hw0 = pxg0 & 4095;
  floatx4 acc[6];
#pragma unroll
  for (int m = 0; m < 6; m++) acc[m] = (floatx4){0.f, 0.f, 0.f, 0.f};
  const us* xrow = xT + (size_t)(pxg0 + l16) * 256 + quad * 8;
#pragma unroll
  for (int k0 = 0; k0 < 256; k0 += 32) {
    short8 bf = ld8(xrow + k0);
#pragma unroll
    for (int m = 0; m < 6; m++) {
      short8 af = ld8(wq + (size_t)(m * 16 + l16) * 256 + k0 + quad * 8);
      acc[m] = __builtin_amdgcn_mfma_f32_16x16x32_bf16(af, bf, acc[m], 0, 0, 0);
    }
  }
#pragma unroll
  for (int m = 0; m < 6; m++) {
    if (m == 2 || m == 3) {
      // K channels -> px-major, 4 consecutive oc per lane -> one b64 store
      short4v pkv;
#pragma unroll
      for (int r = 0; r < 4; r++) {
        int oc = m * 16 + quad * 4 + r;
        pkv[r] = (short)f2bu(acc[m][r] + bias[oc]);
      }
      *(short4v*)&kpx[((size_t)(b * NHW) + hw0 + l16) * 32 + (m - 2) * 16 + quad * 4] = pkv;
    } else if (m >= 4) {
      // V -> blocked [key/32][ch][key%32]
      int key = hw0 + l16;
      size_t base = ((size_t)(b * NHW + key) >> 5) * 1024 + (size_t)(key & 31);
#pragma unroll
      for (int r = 0; r < 4; r++) {
        int ch = (m - 4) * 16 + quad * 4 + r;
        vblk[base + (size_t)ch * 32] = f2bu(acc[m][r] + bias[64 + ch]);
      }
    } else {
#pragma unroll
      for (int r = 0; r < 4; r++) {
        int oc = m * 16 + quad * 4 + r;
        float v = (acc[m][r] + bias[oc]) * 0.25503485f;   // (1/sqrt(32)) * log2(e)
        qkvb[(size_t)(b * 32 + oc) * NHW + hw0 + l16] = f2bu(v);
      }
    }
  }
}

// ---------------- 4. LDS-free flash attention, SPLIT-K x4, swapped QK^T.
// Each lane owns one query (q = l16). S^T = mfma(K_px, Q); softmax reduce =
// max3-fused in-lane tree + permlane swaps; P packed via v_cvt_pk_bf16_f32;
// P^T in-register via permlane32/16_swap; O^T = mfma(V_blk, P^T).
// K prefetched across tiles (r2-proven); V fragments lane-contiguous via vblk.
__global__ __launch_bounds__(256, 4) void k_attn(const us* qkvb, const us* kpx, const us* vblk,
                                                 us* Opart, float* ml) {
  int tid = threadIdx.x;
  int wave = tid >> 6, lane = tid & 63;
  int quad = lane >> 4, l16 = lane & 15;
  int blk = blockIdx.x;
  int kh = blk & 3;
  int rest = blk >> 2;
  int b = rest >> 6;
  int qbase = (rest & 63) * 64 + wave * 16;
  const us* qp = qkvb + (size_t)b * 32 * NHW;
  const us* kb_base = kpx + (size_t)b * NHW * 32;

  // Q fragment as B-operand: B[col=q=l16][k=ch=quad*8+j]
  short8 bq;
#pragma unroll
  for (int j = 0; j < 8; j++)
    bq[j] = (short)qp[(size_t)(quad * 8 + j) * NHW + qbase + l16];

  float m_r = -1e30f, l_r = 0.f;
  floatx4 o0 = {0.f, 0.f, 0.f, 0.f}, o1 = {0.f, 0.f, 0.f, 0.f};

  int kb0 = kh * 1024;
  // prefetch first K tile: A[row=key=l16][k=ch]
  short8 akf[8];
#pragma unroll
  for (int t = 0; t < 8; t++)
    akf[t] = ld8(kb_base + (size_t)(kb0 + t * 16 + l16) * 32 + quad * 8);

  for (int kb = kb0; kb < kb0 + 1024; kb += 128) {
    // S^T: sT[t][r] = S[key = kb + t*16 + quad*4 + r][q = l16]
    floatx4 sT[8];
    __builtin_amdgcn_s_setprio(1);
#pragma unroll
    for (int t = 0; t < 8; t++) {
      floatx4 z = {0.f, 0.f, 0.f, 0.f};
      sT[t] = __builtin_amdgcn_mfma_f32_16x16x32_bf16(akf[t], bq, z, 0, 0, 0);
    }
    __builtin_amdgcn_s_setprio(0);

    // prefetch next K tile under the softmax VALU work
    int kbn = (kb + 128 < kb0 + 1024) ? kb + 128 : kb0;
#pragma unroll
    for (int t = 0; t < 8; t++)
      akf[t] = ld8(kb_base + (size_t)(kbn + t * 16 + l16) * 32 + quad * 8);

    // running max: chained in-lane tree (fuses to v_max3) + 2 permlane swaps
    float tm[8];
#pragma unroll
    for (int t = 0; t < 8; t++)
      tm[t] = fmaxf(fmaxf(fmaxf(sT[t][0], sT[t][1]), sT[t][2]), sT[t][3]);
    float mx = fmaxf(fmaxf(fmaxf(tm[0], tm[1]), tm[2]), tm[3]);
    mx = fmaxf(fmaxf(fmaxf(fmaxf(mx, tm[4]), tm[5]), tm[6]), tm[7]);
    mx = qmax4(mx);
    float mnew = fmaxf(m_r, mx);
    float alpha = exp2f(m_r - mnew);
    m_r = mnew;

    // P = 2^(s - m), packed to bf16 pairs via v_cvt_pk_bf16_f32
    float rs0 = 0.f, rs1 = 0.f;
    unsigned pkw[8][2];
#pragma unroll
    for (int t = 0; t < 8; t++) {
      float p0 = exp2f(sT[t][0] - mnew);
      float p1 = exp2f(sT[t][1] - mnew);
      float p2 = exp2f(sT[t][2] - mnew);
      float p3 = exp2f(sT[t][3] - mnew);
      rs0 += p0 + p1;
      rs1 += p2 + p3;
      pkw[t][0] = cvt_pk_bf16(p0, p1);
      pkw[t][1] = cvt_pk_bf16(p2, p3);
    }
    float rs = qsum4(rs0 + rs1);
    l_r = l_r * alpha + rs;
#pragma unroll
    for (int r = 0; r < 4; r++) { o0[r] *= alpha; o1[r] *= alpha; }

    // PV: O^T += V * P^T. V fragments from vblk: base + ch*32 + keyoff, lane-contiguous 1KB.
    __builtin_amdgcn_s_setprio(1);
#pragma unroll
    for (int cc = 0; cc < 4; cc++) {
      uint2v t1 = __builtin_amdgcn_permlane32_swap(pkw[2 * cc][0], pkw[2 * cc + 1][0], false, false);
      uint2v t2 = __builtin_amdgcn_permlane16_swap(t1.x, t1.y, false, false);
      uint2v t3 = __builtin_amdgcn_permlane32_swap(pkw[2 * cc][1], pkw[2 * cc + 1][1], false, false);
      uint2v t4 = __builtin_amdgcn_permlane16_swap(t3.x, t3.y, false, false);
      uint4v pw = {t2.x, t4.x, t2.y, t4.y};
      short8 pa = *(short8*)&pw;
      const us* vb = vblk + ((size_t)(b * NHW + kb + cc * 32) >> 5) * 1024 + quad * 8;
      short8 av0 = ld8(vb + (size_t)l16 * 32);
      short8 av1 = ld8(vb + (size_t)(l16 + 16) * 32);
      o0 = __builtin_amdgcn_mfma_f32_16x16x32_bf16(av0, pa, o0, 0, 0, 0);
      o1 = __builtin_amdgcn_mfma_f32_16x16x32_bf16(av1, pa, o1, 0, 0, 0);
    }
    __builtin_amdgcn_s_setprio(0);
  }

  // epilogue: lane owns q = qbase + l16, channels quad*4+r (o0) and 16+quad*4+r (o1)
  int q = qbase + l16;
  size_t qg = (size_t)b * NHW + q;
  us* dst = Opart + ((size_t)kh * NBN + qg) * 32;
  short4v e0, e1;
#pragma unroll
  for (int r = 0; r < 4; r++) { e0[r] = (short)f2bu(o0[r]); e1[r] = (short)f2bu(o1[r]); }
  *(short4v*)(dst + quad * 4) = e0;
  *(short4v*)(dst + 16 + quad * 4) = e1;
  if (quad == 0) {
    ml[(size_t)kh * NBN + qg] = m_r;
    ml[(size_t)KSPLIT * NBN + (size_t)kh * NBN + qg] = l_r;
  }
}

// ---------------- 4b. merge 4 split-K partials -> avb px-major bf16 (exp2 domain)
__global__ __launch_bounds__(256) void k_merge(const us* Opart, const float* ml, us* avb) {
  int idx = blockIdx.x * 256 + threadIdx.x;
  int ch = idx & 31, qg = idx >> 5;
  float mk[KSPLIT];
  float m = -1e30f;
#pragma unroll
  for (int kh = 0; kh < KSPLIT; kh++) { mk[kh] = ml[kh * NBN + qg]; m = fmaxf(m, mk[kh]); }
  float l = 0.f, v = 0.f;
#pragma unroll
  for (int kh = 0; kh < KSPLIT; kh++) {
    float a = exp2f(mk[kh] - m);
    l += ml[KSPLIT * NBN + kh * NBN + qg] * a;
    v += bu2f(Opart[((size_t)(kh * NBN) + qg) * 32 + ch]) * a;
  }
  avb[idx] = f2bu(v / l);
}

// ---------------- 5. proj GEMM act-first (r10 verbatim)
__global__ __launch_bounds__(256) void k_proj_g(const us* avb, const us* xT, const us* wpj, fp bias, us* x2T) {
  int wave = threadIdx.x >> 6, lane = threadIdx.x & 63;
  int quad = lane >> 4, l16 = lane & 15;
  int pxg0 = blockIdx.x * 64 + wave * 16;
  short8 act = ld8(avb + (size_t)(pxg0 + l16) * 32 + quad * 8);
  floatx4 acc[16];
#pragma unroll
  for (int n = 0; n < 16; n++) {
    short8 wf = ld8(wpj + (size_t)(n * 16 + l16) * 32 + quad * 8);
    floatx4 z = {0.f, 0.f, 0.f, 0.f};
    acc[n] = __builtin_amdgcn_mfma_f32_16x16x32_bf16(act, wf, z, 0, 0, 0);
  }
#pragma unroll
  for (int n = 0; n < 16; n++)
#pragma unroll
    for (int r = 0; r < 4; r++) {
      int px = pxg0 + quad * 4 + r;
      int oc = n * 16 + l16;
      size_t oidx = (size_t)px * 256 + oc;
      x2T[oidx] = f2bu(acc[n][r] + bias[oc] + bu2f(xT[oidx]));
    }
}

// ---------------- 6. channel mean + thick: 8 lanes/px + shfl reduce (512 blocks)
__global__ __launch_bounds__(256) void k_meanthick(const float* su, fp tw, fp tb, float* sm, float* thick) {
  int idx = blockIdx.x * 256 + threadIdx.x;   // NB*NHW*8
  int l8 = idx & 7, pxg = idx >> 3;
  int hw = pxg & 4095, b = pxg >> 12;
  const float* p = su + ((size_t)(b * 64 + l8 * 8)) * NHW + hw;
  float s = 0.f, ts = 0.f;
#pragma unroll
  for (int c = 0; c < 8; c++) {
    float v = p[(size_t)c * NHW];
    s += v;
    ts += v * tw[l8 * 8 + c];
  }
  s += __shfl_xor(s, 1); ts += __shfl_xor(ts, 1);
  s += __shfl_xor(s, 2); ts += __shfl_xor(ts, 2);
  s += __shfl_xor(s, 4); ts += __shfl_xor(ts, 4);
  if (l8 == 0) {
    sm[pxg] = s * (1.f / 64.f);
    thick[pxg] = 1.f / (1.f + __expf(-(ts + tb[0])));
  }
}

// ---------------- 7. edge conv 3x3 px-major: thread=(px, 8-oc block) -> edgeT bf16 [b*N][64]
__global__ __launch_bounds__(256) void k_edge_px(const float* sm, const us* ewT, us* edgeT) {
  int idx = blockIdx.x * 256 + threadIdx.x;   // NB*NHW*8
  int cb = idx & 7, pxg = idx >> 3;
  int b = pxg >> 12, hw = pxg & 4095;
  int y = hw >> 6, x = hw & 63;
  int c0 = cb * 8;
  float acc[8] = {0.f, 0.f, 0.f, 0.f, 0.f, 0.f, 0.f, 0.f};
#pragma unroll
  for (int ky = 0; ky < 3; ky++) {
#pragma unroll
    for (int kx = 0; kx < 3; kx++) {
      int yy = y + ky - 1, xx = x + kx - 1;
      if (yy >= 0 && yy < 64 && xx >= 0 && xx < 64) {
        float sv = sm[b * NHW + yy * 64 + xx];
        short8 wv = ld8(ewT + (ky * 3 + kx) * 64 + c0);
#pragma unroll
        for (int j = 0; j < 8; j++) acc[j] += sv * bu2f((us)wv[j]);
      }
    }
  }
  short8 pk;
#pragma unroll
  for (int j = 0; j < 8; j++) pk[j] = (short)f2bu(acc[j]);
  *(short8*)(edgeT + (size_t)pxg * 64 + c0) = pk;
}

// ---------------- 8. offset conv as MFMA GEMM: K=9x64, N=32(18 used), act=shifted edgeT rows
__global__ __launch_bounds__(256) void k_off_g(const us* edgeT, const us* woff, fp ob,
                                               const float* thick, float* offb) {
  int wave = threadIdx.x >> 6, lane = threadIdx.x & 63;
  int quad = lane >> 4, l16 = lane & 15;
  int pxg0 = blockIdx.x * 64 + wave * 16;
  int b = pxg0 >> 12;
  int pxl = pxg0 + l16;
  int hwl = pxl & 4095;
  int yl = hwl >> 6, xl = hwl & 63;
  floatx4 acc[2];
  acc[0] = (floatx4){0.f, 0.f, 0.f, 0.f};
  acc[1] = (floatx4){0.f, 0.f, 0.f, 0.f};
  const short8 zz = {0, 0, 0, 0, 0, 0, 0, 0};
#pragma unroll
  for (int t = 0; t < 9; t++) {
    int yy = yl + t / 3 - 1, xx = xl + t % 3 - 1;
    bool valid = (yy >= 0 && yy < 64 && xx >= 0 && xx < 64);
    const us* arow = edgeT + ((size_t)(b * NHW + yy * 64 + xx)) * 64;
#pragma unroll
    for (int s = 0; s < 2; s++) {
      short8 act = valid ? ld8(arow + s * 32 + quad * 8) : zz;   // k_dw-style conditional row load
      int kk = t * 64 + s * 32 + quad * 8;
#pragma unroll
      for (int n = 0; n < 2; n++) {
        short8 wf = ld8(woff + (size_t)(n * 16 + l16) * 576 + kk);
        acc[n] = __builtin_amdgcn_mfma_f32_16x16x32_bf16(act, wf, acc[n], 0, 0, 0);
      }
    }
  }
#pragma unroll
  for (int n = 0; n < 2; n++)
#pragma unroll
    for (int r = 0; r < 4; r++) {
      int oc = n * 16 + l16;
      if (oc < 18) {
        int px = pxg0 + quad * 4 + r;
        int hw = px & 4095;
        float v = (acc[n][r] + ob[oc]) * (1.f + 16.f * thick[px]);
        offb[(size_t)(b * 18 + oc) * NHW + hw] = v;
      }
    }
}

// ---------------- 9. MFMA deformable conv (r10 structure; edge residual from edgeT rows)
__global__ __launch_bounds__(256) void k_deform(const float* su, const float* offb,
                                                const us* wbf, fp db,
                                                const us* edgeT, us* dbufT) {
  __shared__ __align__(16) us samT[4][16][72];
  int tid = threadIdx.x;
  int wave = tid >> 6, lane = tid & 63;
  int quad = lane >> 4, l16 = lane & 15;
  int b = blockIdx.x >> 6, row = blockIdx.x & 63;
  const float* sub = su + (size_t)b * 64 * NHW;

  int sp = lane & 15, sq = lane >> 4;
  int hw_s = row * 64 + wave * 16 + sp;
  int x_s = wave * 16 + sp;

  floatx4 acc[4];
#pragma unroll
  for (int a = 0; a < 4; a++) acc[a] = (floatx4){0.f, 0.f, 0.f, 0.f};

  for (int k = 0; k < 9; k++) {
    float dy = offb[((size_t)(b * 18 + 2 * k)) * NHW + hw_s];
    float dx = offb[((size_t)(b * 18 + 2 * k + 1)) * NHW + hw_s];
    float py = (float)(row + k / 3 - 1) + dy;
    float pxf = (float)(x_s + k % 3 - 1) + dx;
    float y0f = floorf(py), x0f = floorf(pxf);
    float wy = py - y0f, wx = pxf - x0f;
    int y0 = (int)y0f, x0 = (int)x0f;
    int y1 = y0 + 1, x1 = x0 + 1;
    float vy0 = (y0 >= 0 && y0 < 64) ? 1.f : 0.f;
    float vy1 = (y1 >= 0 && y1 < 64) ? 1.f : 0.f;
    float vx0 = (x0 >= 0 && x0 < 64) ? 1.f : 0.f;
    float vx1 = (x1 >= 0 && x1 < 64) ? 1.f : 0.f;
    float w00 = (1.f - wy) * (1.f - wx) * vy0 * vx0;
    float w01 = (1.f - wy) * wx * vy0 * vx1;
    float w10 = wy * (1.f - wx) * vy1 * vx0;
    float w11 = wy * wx * vy1 * vx1;
    int y0c = min(63, max(0, y0)), y1c = min(63, max(0, y1));
    int x0c = min(63, max(0, x0)), x1c = min(63, max(0, x1));
    int i00 = y0c * 64 + x0c, i01 = y0c * 64 + x1c;
    int i10 = y1c * 64 + x0c, i11 = y1c * 64 + x1c;

#pragma unroll
    for (int i = 0; i < 16; i += 2) {
      int c0 = sq * 16 + i;
      const float* s0 = sub + (size_t)c0 * NHW;
      const float* s1 = s0 + NHW;
      float v0 = w00 * s0[i00] + w01 * s0[i01] + w10 * s0[i10] + w11 * s0[i11];
      float v1 = w00 * s1[i00] + w01 * s1[i01] + w10 * s1[i10] + w11 * s1[i11];
      unsigned int pk = (unsigned int)f2bu(v0) | ((unsigned int)f2bu(v1) << 16);
      *(unsigned int*)&samT[wave][sp][c0] = pk;
    }

#pragma unroll
    for (int s = 0; s < 2; s++) {
      short8 bfrag = *(const short8*)&samT[wave][l16][s * 32 + quad * 8];
#pragma unroll
      for (int a = 0; a < 4; a++) {
        short8 afrag = ld8(wbf + ((size_t)(k * 64 + a * 16 + l16) * 64 + s * 32 + quad * 8));
        acc[a] = __builtin_amdgcn_mfma_f32_16x16x32_bf16(bfrag, afrag, acc[a], 0, 0, 0);
      }
    }
  }

#pragma unroll
  for (int a = 0; a < 4; a++)
#pragma unroll
    for (int r = 0; r < 4; r++) {
      int oc = a * 16 + l16;
      int pxr = row * 64 + wave * 16 + quad * 4 + r;
      size_t rowi = (size_t)(b * NHW) + pxr;
      float v = acc[a][r] + db[oc] + bu2f(edgeT[rowi * 64 + oc]);
      dbufT[rowi * 64 + oc] = f2bu(v);
    }
}

// ---------------- 10. down GEMM act-first -> ebufT px-major f32 (r11 verbatim)
__global__ __launch_bounds__(256) void k_down_g(const us* x2T, const us* dbufT, const us* wd, fp bias, float* ebufT) {
  int wave = threadIdx.x >> 6, lane = threadIdx.x & 63;
  int quad = lane >> 4, l16 = lane & 15;
  int pxg0 = blockIdx.x * 64 + wave * 16;
  floatx4 acc[4];
#pragma unroll
  for (int m = 0; m < 4; m++) acc[m] = (floatx4){0.f, 0.f, 0.f, 0.f};
  const us* xrow = x2T + (size_t)(pxg0 + l16) * 256 + quad * 8;
#pragma unroll
  for (int k0 = 0; k0 < 256; k0 += 32) {
    short8 act = ld8(xrow + k0);
#pragma unroll
    for (int m = 0; m < 4; m++) {
      short8 wf = ld8(wd + (size_t)(m * 16 + l16) * 320 + k0 + quad * 8);
      acc[m] = __builtin_amdgcn_mfma_f32_16x16x32_bf16(act, wf, acc[m], 0, 0, 0);
    }
  }
  const us* drow = dbufT + (size_t)(pxg0 + l16) * 64 + quad * 8;
#pragma unroll
  for (int k0 = 0; k0 < 64; k0 += 32) {
    short8 act = ld8(drow + k0);
#pragma unroll
    for (int m = 0; m < 4; m++) {
      short8 wf = ld8(wd + (size_t)(m * 16 + l16) * 320 + 256 + k0 + quad * 8);
      acc[m] = __builtin_amdgcn_mfma_f32_16x16x32_bf16(act, wf, acc[m], 0, 0, 0);
    }
  }
#pragma unroll
  for (int m = 0; m < 4; m++)
#pragma unroll
    for (int r = 0; r < 4; r++) {
      int px = pxg0 + quad * 4 + r;
      int oc = m * 16 + l16;
      ebufT[(size_t)px * 64 + oc] = acc[m][r] + bias[oc];
    }
}

// ---------------- 11. LayerNorm px-major: 4 lanes/px + shfl reduce (256 blocks)
__global__ __launch_bounds__(256) void k_ln(const float* eT, fp g, fp bt, us* hnT) {
  int idx = blockIdx.x * 256 + threadIdx.x;   // NB*NHW*4
  int l4 = idx & 3, px = idx >> 2;
  const float* p = eT + (size_t)px * 64 + l4 * 16;
  float v[16];
  float s = 0.f;
#pragma unroll
  for (int i = 0; i < 4; i++) {
    float4 t = ((const float4*)p)[i];
    v[i * 4] = t.x; v[i * 4 + 1] = t.y; v[i * 4 + 2] = t.z; v[i * 4 + 3] = t.w;
    s += t.x + t.y + t.z + t.w;
  }
  s += __shfl_xor(s, 1);
  s += __shfl_xor(s, 2);
  float mu = s * (1.f / 64.f);
  float q = 0.f;
#pragma unroll
  for (int c = 0; c < 16; c++) { float d = v[c] - mu; q += d * d; }
  q += __shfl_xor(q, 1);
  q += __shfl_xor(q, 2);
  float rstd = rsqrtf(q * (1.f / 64.f) + 1e-5f);
  us* o = hnT + (size_t)px * 64 + l4 * 16;
#pragma unroll
  for (int j = 0; j < 2; j++) {
    short8 pk;
#pragma unroll
    for (int t = 0; t < 8; t++) {
      int c = j * 8 + t;
      pk[t] = (short)f2bu((v[c] - mu) * rstd * g[l4 * 16 + c] + bt[l4 * 16 + c]);
    }
    *(short8*)(o + j * 8) = pk;
  }
}

// ---------------- 12. mlp1 GEMM act-first (r11 verbatim)
__global__ __launch_bounds__(256) void k_mlp1_g(const us* hnT, const us* wm1, fp bias, us* h1T) {
  int wave = threadIdx.x >> 6, lane = threadIdx.x & 63;
  int quad = lane >> 4, l16 = lane & 15;
  int pxg0 = blockIdx.x * 64 + wave * 16;
  floatx4 acc[16];
#pragma unroll
  for (int m = 0; m < 16; m++) acc[m] = (floatx4){0.f, 0.f, 0.f, 0.f};
  const us* hrow = hnT + (size_t)(pxg0 + l16) * 64 + quad * 8;
#pragma unroll
  for (int k0 = 0; k0 < 64; k0 += 32) {
    short8 act = ld8(hrow + k0);
#pragma unroll
    for (int m = 0; m < 16; m++) {
      short8 wf = ld8(wm1 + (size_t)(m * 16 + l16) * 64 + k0 + quad * 8);
      acc[m] = __builtin_amdgcn_mfma_f32_16x16x32_bf16(act, wf, acc[m], 0, 0, 0);
    }
  }
#pragma unroll
  for (int m = 0; m < 16; m++)
#pragma unroll
    for (int r = 0; r < 4; r++) {
      int px = pxg0 + quad * 4 + r;
      int oc = m * 16 + l16;
      h1T[(size_t)px * 256 + oc] = f2bu(gelu_ex(acc[m][r] + bias[oc]));
    }
}

// ---------------- 13. depthwise 3x3 + GELU, px-major (r12 verbatim)
__global__ __launch_bounds__(256) void k_dw(const us* h1T, const us* wdwT, fp bias, us* h2T) {
  int idx = blockIdx.x * 256 + threadIdx.x;   // NB*NHW*32
  int cb = idx & 31, pxg = idx >> 5;
  int b = pxg >> 12, hw = pxg & 4095;
  int y = hw >> 6, x = hw & 63;
  int c0 = cb * 8;
  float4 b0 = *(const float4*)(bias + c0);
  float4 b1 = *(const float4*)(bias + c0 + 4);
  float acc[8] = {b0.x, b0.y, b0.z, b0.w, b1.x, b1.y, b1.z, b1.w};
#pragma unroll
  for (int ky = 0; ky < 3; ky++) {
#pragma unroll
    for (int kx = 0; kx < 3; kx++) {
      int tap = ky * 3 + kx;
      short8 wv = ld8(wdwT + tap * 256 + c0);
      int yy = y + ky - 1, xx = x + kx - 1;
      if (yy >= 0 && yy < 64 && xx >= 0 && xx < 64) {
        short8 vv = ld8(h1T + ((size_t)(b * NHW + yy * 64 + xx)) * 256 + c0);
#pragma unroll
        for (int j = 0; j < 8; j++)
          acc[j] += bu2f((us)vv[j]) * bu2f((us)wv[j]);
      }
    }
  }
  short8 pk;
#pragma unroll
  for (int j = 0; j < 8; j++) pk[j] = (short)f2bu(gelu_ex(acc[j]));
  *(short8*)(h2T + (size_t)pxg * 256 + c0) = pk;
}

// ---------------- 14. mlp2 GEMM act-first (r11 verbatim)
__global__ __launch_bounds__(256) void k_mlp2_g(const us* h2T, const us* wm2, fp bias, const float* ebufT, us* tbufT) {
  int wave = threadIdx.x >> 6, lane = threadIdx.x & 63;
  int quad = lane >> 4, l16 = lane & 15;
  int pxg0 = blockIdx.x * 64 + wave * 16;
  floatx4 acc[4];
#pragma unroll
  for (int m = 0; m < 4; m++) acc[m] = (floatx4){0.f, 0.f, 0.f, 0.f};
  const us* hrow = h2T + (size_t)(pxg0 + l16) * 256 + quad * 8;
#pragma unroll
  for (int k0 = 0; k0 < 256; k0 += 32) {
    short8 act = ld8(hrow + k0);
#pragma unroll
    for (int m = 0; m < 4; m++) {
      short8 wf = ld8(wm2 + (size_t)(m * 16 + l16) * 256 + k0 + quad * 8);
      acc[m] = __builtin_amdgcn_mfma_f32_16x16x32_bf16(act, wf, acc[m], 0, 0, 0);
    }
  }
#pragma unroll
  for (int m = 0; m < 4; m++)
#pragma unroll
    for (int r = 0; r < 4; r++) {
      int px = pxg0 + quad * 4 + r;
      int oc = m * 16 + l16;
      size_t oidx = (size_t)px * 64 + oc;
      tbufT[oidx] = f2bu(acc[m][r] + bias[oc] + ebufT[oidx]);
    }
}

// ---------------- 15. up GEMM W-first (r11 verbatim)
__global__ __launch_bounds__(256) void k_up_g(const us* tbufT, const us* wu, fp bias, float* out) {
  int wave = threadIdx.x >> 6, lane = threadIdx.x & 63;
  int quad = lane >> 4, l16 = lane & 15;
  int pxg0 = blockIdx.x * 64 + wave * 16;
  int b = pxg0 >> 12, hw0 = pxg0 & 4095;
  floatx4 acc[16];
#pragma unroll
  for (int m = 0; m < 16; m++) acc[m] = (floatx4){0.f, 0.f, 0.f, 0.f};
  const us* trow = tbufT + (size_t)(pxg0 + l16) * 64 + quad * 8;
#pragma unroll
  for (int k0 = 0; k0 < 64; k0 += 32) {
    short8 bf = ld8(trow + k0);
#pragma unroll
    for (int m = 0; m < 16; m++) {
      short8 af = ld8(wu + (size_t)(m * 16 + l16) * 64 + k0 + quad * 8);
      acc[m] = __builtin_amdgcn_mfma_f32_16x16x32_bf16(af, bf, acc[m], 0, 0, 0);
    }
  }
#pragma unroll
  for (int m = 0; m < 16; m++)
#pragma unroll
    for (int r = 0; r < 4; r++) {
      int oc = m * 16 + quad * 4 + r;
      out[(size_t)(b * 256 + oc) * NHW + hw0 + l16] = acc[m][r] + bias[oc];
    }
}

extern "C" void kernel_launch(void* const* d_in, const int* in_sizes, int n_in,
                              void* d_out, int out_size, void* d_ws, size_t ws_size,
                              hipStream_t stream) {
  fp x = (fp)d_in[0], skip = (fp)d_in[1], qkv_w = (fp)d_in[2], qkv_b = (fp)d_in[3],
     proj_w = (fp)d_in[4], proj_b = (fp)d_in[5], edge_w = (fp)d_in[6], thick_w = (fp)d_in[7],
     thick_b = (fp)d_in[8], off_w = (fp)d_in[9], off_b = (fp)d_in[10], deform_w = (fp)d_in[11],
     deform_b = (fp)d_in[12], ln_g = (fp)d_in[13], ln_b = (fp)d_in[14], mlp1_w = (fp)d_in[15],
     mlp1_b = (fp)d_in[16], dw_w = (fp)d_in[17], dw_b = (fp)d_in[18], mlp2_w = (fp)d_in[19],
     mlp2_b = (fp)d_in[20], down_w = (fp)d_in[21], down_b = (fp)d_in[22], up_w = (fp)d_in[23],
     up_b = (fp)d_in[24];

  float* ws = (float*)d_ws;
  // ---- layout; wc 99,136 shorts; ml 2*4*NBN f32; kpx + vblk + wbf in free gap ----
  float* su    = ws + 0;              // f32 [0, 1048576)
  us* qkvb  = (us*)(ws + 1048576);    // bf16 Q-only [b][32][N] [1048576, 1835008)
  us* avb   = (us*)(ws + 1835008);    // bf16 524,288 elems [1835008, 2097152)
  us* wc    = (us*)(ws + 2097152);    // bf16 99,136 elems  [2097152, 2146720)
  float* ml = ws + 2146720;           // f32 2*4*NBN = 131,072  [2146720, 2277792)
  us* kpx   = (us*)(ws + 2277792);    // bf16 K px-major [b*N][32]: 524,288 elems [2277792, 2539936)
  us* vblk  = (us*)(ws + 2539936);    // bf16 V blocked [(b*N)/32][32ch][32key]: 524,288 elems [2539936, 2802080)
  us* wbf   = (us*)(ws + 2802080);    // bf16 deform W 36,864 elems [2802080, 2820512) — written once by k_wall,
                                      // read by k_deform; no intermediate writer in this gap
  us* x2T   = (us*)(ws + 3145728);    // bf16 px-major [b*N][256]: [3145728, 5242880)
  us* edgeT = (us*)(ws + 5242880);    // bf16 px-major [b*N][64]: 524,288 slots of 1M region
  float* offb  = ws + 6291456;        // f32 [6291456, 6586368)
  float* sm    = ws + 6586368;        // f32 (dead after k_edge_px)
  float* thick = ws + 6602752;        // f32 (dead after k_off_g)
  us* dbufT = (us*)(ws + 6619136);    // bf16 px-major [b*N][64]: [6619136, 7143424)
  float* ebufT = ws + 7143424;        // f32 px-major [b*N][64]: [7143424, 8192000)
  // aliases of dead/late regions:
  us* xT   = x2T;                     // xT live #3..#7; proj_g updates in-place
  us* wq   = dbufT;                   // wq written by k_wall, read by k_qkv_g; dbufT written later — disjoint
  us* Opart = (us*)ebufT;             // attn bf16 partials x4: 2,097,152 shorts = exact region
  us* hnT  = qkvb;                    // qkvb dead after k_attn
  us* h1T  = x2T;                     // x2T dead after k_down_g
  us* h2T  = (us*)ws;                 // [0, 2097152) slots all dead by k_dw
  us* tbufT = edgeT;                  // edgeT dead after k_deform

  dim3 blk(256);
  k_wall<<<628, blk, 0, stream>>>(qkv_w, proj_w, mlp1_w, down_w, mlp2_w, up_w,
                                  dw_w, edge_w, off_w, deform_w, wq, wc, wbf);
  k_upsample<<<(NB * 64 * NHW) / 256, blk, 0, stream>>>(skip, su);
  k_xpose<<<1024, blk, 0, stream>>>(x, xT);
  k_qkv_g<<<(NB * NHW) / 64, blk, 0, stream>>>(xT, wq, qkv_b, qkvb, kpx, vblk);
  k_attn<<<(NB * NHW / 64) * KSPLIT, blk, 0, stream>>>(qkvb, kpx, vblk, Opart, ml);
  k_merge<<<(NB * NHW * 32) / 256, blk, 0, stream>>>(Opart, ml, avb);
  k_proj_g<<<(NB * NHW) / 64, blk, 0, stream>>>(avb, xT, wc, proj_b, x2T);
  k_meanthick<<<(NB * NHW * 8) / 256, blk, 0, stream>>>(su, thick_w, thick_b, sm, thick);
  k_edge_px<<<(NB * NHW * 8) / 256, blk, 0, stream>>>(sm, wc + 80128, edgeT);
  k_off_g<<<(NB * NHW) / 64, blk, 0, stream>>>(edgeT, wc + 80704, off_b, thick, offb);
  k_deform<<<NB * 64, blk, 0, stream>>>(su, offb, wbf, deform_b, edgeT, dbufT);
  k_down_g<<<(NB * NHW) / 64, blk, 0, stream>>>(x2T, dbufT, wc + 24576, down_b, ebufT);
  k_ln<<<(NB * NHW * 4) / 256, blk, 0, stream>>>(ebufT, ln_g, ln_b, hnT);
  k_mlp1_g<<<(NB * NHW) / 64, blk, 0, stream>>>(hnT, wc + 8192, mlp1_b, h1T);
  k_dw<<<(NB * NHW * 32) / 256, blk, 0, stream>>>(h1T, wc + 77824, dw_b, h2T);
  k_mlp2_g<<<(NB * NHW) / 64, blk, 0, stream>>>(h2T, wc + 45056, mlp2_b, ebufT, tbufT);
  k_up_g<<<(NB * NHW) / 64, blk, 0, stream>>>(tbufT, wc + 61440, up_b, (float*)d_out);
}

// Round 14
// 283.895 us; speedup vs baseline: 1.3019x; 1.0295x over previous
//
#include <hip/hip_runtime.h>
#include <hip/hip_bf16.h>
#include <math.h>

#define NB 4
#define NHW 4096
#define NBN (NB * NHW)
#define KSPLIT 4

typedef const float* fp;
typedef unsigned short us;
typedef __attribute__((ext_vector_type(8))) short short8;
typedef __attribute__((ext_vector_type(4))) short short4v;
typedef __attribute__((ext_vector_type(4))) float floatx4;
typedef __attribute__((ext_vector_type(2))) unsigned int uint2v;
typedef __attribute__((ext_vector_type(4))) unsigned int uint4v;

__device__ __forceinline__ float b2f(__hip_bfloat16 v) { return __bfloat162float(v); }
__device__ __forceinline__ __hip_bfloat16 f2b(float v) { return __float2bfloat16(v); }
__device__ __forceinline__ us f2bu(float f) {
  __hip_bfloat16 h = __float2bfloat16(f);
  return *reinterpret_cast<us*>(&h);
}
__device__ __forceinline__ float bu2f(us u) {
  __hip_bfloat16 h = *reinterpret_cast<__hip_bfloat16*>(&u);
  return __bfloat162float(h);
}
__device__ __forceinline__ float gelu_ex(float x) { return 0.5f * x * (1.0f + erff(x * 0.70710678118654752f)); }
__device__ __forceinline__ short8 ld8(const us* p) { return *(const short8*)p; }

// packed f32x2 -> bf16x2 (RNE), single instruction (T12; no builtin on gfx950)
__device__ __forceinline__ unsigned cvt_pk_bf16(float lo, float hi) {
  unsigned r;
  asm("v_cvt_pk_bf16_f32 %0, %1, %2" : "=v"(r) : "v"(lo), "v"(hi));
  return r;
}
// cross-quad reductions via permlane swaps (VALU-speed, no LDS/bpermute latency)
__device__ __forceinline__ float qmax4(float v) {
  uint2v p = __builtin_amdgcn_permlane16_swap(__float_as_uint(v), __float_as_uint(v), false, false);
  v = fmaxf(__uint_as_float(p.x), __uint_as_float(p.y));
  p = __builtin_amdgcn_permlane32_swap(__float_as_uint(v), __float_as_uint(v), false, false);
  return fmaxf(__uint_as_float(p.x), __uint_as_float(p.y));
}
__device__ __forceinline__ float qsum4(float v) {
  uint2v p = __builtin_amdgcn_permlane16_swap(__float_as_uint(v), __float_as_uint(v), false, false);
  v = __uint_as_float(p.x) + __uint_as_float(p.y);
  p = __builtin_amdgcn_permlane32_swap(__float_as_uint(v), __float_as_uint(v), false, false);
  return __uint_as_float(p.x) + __uint_as_float(p.y);
}

// ---------------- 0. fused weight prep: wq (24576) | wc (99136) | wbf (36864), one launch
__global__ __launch_bounds__(256) void k_wall(fp qw, fp pw, fp m1w, fp dnw, fp m2w, fp uw,
                                              fp dww, fp ew, fp ow, fp dfw,
                                              us* wq, us* wc, us* wbf) {
  int i = blockIdx.x * 256 + threadIdx.x;
  if (i < 24576) { wq[i] = f2bu(qw[i]); return; }
  i -= 24576;
  if (i < 99136) {
    float v;
    if (i < 8192) v = pw[i];
    else if (i < 24576) v = m1w[i - 8192];
    else if (i < 45056) v = dnw[i - 24576];
    else if (i < 61440) v = m2w[i - 45056];
    else if (i < 77824) v = uw[i - 61440];
    else if (i < 80128) {
      int i2 = i - 77824;           // dwT: tap = i2>>8, ch = i2&255
      v = dww[(i2 & 255) * 9 + (i2 >> 8)];
    } else if (i < 80704) {
      int i2 = i - 80128;           // ewT: tap = i2>>6, oc = i2&63
      v = ew[(i2 & 63) * 9 + (i2 >> 6)];
    } else {
      int i2 = i - 80704;           // woff[oc][tap*64+c], oc padded to 32
      int oc = i2 / 576, rem = i2 % 576;
      int tap = rem >> 6, c = rem & 63;
      v = (oc < 18) ? ow[(oc * 64 + c) * 9 + tap] : 0.f;
    }
    wc[i] = f2bu(v);
    return;
  }
  i -= 99136;
  if (i >= 9 * 64 * 64) return;
  int c = i & 63, oc = (i >> 6) & 63, k = i >> 12;
  wbf[i] = f2bu(dfw[(oc * 64 + c) * 9 + k]);
}

// ---------------- 1. bilinear upsample -> su f32 (r8 verbatim)
__global__ __launch_bounds__(256) void k_upsample(fp skip, float* su) {
  int idx = blockIdx.x * 256 + threadIdx.x;
  if (idx >= NB * 64 * NHW) return;
  int hw = idx & 4095, bc = idx >> 12;
  int y = hw >> 6, x = hw & 63;
  float fy = 0.5f * y - 0.25f, fx = 0.5f * x - 0.25f;
  float y0f = floorf(fy), x0f = floorf(fx);
  float wy = fy - y0f, wx = fx - x0f;
  int y0 = (int)y0f, x0 = (int)x0f;
  int y0c = min(31, max(0, y0)), y1c = min(31, max(0, y0 + 1));
  int x0c = min(31, max(0, x0)), x1c = min(31, max(0, x0 + 1));
  const float* p = skip + (size_t)bc * 1024;
  float v00 = p[y0c * 32 + x0c], v01 = p[y0c * 32 + x1c];
  float v10 = p[y1c * 32 + x0c], v11 = p[y1c * 32 + x1c];
  su[idx] = (1.f - wy) * ((1.f - wx) * v00 + wx * v01) + wy * ((1.f - wx) * v10 + wx * v11);
}

// ---------------- 2. transpose x f32 -> xT bf16 [b*4096][256] (r8 verbatim)
__global__ __launch_bounds__(256) void k_xpose(fp x, us* xT) {
  __shared__ float tile[64][65];
  int bid = blockIdx.x;
  int pt = bid & 63, ct = (bid >> 6) & 3, b = bid >> 8;
  int px0 = pt * 64, c0 = ct * 64;
  int tx = threadIdx.x & 63, ty = threadIdx.x >> 6;
  const float* src = x + ((size_t)(b * 256 + c0)) * NHW + px0;
#pragma unroll
  for (int i = 0; i < 16; i++) {
    int r = i * 4 + ty;
    tile[r][tx] = src[(size_t)r * NHW + tx];
  }
  __syncthreads();
  int cseg = threadIdx.x & 7, p0 = threadIdx.x >> 3;
#pragma unroll
  for (int h = 0; h < 2; h++) {
    int p = p0 + h * 32;
    short8 v;
#pragma unroll
    for (int j = 0; j < 8; j++) v[j] = (short)f2bu(tile[cseg * 8 + j][p]);
    *(short8*)&xT[((size_t)(b * NHW) + px0 + p) * 256 + c0 + cseg * 8] = v;
  }
}

// ---------------- 3. qkv GEMM, N-SPLIT x3 (seg 0:Q 1:K 2:V) -> grid 768, 3-4 waves/SIMD.
// Q ch-major bf16 [b][32][N]; K px-major kpx[b*N][32]; V blocked vblk.
// Q scale folds 1/sqrt(32) * log2(e) so attention runs in exp2 domain.
__global__ __launch_bounds__(256) void k_qkv_g(const us* xT, const us* wq, fp bias, us* qkvb, us* kpx, us* vblk) {
  int wave = threadIdx.x >> 6, lane = threadIdx.x & 63;
  int quad = lane >> 4, l16 = lane & 15;
  int seg = blockIdx.x >> 8;                      // 0:Q 1:K 2:V
  int pxg0 = (blockIdx.x & 255) * 64 + wave * 16;
  int b = pxg0 >> 12, hw0 = pxg0 & 4095;
  floatx4 acc[2];
  acc[0] = (floatx4){0.f, 0.f, 0.f, 0.f};
  acc[1] = (floatx4){0.f, 0.f, 0.f, 0.f};
  const us* xrow = xT + (size_t)(pxg0 + l16) * 256 + quad * 8;
  const us* wseg = wq + (size_t)(seg * 32) * 256;
#pragma unroll
  for (int k0 = 0; k0 < 256; k0 += 32) {
    short8 bf = ld8(xrow + k0);
#pragma unroll
    for (int j = 0; j < 2; j++) {
      short8 af = ld8(wseg + (size_t)(j * 16 + l16) * 256 + k0 + quad * 8);
      acc[j] = __builtin_amdgcn_mfma_f32_16x16x32_bf16(af, bf, acc[j], 0, 0, 0);
    }
  }
  if (seg == 0) {
#pragma unroll
    for (int j = 0; j < 2; j++)
#pragma unroll
      for (int r = 0; r < 4; r++) {
        int oc = j * 16 + quad * 4 + r;
        float v = (acc[j][r] + bias[oc]) * 0.25503485f;   // (1/sqrt(32)) * log2(e)
        qkvb[(size_t)(b * 32 + oc) * NHW + hw0 + l16] = f2bu(v);
      }
  } else if (seg == 1) {
#pragma unroll
    for (int j = 0; j < 2; j++) {
      short4v pkv;
#pragma unroll
      for (int r = 0; r < 4; r++)
        pkv[r] = (short)f2bu(acc[j][r] + bias[32 + j * 16 + quad * 4 + r]);
      *(short4v*)&kpx[((size_t)(b * NHW) + hw0 + l16) * 32 + j * 16 + quad * 4] = pkv;
    }
  } else {
    int key = hw0 + l16;
    size_t base = ((size_t)(b * NHW + key) >> 5) * 1024 + (size_t)(key & 31);
#pragma unroll
    for (int j = 0; j < 2; j++)
#pragma unroll
      for (int r = 0; r < 4; r++) {
        int ch = j * 16 + quad * 4 + r;
        vblk[base + (size_t)ch * 32] = f2bu(acc[j][r] + bias[64 + ch]);
      }
  }
}

// ---------------- 4. LDS-free flash attention, SPLIT-K x4, swapped QK^T (r6-proven).
__global__ __launch_bounds__(256, 4) void k_attn(const us* qkvb, const us* kpx, const us* vblk,
                                                 us* Opart, float* ml) {
  int tid = threadIdx.x;
  int wave = tid >> 6, lane = tid & 63;
  int quad = lane >> 4, l16 = lane & 15;
  int blk = blockIdx.x;
  int kh = blk & 3;
  int rest = blk >> 2;
  int b = rest >> 6;
  int qbase = (rest & 63) * 64 + wave * 16;
  const us* qp = qkvb + (size_t)b * 32 * NHW;
  const us* kb_base = kpx + (size_t)b * NHW * 32;

  short8 bq;
#pragma unroll
  for (int j = 0; j < 8; j++)
    bq[j] = (short)qp[(size_t)(quad * 8 + j) * NHW + qbase + l16];

  float m_r = -1e30f, l_r = 0.f;
  floatx4 o0 = {0.f, 0.f, 0.f, 0.f}, o1 = {0.f, 0.f, 0.f, 0.f};

  int kb0 = kh * 1024;
  short8 akf[8];
#pragma unroll
  for (int t = 0; t < 8; t++)
    akf[t] = ld8(kb_base + (size_t)(kb0 + t * 16 + l16) * 32 + quad * 8);

  for (int kb = kb0; kb < kb0 + 1024; kb += 128) {
    floatx4 sT[8];
    __builtin_amdgcn_s_setprio(1);
#pragma unroll
    for (int t = 0; t < 8; t++) {
      floatx4 z = {0.f, 0.f, 0.f, 0.f};
      sT[t] = __builtin_amdgcn_mfma_f32_16x16x32_bf16(akf[t], bq, z, 0, 0, 0);
    }
    __builtin_amdgcn_s_setprio(0);

    int kbn = (kb + 128 < kb0 + 1024) ? kb + 128 : kb0;
#pragma unroll
    for (int t = 0; t < 8; t++)
      akf[t] = ld8(kb_base + (size_t)(kbn + t * 16 + l16) * 32 + quad * 8);

    float tm[8];
#pragma unroll
    for (int t = 0; t < 8; t++)
      tm[t] = fmaxf(fmaxf(fmaxf(sT[t][0], sT[t][1]), sT[t][2]), sT[t][3]);
    float mx = fmaxf(fmaxf(fmaxf(tm[0], tm[1]), tm[2]), tm[3]);
    mx = fmaxf(fmaxf(fmaxf(fmaxf(mx, tm[4]), tm[5]), tm[6]), tm[7]);
    mx = qmax4(mx);
    float mnew = fmaxf(m_r, mx);
    float alpha = exp2f(m_r - mnew);
    m_r = mnew;

    float rs0 = 0.f, rs1 = 0.f;
    unsigned pkw[8][2];
#pragma unroll
    for (int t = 0; t < 8; t++) {
      float p0 = exp2f(sT[t][0] - mnew);
      float p1 = exp2f(sT[t][1] - mnew);
      float p2 = exp2f(sT[t][2] - mnew);
      float p3 = exp2f(sT[t][3] - mnew);
      rs0 += p0 + p1;
      rs1 += p2 + p3;
      pkw[t][0] = cvt_pk_bf16(p0, p1);
      pkw[t][1] = cvt_pk_bf16(p2, p3);
    }
    float rs = qsum4(rs0 + rs1);
    l_r = l_r * alpha + rs;
#pragma unroll
    for (int r = 0; r < 4; r++) { o0[r] *= alpha; o1[r] *= alpha; }

    __builtin_amdgcn_s_setprio(1);
#pragma unroll
    for (int cc = 0; cc < 4; cc++) {
      uint2v t1 = __builtin_amdgcn_permlane32_swap(pkw[2 * cc][0], pkw[2 * cc + 1][0], false, false);
      uint2v t2 = __builtin_amdgcn_permlane16_swap(t1.x, t1.y, false, false);
      uint2v t3 = __builtin_amdgcn_permlane32_swap(pkw[2 * cc][1], pkw[2 * cc + 1][1], false, false);
      uint2v t4 = __builtin_amdgcn_permlane16_swap(t3.x, t3.y, false, false);
      uint4v pw = {t2.x, t4.x, t2.y, t4.y};
      short8 pa = *(short8*)&pw;
      const us* vb = vblk + ((size_t)(b * NHW + kb + cc * 32) >> 5) * 1024 + quad * 8;
      short8 av0 = ld8(vb + (size_t)l16 * 32);
      short8 av1 = ld8(vb + (size_t)(l16 + 16) * 32);
      o0 = __builtin_amdgcn_mfma_f32_16x16x32_bf16(av0, pa, o0, 0, 0, 0);
      o1 = __builtin_amdgcn_mfma_f32_16x16x32_bf16(av1, pa, o1, 0, 0, 0);
    }
    __builtin_amdgcn_s_setprio(0);
  }

  int q = qbase + l16;
  size_t qg = (size_t)b * NHW + q;
  us* dst = Opart + ((size_t)kh * NBN + qg) * 32;
  short4v e0, e1;
#pragma unroll
  for (int r = 0; r < 4; r++) { e0[r] = (short)f2bu(o0[r]); e1[r] = (short)f2bu(o1[r]); }
  *(short4v*)(dst + quad * 4) = e0;
  *(short4v*)(dst + 16 + quad * 4) = e1;
  if (quad == 0) {
    ml[(size_t)kh * NBN + qg] = m_r;
    ml[(size_t)KSPLIT * NBN + (size_t)kh * NBN + qg] = l_r;
  }
}

// ---------------- 4b. merge 4 split-K partials -> avb px-major bf16 (exp2 domain)
__global__ __launch_bounds__(256) void k_merge(const us* Opart, const float* ml, us* avb) {
  int idx = blockIdx.x * 256 + threadIdx.x;
  int ch = idx & 31, qg = idx >> 5;
  float mk[KSPLIT];
  float m = -1e30f;
#pragma unroll
  for (int kh = 0; kh < KSPLIT; kh++) { mk[kh] = ml[kh * NBN + qg]; m = fmaxf(m, mk[kh]); }
  float l = 0.f, v = 0.f;
#pragma unroll
  for (int kh = 0; kh < KSPLIT; kh++) {
    float a = exp2f(mk[kh] - m);
    l += ml[KSPLIT * NBN + kh * NBN + qg] * a;
    v += bu2f(Opart[((size_t)(kh * NBN) + qg) * 32 + ch]) * a;
  }
  avb[idx] = f2bu(v / l);
}

// ---------------- 5. proj GEMM, N-SPLIT x4 -> grid 1024
__global__ __launch_bounds__(256) void k_proj_g(const us* avb, const us* xT, const us* wpj, fp bias, us* x2T) {
  int wave = threadIdx.x >> 6, lane = threadIdx.x & 63;
  int quad = lane >> 4, l16 = lane & 15;
  int seg = blockIdx.x >> 8;
  int pxg0 = (blockIdx.x & 255) * 64 + wave * 16;
  short8 act = ld8(avb + (size_t)(pxg0 + l16) * 32 + quad * 8);
  floatx4 acc[4];
#pragma unroll
  for (int jn = 0; jn < 4; jn++) {
    int n = seg * 4 + jn;
    short8 wf = ld8(wpj + (size_t)(n * 16 + l16) * 32 + quad * 8);
    floatx4 z = {0.f, 0.f, 0.f, 0.f};
    acc[jn] = __builtin_amdgcn_mfma_f32_16x16x32_bf16(act, wf, z, 0, 0, 0);
  }
#pragma unroll
  for (int jn = 0; jn < 4; jn++)
#pragma unroll
    for (int r = 0; r < 4; r++) {
      int px = pxg0 + quad * 4 + r;
      int oc = (seg * 4 + jn) * 16 + l16;
      size_t oidx = (size_t)px * 256 + oc;
      x2T[oidx] = f2bu(acc[jn][r] + bias[oc] + bu2f(xT[oidx]));
    }
}

// ---------------- 6. channel mean + thick: 8 lanes/px + shfl reduce (512 blocks)
__global__ __launch_bounds__(256) void k_meanthick(const float* su, fp tw, fp tb, float* sm, float* thick) {
  int idx = blockIdx.x * 256 + threadIdx.x;   // NB*NHW*8
  int l8 = idx & 7, pxg = idx >> 3;
  int hw = pxg & 4095, b = pxg >> 12;
  const float* p = su + ((size_t)(b * 64 + l8 * 8)) * NHW + hw;
  float s = 0.f, ts = 0.f;
#pragma unroll
  for (int c = 0; c < 8; c++) {
    float v = p[(size_t)c * NHW];
    s += v;
    ts += v * tw[l8 * 8 + c];
  }
  s += __shfl_xor(s, 1); ts += __shfl_xor(ts, 1);
  s += __shfl_xor(s, 2); ts += __shfl_xor(ts, 2);
  s += __shfl_xor(s, 4); ts += __shfl_xor(ts, 4);
  if (l8 == 0) {
    sm[pxg] = s * (1.f / 64.f);
    thick[pxg] = 1.f / (1.f + __expf(-(ts + tb[0])));
  }
}

// ---------------- 7. edge conv 3x3 px-major: thread=(px, 8-oc block) -> edgeT bf16 [b*N][64]
__global__ __launch_bounds__(256) void k_edge_px(const float* sm, const us* ewT, us* edgeT) {
  int idx = blockIdx.x * 256 + threadIdx.x;   // NB*NHW*8
  int cb = idx & 7, pxg = idx >> 3;
  int b = pxg >> 12, hw = pxg & 4095;
  int y = hw >> 6, x = hw & 63;
  int c0 = cb * 8;
  float acc[8] = {0.f, 0.f, 0.f, 0.f, 0.f, 0.f, 0.f, 0.f};
#pragma unroll
  for (int ky = 0; ky < 3; ky++) {
#pragma unroll
    for (int kx = 0; kx < 3; kx++) {
      int yy = y + ky - 1, xx = x + kx - 1;
      if (yy >= 0 && yy < 64 && xx >= 0 && xx < 64) {
        float sv = sm[b * NHW + yy * 64 + xx];
        short8 wv = ld8(ewT + (ky * 3 + kx) * 64 + c0);
#pragma unroll
        for (int j = 0; j < 8; j++) acc[j] += sv * bu2f((us)wv[j]);
      }
    }
  }
  short8 pk;
#pragma unroll
  for (int j = 0; j < 8; j++) pk[j] = (short)f2bu(acc[j]);
  *(short8*)(edgeT + (size_t)pxg * 64 + c0) = pk;
}

// ---------------- 8. offset conv as MFMA GEMM: K=9x64, N=32(18 used), act=shifted edgeT rows
__global__ __launch_bounds__(256) void k_off_g(const us* edgeT, const us* woff, fp ob,
                                               const float* thick, float* offb) {
  int wave = threadIdx.x >> 6, lane = threadIdx.x & 63;
  int quad = lane >> 4, l16 = lane & 15;
  int pxg0 = blockIdx.x * 64 + wave * 16;
  int b = pxg0 >> 12;
  int pxl = pxg0 + l16;
  int hwl = pxl & 4095;
  int yl = hwl >> 6, xl = hwl & 63;
  floatx4 acc[2];
  acc[0] = (floatx4){0.f, 0.f, 0.f, 0.f};
  acc[1] = (floatx4){0.f, 0.f, 0.f, 0.f};
  const short8 zz = {0, 0, 0, 0, 0, 0, 0, 0};
#pragma unroll
  for (int t = 0; t < 9; t++) {
    int yy = yl + t / 3 - 1, xx = xl + t % 3 - 1;
    bool valid = (yy >= 0 && yy < 64 && xx >= 0 && xx < 64);
    const us* arow = edgeT + ((size_t)(b * NHW + yy * 64 + xx)) * 64;
#pragma unroll
    for (int s = 0; s < 2; s++) {
      short8 act = valid ? ld8(arow + s * 32 + quad * 8) : zz;
      int kk = t * 64 + s * 32 + quad * 8;
#pragma unroll
      for (int n = 0; n < 2; n++) {
        short8 wf = ld8(woff + (size_t)(n * 16 + l16) * 576 + kk);
        acc[n] = __builtin_amdgcn_mfma_f32_16x16x32_bf16(act, wf, acc[n], 0, 0, 0);
      }
    }
  }
#pragma unroll
  for (int n = 0; n < 2; n++)
#pragma unroll
    for (int r = 0; r < 4; r++) {
      int oc = n * 16 + l16;
      if (oc < 18) {
        int px = pxg0 + quad * 4 + r;
        int hw = px & 4095;
        float v = (acc[n][r] + ob[oc]) * (1.f + 16.f * thick[px]);
        offb[(size_t)(b * 18 + oc) * NHW + hw] = v;
      }
    }
}

// ---------------- 9. MFMA deformable conv (r10 structure; edge residual from edgeT rows)
__global__ __launch_bounds__(256) void k_deform(const float* su, const float* offb,
                                                const us* wbf, fp db,
                                                const us* edgeT, us* dbufT) {
  __shared__ __align__(16) us samT[4][16][72];
  int tid = threadIdx.x;
  int wave = tid >> 6, lane = tid & 63;
  int quad = lane >> 4, l16 = lane & 15;
  int b = blockIdx.x >> 6, row = blockIdx.x & 63;
  const float* sub = su + (size_t)b * 64 * NHW;

  int sp = lane & 15, sq = lane >> 4;
  int hw_s = row * 64 + wave * 16 + sp;
  int x_s = wave * 16 + sp;

  floatx4 acc[4];
#pragma unroll
  for (int a = 0; a < 4; a++) acc[a] = (floatx4){0.f, 0.f, 0.f, 0.f};

  for (int k = 0; k < 9; k++) {
    float dy = offb[((size_t)(b * 18 + 2 * k)) * NHW + hw_s];
    float dx = offb[((size_t)(b * 18 + 2 * k + 1)) * NHW + hw_s];
    float py = (float)(row + k / 3 - 1) + dy;
    float pxf = (float)(x_s + k % 3 - 1) + dx;
    float y0f = floorf(py), x0f = floorf(pxf);
    float wy = py - y0f, wx = pxf - x0f;
    int y0 = (int)y0f, x0 = (int)x0f;
    int y1 = y0 + 1, x1 = x0 + 1;
    float vy0 = (y0 >= 0 && y0 < 64) ? 1.f : 0.f;
    float vy1 = (y1 >= 0 && y1 < 64) ? 1.f : 0.f;
    float vx0 = (x0 >= 0 && x0 < 64) ? 1.f : 0.f;
    float vx1 = (x1 >= 0 && x1 < 64) ? 1.f : 0.f;
    float w00 = (1.f - wy) * (1.f - wx) * vy0 * vx0;
    float w01 = (1.f - wy) * wx * vy0 * vx1;
    float w10 = wy * (1.f - wx) * vy1 * vx0;
    float w11 = wy * wx * vy1 * vx1;
    int y0c = min(63, max(0, y0)), y1c = min(63, max(0, y1));
    int x0c = min(63, max(0, x0)), x1c = min(63, max(0, x1));
    int i00 = y0c * 64 + x0c, i01 = y0c * 64 + x1c;
    int i10 = y1c * 64 + x0c, i11 = y1c * 64 + x1c;

#pragma unroll
    for (int i = 0; i < 16; i += 2) {
      int c0 = sq * 16 + i;
      const float* s0 = sub + (size_t)c0 * NHW;
      const float* s1 = s0 + NHW;
      float v0 = w00 * s0[i00] + w01 * s0[i01] + w10 * s0[i10] + w11 * s0[i11];
      float v1 = w00 * s1[i00] + w01 * s1[i01] + w10 * s1[i10] + w11 * s1[i11];
      unsigned int pk = (unsigned int)f2bu(v0) | ((unsigned int)f2bu(v1) << 16);
      *(unsigned int*)&samT[wave][sp][c0] = pk;
    }

#pragma unroll
    for (int s = 0; s < 2; s++) {
      short8 bfrag = *(const short8*)&samT[wave][l16][s * 32 + quad * 8];
#pragma unroll
      for (int a = 0; a < 4; a++) {
        short8 afrag = ld8(wbf + ((size_t)(k * 64 + a * 16 + l16) * 64 + s * 32 + quad * 8));
        acc[a] = __builtin_amdgcn_mfma_f32_16x16x32_bf16(bfrag, afrag, acc[a], 0, 0, 0);
      }
    }
  }

#pragma unroll
  for (int a = 0; a < 4; a++)
#pragma unroll
    for (int r = 0; r < 4; r++) {
      int oc = a * 16 + l16;
      int pxr = row * 64 + wave * 16 + quad * 4 + r;
      size_t rowi = (size_t)(b * NHW) + pxr;
      float v = acc[a][r] + db[oc] + bu2f(edgeT[rowi * 64 + oc]);
      dbufT[rowi * 64 + oc] = f2bu(v);
    }
}

// ---------------- 10. down GEMM, N-SPLIT x4 (1 m-block each) -> grid 1024
__global__ __launch_bounds__(256) void k_down_g(const us* x2T, const us* dbufT, const us* wd, fp bias, float* ebufT) {
  int wave = threadIdx.x >> 6, lane = threadIdx.x & 63;
  int quad = lane >> 4, l16 = lane & 15;
  int seg = blockIdx.x >> 8;
  int pxg0 = (blockIdx.x & 255) * 64 + wave * 16;
  floatx4 acc = {0.f, 0.f, 0.f, 0.f};
  const us* xrow = x2T + (size_t)(pxg0 + l16) * 256 + quad * 8;
  const us* wrow = wd + (size_t)(seg * 16 + l16) * 320 + quad * 8;
#pragma unroll
  for (int k0 = 0; k0 < 256; k0 += 32) {
    short8 act = ld8(xrow + k0);
    short8 wf = ld8(wrow + k0);
    acc = __builtin_amdgcn_mfma_f32_16x16x32_bf16(act, wf, acc, 0, 0, 0);
  }
  const us* drow = dbufT + (size_t)(pxg0 + l16) * 64 + quad * 8;
#pragma unroll
  for (int k0 = 0; k0 < 64; k0 += 32) {
    short8 act = ld8(drow + k0);
    short8 wf = ld8(wrow + 256 + k0);
    acc = __builtin_amdgcn_mfma_f32_16x16x32_bf16(act, wf, acc, 0, 0, 0);
  }
  int oc = seg * 16 + l16;
#pragma unroll
  for (int r = 0; r < 4; r++) {
    int px = pxg0 + quad * 4 + r;
    ebufT[(size_t)px * 64 + oc] = acc[r] + bias[oc];
  }
}

// ---------------- 11. LayerNorm px-major: 8 lanes/px + shfl reduce (512 blocks)
__global__ __launch_bounds__(256) void k_ln(const float* eT, fp g, fp bt, us* hnT) {
  int idx = blockIdx.x * 256 + threadIdx.x;   // NB*NHW*8
  int l8 = idx & 7, px = idx >> 3;
  const float* p = eT + (size_t)px * 64 + l8 * 8;
  float v[8];
  float s = 0.f;
#pragma unroll
  for (int i = 0; i < 2; i++) {
    float4 t = ((const float4*)p)[i];
    v[i * 4] = t.x; v[i * 4 + 1] = t.y; v[i * 4 + 2] = t.z; v[i * 4 + 3] = t.w;
    s += t.x + t.y + t.z + t.w;
  }
  s += __shfl_xor(s, 1);
  s += __shfl_xor(s, 2);
  s += __shfl_xor(s, 4);
  float mu = s * (1.f / 64.f);
  float q = 0.f;
#pragma unroll
  for (int c = 0; c < 8; c++) { float d = v[c] - mu; q += d * d; }
  q += __shfl_xor(q, 1);
  q += __shfl_xor(q, 2);
  q += __shfl_xor(q, 4);
  float rstd = rsqrtf(q * (1.f / 64.f) + 1e-5f);
  short8 pk;
#pragma unroll
  for (int t = 0; t < 8; t++)
    pk[t] = (short)f2bu((v[t] - mu) * rstd * g[l8 * 8 + t] + bt[l8 * 8 + t]);
  *(short8*)(hnT + (size_t)px * 64 + l8 * 8) = pk;
}

// ---------------- 12. mlp1 GEMM, N-SPLIT x4 (4 m-blocks each) -> grid 1024
__global__ __launch_bounds__(256) void k_mlp1_g(const us* hnT, const us* wm1, fp bias, us* h1T) {
  int wave = threadIdx.x >> 6, lane = threadIdx.x & 63;
  int quad = lane >> 4, l16 = lane & 15;
  int seg = blockIdx.x >> 8;
  int pxg0 = (blockIdx.x & 255) * 64 + wave * 16;
  floatx4 acc[4];
#pragma unroll
  for (int j = 0; j < 4; j++) acc[j] = (floatx4){0.f, 0.f, 0.f, 0.f};
  const us* hrow = hnT + (size_t)(pxg0 + l16) * 64 + quad * 8;
#pragma unroll
  for (int k0 = 0; k0 < 64; k0 += 32) {
    short8 act = ld8(hrow + k0);
#pragma unroll
    for (int j = 0; j < 4; j++) {
      int m = seg * 4 + j;
      short8 wf = ld8(wm1 + (size_t)(m * 16 + l16) * 64 + k0 + quad * 8);
      acc[j] = __builtin_amdgcn_mfma_f32_16x16x32_bf16(act, wf, acc[j], 0, 0, 0);
    }
  }
#pragma unroll
  for (int j = 0; j < 4; j++)
#pragma unroll
    for (int r = 0; r < 4; r++) {
      int px = pxg0 + quad * 4 + r;
      int oc = (seg * 4 + j) * 16 + l16;
      h1T[(size_t)px * 256 + oc] = f2bu(gelu_ex(acc[j][r] + bias[oc]));
    }
}

// ---------------- 13. depthwise 3x3 + GELU, px-major (r12 verbatim)
__global__ __launch_bounds__(256) void k_dw(const us* h1T, const us* wdwT, fp bias, us* h2T) {
  int idx = blockIdx.x * 256 + threadIdx.x;   // NB*NHW*32
  int cb = idx & 31, pxg = idx >> 5;
  int b = pxg >> 12, hw = pxg & 4095;
  int y = hw >> 6, x = hw & 63;
  int c0 = cb * 8;
  float4 b0 = *(const float4*)(bias + c0);
  float4 b1 = *(const float4*)(bias + c0 + 4);
  float acc[8] = {b0.x, b0.y, b0.z, b0.w, b1.x, b1.y, b1.z, b1.w};
#pragma unroll
  for (int ky = 0; ky < 3; ky++) {
#pragma unroll
    for (int kx = 0; kx < 3; kx++) {
      int tap = ky * 3 + kx;
      short8 wv = ld8(wdwT + tap * 256 + c0);
      int yy = y + ky - 1, xx = x + kx - 1;
      if (yy >= 0 && yy < 64 && xx >= 0 && xx < 64) {
        short8 vv = ld8(h1T + ((size_t)(b * NHW + yy * 64 + xx)) * 256 + c0);
#pragma unroll
        for (int j = 0; j < 8; j++)
          acc[j] += bu2f((us)vv[j]) * bu2f((us)wv[j]);
      }
    }
  }
  short8 pk;
#pragma unroll
  for (int j = 0; j < 8; j++) pk[j] = (short)f2bu(gelu_ex(acc[j]));
  *(short8*)(h2T + (size_t)pxg * 256 + c0) = pk;
}

// ---------------- 14. mlp2 GEMM, N-SPLIT x4 (1 m-block each) -> grid 1024
__global__ __launch_bounds__(256) void k_mlp2_g(const us* h2T, const us* wm2, fp bias, const float* ebufT, us* tbufT) {
  int wave = threadIdx.x >> 6, lane = threadIdx.x & 63;
  int quad = lane >> 4, l16 = lane & 15;
  int seg = blockIdx.x >> 8;
  int pxg0 = (blockIdx.x & 255) * 64 + wave * 16;
  floatx4 acc = {0.f, 0.f, 0.f, 0.f};
  const us* hrow = h2T + (size_t)(pxg0 + l16) * 256 + quad * 8;
  const us* wrow = wm2 + (size_t)(seg * 16 + l16) * 256 + quad * 8;
#pragma unroll
  for (int k0 = 0; k0 < 256; k0 += 32) {
    short8 act = ld8(hrow + k0);
    short8 wf = ld8(wrow + k0);
    acc = __builtin_amdgcn_mfma_f32_16x16x32_bf16(act, wf, acc, 0, 0, 0);
  }
  int oc = seg * 16 + l16;
#pragma unroll
  for (int r = 0; r < 4; r++) {
    int px = pxg0 + quad * 4 + r;
    size_t oidx = (size_t)px * 64 + oc;
    tbufT[oidx] = f2bu(acc[r] + bias[oc] + ebufT[oidx]);
  }
}

// ---------------- 15. up GEMM, N-SPLIT x4 (4 m-blocks each) -> grid 1024
__global__ __launch_bounds__(256) void k_up_g(const us* tbufT, const us* wu, fp bias, float* out) {
  int wave = threadIdx.x >> 6, lane = threadIdx.x & 63;
  int quad = lane >> 4, l16 = lane & 15;
  int seg = blockIdx.x >> 8;
  int pxg0 = (blockIdx.x & 255) * 64 + wave * 16;
  int b = pxg0 >> 12, hw0 = pxg0 & 4095;
  floatx4 acc[4];
#pragma unroll
  for (int j = 0; j < 4; j++) acc[j] = (floatx4){0.f, 0.f, 0.f, 0.f};
  const us* trow = tbufT + (size_t)(pxg0 + l16) * 64 + quad * 8;
#pragma unroll
  for (int k0 = 0; k0 < 64; k0 += 32) {
    short8 bf = ld8(trow + k0);
#pragma unroll
    for (int j = 0; j < 4; j++) {
      int m = seg * 4 + j;
      short8 af = ld8(wu + (size_t)(m * 16 + l16) * 64 + k0 + quad * 8);
      acc[j] = __builtin_amdgcn_mfma_f32_16x16x32_bf16(af, bf, acc[j], 0, 0, 0);
    }
  }
#pragma unroll
  for (int j = 0; j < 4; j++)
#pragma unroll
    for (int r = 0; r < 4; r++) {
      int oc = (seg * 4 + j) * 16 + quad * 4 + r;
      out[(size_t)(b * 256 + oc) * NHW + hw0 + l16] = acc[j][r] + bias[oc];
    }
}

extern "C" void kernel_launch(void* const* d_in, const int* in_sizes, int n_in,
                              void* d_out, int out_size, void* d_ws, size_t ws_size,
                              hipStream_t stream) {
  fp x = (fp)d_in[0], skip = (fp)d_in[1], qkv_w = (fp)d_in[2], qkv_b = (fp)d_in[3],
     proj_w = (fp)d_in[4], proj_b = (fp)d_in[5], edge_w = (fp)d_in[6], thick_w = (fp)d_in[7],
     thick_b = (fp)d_in[8], off_w = (fp)d_in[9], off_b = (fp)d_in[10], deform_w = (fp)d_in[11],
     deform_b = (fp)d_in[12], ln_g = (fp)d_in[13], ln_b = (fp)d_in[14], mlp1_w = (fp)d_in[15],
     mlp1_b = (fp)d_in[16], dw_w = (fp)d_in[17], dw_b = (fp)d_in[18], mlp2_w = (fp)d_in[19],
     mlp2_b = (fp)d_in[20], down_w = (fp)d_in[21], down_b = (fp)d_in[22], up_w = (fp)d_in[23],
     up_b = (fp)d_in[24];

  float* ws = (float*)d_ws;
  // ---- layout; wc 99,136 shorts; ml 2*4*NBN f32; kpx + vblk + wbf in free gap ----
  float* su    = ws + 0;              // f32 [0, 1048576)
  us* qkvb  = (us*)(ws + 1048576);    // bf16 Q-only [b][32][N] [1048576, 1835008)
  us* avb   = (us*)(ws + 1835008);    // bf16 524,288 elems [1835008, 2097152)
  us* wc    = (us*)(ws + 2097152);    // bf16 99,136 elems  [2097152, 2146720)
  float* ml = ws + 2146720;           // f32 2*4*NBN = 131,072  [2146720, 2277792)
  us* kpx   = (us*)(ws + 2277792);    // bf16 K px-major [b*N][32]: 524,288 elems [2277792, 2539936)
  us* vblk  = (us*)(ws + 2539936);    // bf16 V blocked [(b*N)/32][32ch][32key]: 524,288 elems [2539936, 2802080)
  us* wbf   = (us*)(ws + 2802080);    // bf16 deform W 36,864 elems [2802080, 2820512)
  us* x2T   = (us*)(ws + 3145728);    // bf16 px-major [b*N][256]: [3145728, 5242880)
  us* edgeT = (us*)(ws + 5242880);    // bf16 px-major [b*N][64]: 524,288 slots of 1M region
  float* offb  = ws + 6291456;        // f32 [6291456, 6586368)
  float* sm    = ws + 6586368;        // f32 (dead after k_edge_px)
  float* thick = ws + 6602752;        // f32 (dead after k_off_g)
  us* dbufT = (us*)(ws + 6619136);    // bf16 px-major [b*N][64]: [6619136, 7143424)
  float* ebufT = ws + 7143424;        // f32 px-major [b*N][64]: [7143424, 8192000)
  // aliases of dead/late regions:
  us* xT   = x2T;                     // xT live #3..#7; proj_g updates in-place
  us* wq   = dbufT;                   // wq written by k_wall, read by k_qkv_g; dbufT written later — disjoint
  us* Opart = (us*)ebufT;             // attn bf16 partials x4: 2,097,152 shorts = exact region
  us* hnT  = qkvb;                    // qkvb dead after k_attn
  us* h1T  = x2T;                     // x2T dead after k_down_g
  us* h2T  = (us*)ws;                 // [0, 2097152) slots all dead by k_dw
  us* tbufT = edgeT;                  // edgeT dead after k_deform

  dim3 blk(256);
  k_wall<<<628, blk, 0, stream>>>(qkv_w, proj_w, mlp1_w, down_w, mlp2_w, up_w,
                                  dw_w, edge_w, off_w, deform_w, wq, wc, wbf);
  k_upsample<<<(NB * 64 * NHW) / 256, blk, 0, stream>>>(skip, su);
  k_xpose<<<1024, blk, 0, stream>>>(x, xT);
  k_qkv_g<<<3 * 256, blk, 0, stream>>>(xT, wq, qkv_b, qkvb, kpx, vblk);
  k_attn<<<(NB * NHW / 64) * KSPLIT, blk, 0, stream>>>(qkvb, kpx, vblk, Opart, ml);
  k_merge<<<(NB * NHW * 32) / 256, blk, 0, stream>>>(Opart, ml, avb);
  k_proj_g<<<4 * 256, blk, 0, stream>>>(avb, xT, wc, proj_b, x2T);
  k_meanthick<<<(NB * NHW * 8) / 256, blk, 0, stream>>>(su, thick_w, thick_b, sm, thick);
  k_edge_px<<<(NB * NHW * 8) / 256, blk, 0, stream>>>(sm, wc + 80128, edgeT);
  k_off_g<<<(NB * NHW) / 64, blk, 0, stream>>>(edgeT, wc + 80704, off_b, thick, offb);
  k_deform<<<NB * 64, blk, 0, stream>>>(su, offb, wbf, deform_b, edgeT, dbufT);
  k_down_g<<<4 * 256, blk, 0, stream>>>(x2T, dbufT, wc + 24576, down_b, ebufT);
  k_ln<<<(NB * NHW * 8) / 256, blk, 0, stream>>>(ebufT, ln_g, ln_b, hnT);
  k_mlp1_g<<<4 * 256, blk, 0, stream>>>(hnT, wc + 8192, mlp1_b, h1T);
  k_dw<<<(NB * NHW * 32) / 256, blk, 0, stream>>>(h1T, wc + 77824, dw_b, h2T);
  k_mlp2_g<<<4 * 256, blk, 0, stream>>>(h2T, wc + 45056, mlp2_b, ebufT, tbufT);
  k_up_g<<<4 * 256, blk, 0, stream>>>(tbufT, wc + 61440, up_b, (float*)d_out);
}

// Round 23
// 280.386 us; speedup vs baseline: 1.3182x; 1.0125x over previous
//
#include <hip/hip_runtime.h>
#include <hip/hip_bf16.h>
#include <math.h>

#define NB 4
#define NHW 4096
#define NBN (NB * NHW)
#define KSPLIT 4

typedef const float* fp;
typedef unsigned short us;
typedef __attribute__((ext_vector_type(8))) short short8;
typedef __attribute__((ext_vector_type(4))) short short4v;
typedef __attribute__((ext_vector_type(4))) float floatx4;
typedef __attribute__((ext_vector_type(2))) unsigned int uint2v;
typedef __attribute__((ext_vector_type(4))) unsigned int uint4v;

__device__ __forceinline__ float b2f(__hip_bfloat16 v) { return __bfloat162float(v); }
__device__ __forceinline__ __hip_bfloat16 f2b(float v) { return __float2bfloat16(v); }
__device__ __forceinline__ us f2bu(float f) {
  __hip_bfloat16 h = __float2bfloat16(f);
  return *reinterpret_cast<us*>(&h);
}
__device__ __forceinline__ float bu2f(us u) {
  __hip_bfloat16 h = *reinterpret_cast<__hip_bfloat16*>(&u);
  return __bfloat162float(h);
}
__device__ __forceinline__ float gelu_ex(float x) { return 0.5f * x * (1.0f + erff(x * 0.70710678118654752f)); }
__device__ __forceinline__ short8 ld8(const us* p) { return *(const short8*)p; }

// packed f32x2 -> bf16x2 (RNE), single instruction (T12; no builtin on gfx950)
__device__ __forceinline__ unsigned cvt_pk_bf16(float lo, float hi) {
  unsigned r;
  asm("v_cvt_pk_bf16_f32 %0, %1, %2" : "=v"(r) : "v"(lo), "v"(hi));
  return r;
}
// cross-quad reductions via permlane swaps (VALU-speed, no LDS/bpermute latency)
__device__ __forceinline__ float qmax4(float v) {
  uint2v p = __builtin_amdgcn_permlane16_swap(__float_as_uint(v), __float_as_uint(v), false, false);
  v = fmaxf(__uint_as_float(p.x), __uint_as_float(p.y));
  p = __builtin_amdgcn_permlane32_swap(__float_as_uint(v), __float_as_uint(v), false, false);
  return fmaxf(__uint_as_float(p.x), __uint_as_float(p.y));
}
__device__ __forceinline__ float qsum4(float v) {
  uint2v p = __builtin_amdgcn_permlane16_swap(__float_as_uint(v), __float_as_uint(v), false, false);
  v = __uint_as_float(p.x) + __uint_as_float(p.y);
  p = __builtin_amdgcn_permlane32_swap(__float_as_uint(v), __float_as_uint(v), false, false);
  return __uint_as_float(p.x) + __uint_as_float(p.y);
}

// ---------------- 0. fused weight prep: wq (24576) | wc (99136) | wbf (36864), one launch
__global__ __launch_bounds__(256) void k_wall(fp qw, fp pw, fp m1w, fp dnw, fp m2w, fp uw,
                                              fp dww, fp ew, fp ow, fp dfw,
                                              us* wq, us* wc, us* wbf) {
  int i = blockIdx.x * 256 + threadIdx.x;
  if (i < 24576) { wq[i] = f2bu(qw[i]); return; }
  i -= 24576;
  if (i < 99136) {
    float v;
    if (i < 8192) v = pw[i];
    else if (i < 24576) v = m1w[i - 8192];
    else if (i < 45056) v = dnw[i - 24576];
    else if (i < 61440) v = m2w[i - 45056];
    else if (i < 77824) v = uw[i - 61440];
    else if (i < 80128) {
      int i2 = i - 77824;           // dwT: tap = i2>>8, ch = i2&255
      v = dww[(i2 & 255) * 9 + (i2 >> 8)];
    } else if (i < 80704) {
      int i2 = i - 80128;           // ewT: tap = i2>>6, oc = i2&63
      v = ew[(i2 & 63) * 9 + (i2 >> 6)];
    } else {
      int i2 = i - 80704;           // woff[oc][tap*64+c], oc padded to 32
      int oc = i2 / 576, rem = i2 % 576;
      int tap = rem >> 6, c = rem & 63;
      v = (oc < 18) ? ow[(oc * 64 + c) * 9 + tap] : 0.f;
    }
    wc[i] = f2bu(v);
    return;
  }
  i -= 99136;
  if (i >= 9 * 64 * 64) return;
  int c = i & 63, oc = (i >> 6) & 63, k = i >> 12;
  wbf[i] = f2bu(dfw[(oc * 64 + c) * 9 + k]);
}

// ---------------- 1. bilinear upsample -> su f32 (r8 verbatim)
__global__ __launch_bounds__(256) void k_upsample(fp skip, float* su) {
  int idx = blockIdx.x * 256 + threadIdx.x;
  if (idx >= NB * 64 * NHW) return;
  int hw = idx & 4095, bc = idx >> 12;
  int y = hw >> 6, x = hw & 63;
  float fy = 0.5f * y - 0.25f, fx = 0.5f * x - 0.25f;
  float y0f = floorf(fy), x0f = floorf(fx);
  float wy = fy - y0f, wx = fx - x0f;
  int y0 = (int)y0f, x0 = (int)x0f;
  int y0c = min(31, max(0, y0)), y1c = min(31, max(0, y0 + 1));
  int x0c = min(31, max(0, x0)), x1c = min(31, max(0, x0 + 1));
  const float* p = skip + (size_t)bc * 1024;
  float v00 = p[y0c * 32 + x0c], v01 = p[y0c * 32 + x1c];
  float v10 = p[y1c * 32 + x0c], v11 = p[y1c * 32 + x1c];
  su[idx] = (1.f - wy) * ((1.f - wx) * v00 + wx * v01) + wy * ((1.f - wx) * v10 + wx * v11);
}

// ---------------- 2. transpose x f32 -> xT bf16 [b*4096][256] (r8 verbatim)
__global__ __launch_bounds__(256) void k_xpose(fp x, us* xT) {
  __shared__ float tile[64][65];
  int bid = blockIdx.x;
  int pt = bid & 63, ct = (bid >> 6) & 3, b = bid >> 8;
  int px0 = pt * 64, c0 = ct * 64;
  int tx = threadIdx.x & 63, ty = threadIdx.x >> 6;
  const float* src = x + ((size_t)(b * 256 + c0)) * NHW + px0;
#pragma unroll
  for (int i = 0; i < 16; i++) {
    int r = i * 4 + ty;
    tile[r][tx] = src[(size_t)r * NHW + tx];
  }
  __syncthreads();
  int cseg = threadIdx.x & 7, p0 = threadIdx.x >> 3;
#pragma unroll
  for (int h = 0; h < 2; h++) {
    int p = p0 + h * 32;
    short8 v;
#pragma unroll
    for (int j = 0; j < 8; j++) v[j] = (short)f2bu(tile[cseg * 8 + j][p]);
    *(short8*)&xT[((size_t)(b * NHW) + px0 + p) * 256 + c0 + cseg * 8] = v;
  }
}

// ---------------- 3. qkv GEMM, N-SPLIT x3 (seg 0:Q 1:K 2:V) -> grid 768, 3-4 waves/SIMD.
// Q ch-major bf16 [b][32][N]; K px-major kpx[b*N][32]; V blocked vblk.
// Q scale folds 1/sqrt(32) * log2(e) so attention runs in exp2 domain.
__global__ __launch_bounds__(256) void k_qkv_g(const us* xT, const us* wq, fp bias, us* qkvb, us* kpx, us* vblk) {
  int wave = threadIdx.x >> 6, lane = threadIdx.x & 63;
  int quad = lane >> 4, l16 = lane & 15;
  int seg = blockIdx.x >> 8;                      // 0:Q 1:K 2:V
  int pxg0 = (blockIdx.x & 255) * 64 + wave * 16;
  int b = pxg0 >> 12, hw0 = pxg0 & 4095;
  floatx4 acc[2];
  acc[0] = (floatx4){0.f, 0.f, 0.f, 0.f};
  acc[1] = (floatx4){0.f, 0.f, 0.f, 0.f};
  const us* xrow = xT + (size_t)(pxg0 + l16) * 256 + quad * 8;
  const us* wseg = wq + (size_t)(seg * 32) * 256;
#pragma unroll
  for (int k0 = 0; k0 < 256; k0 += 32) {
    short8 bf = ld8(xrow + k0);
#pragma unroll
    for (int j = 0; j < 2; j++) {
      short8 af = ld8(wseg + (size_t)(j * 16 + l16) * 256 + k0 + quad * 8);
      acc[j] = __builtin_amdgcn_mfma_f32_16x16x32_bf16(af, bf, acc[j], 0, 0, 0);
    }
  }
  if (seg == 0) {
#pragma unroll
    for (int j = 0; j < 2; j++)
#pragma unroll
      for (int r = 0; r < 4; r++) {
        int oc = j * 16 + quad * 4 + r;
        float v = (acc[j][r] + bias[oc]) * 0.25503485f;   // (1/sqrt(32)) * log2(e)
        qkvb[(size_t)(b * 32 + oc) * NHW + hw0 + l16] = f2bu(v);
      }
  } else if (seg == 1) {
#pragma unroll
    for (int j = 0; j < 2; j++) {
      short4v pkv;
#pragma unroll
      for (int r = 0; r < 4; r++)
        pkv[r] = (short)f2bu(acc[j][r] + bias[32 + j * 16 + quad * 4 + r]);
      *(short4v*)&kpx[((size_t)(b * NHW) + hw0 + l16) * 32 + j * 16 + quad * 4] = pkv;
    }
  } else {
    int key = hw0 + l16;
    size_t base = ((size_t)(b * NHW + key) >> 5) * 1024 + (size_t)(key & 31);
#pragma unroll
    for (int j = 0; j < 2; j++)
#pragma unroll
      for (int r = 0; r < 4; r++) {
        int ch = j * 16 + quad * 4 + r;
        vblk[base + (size_t)ch * 32] = f2bu(acc[j][r] + bias[64 + ch]);
      }
  }
}

// ---------------- 4. LDS-free flash attention, SPLIT-K x4, swapped QK^T (r6-proven).
__global__ __launch_bounds__(256, 4) void k_attn(const us* qkvb, const us* kpx, const us* vblk,
                                                 us* Opart, float* ml) {
  int tid = threadIdx.x;
  int wave = tid >> 6, lane = tid & 63;
  int quad = lane >> 4, l16 = lane & 15;
  int blk = blockIdx.x;
  int kh = blk & 3;
  int rest = blk >> 2;
  int b = rest >> 6;
  int qbase = (rest & 63) * 64 + wave * 16;
  const us* qp = qkvb + (size_t)b * 32 * NHW;
  const us* kb_base = kpx + (size_t)b * NHW * 32;

  short8 bq;
#pragma unroll
  for (int j = 0; j < 8; j++)
    bq[j] = (short)qp[(size_t)(quad * 8 + j) * NHW + qbase + l16];

  float m_r = -1e30f, l_r = 0.f;
  floatx4 o0 = {0.f, 0.f, 0.f, 0.f}, o1 = {0.f, 0.f, 0.f, 0.f};

  int kb0 = kh * 1024;
  short8 akf[8];
#pragma unroll
  for (int t = 0; t < 8; t++)
    akf[t] = ld8(kb_base + (size_t)(kb0 + t * 16 + l16) * 32 + quad * 8);

  for (int kb = kb0; kb < kb0 + 1024; kb += 128) {
    floatx4 sT[8];
    __builtin_amdgcn_s_setprio(1);
#pragma unroll
    for (int t = 0; t < 8; t++) {
      floatx4 z = {0.f, 0.f, 0.f, 0.f};
      sT[t] = __builtin_amdgcn_mfma_f32_16x16x32_bf16(akf[t], bq, z, 0, 0, 0);
    }
    __builtin_amdgcn_s_setprio(0);

    int kbn = (kb + 128 < kb0 + 1024) ? kb + 128 : kb0;
#pragma unroll
    for (int t = 0; t < 8; t++)
      akf[t] = ld8(kb_base + (size_t)(kbn + t * 16 + l16) * 32 + quad * 8);

    float tm[8];
#pragma unroll
    for (int t = 0; t < 8; t++)
      tm[t] = fmaxf(fmaxf(fmaxf(sT[t][0], sT[t][1]), sT[t][2]), sT[t][3]);
    float mx = fmaxf(fmaxf(fmaxf(tm[0], tm[1]), tm[2]), tm[3]);
    mx = fmaxf(fmaxf(fmaxf(fmaxf(mx, tm[4]), tm[5]), tm[6]), tm[7]);
    mx = qmax4(mx);
    float mnew = fmaxf(m_r, mx);
    float alpha = exp2f(m_r - mnew);
    m_r = mnew;

    float rs0 = 0.f, rs1 = 0.f;
    unsigned pkw[8][2];
#pragma unroll
    for (int t = 0; t < 8; t++) {
      float p0 = exp2f(sT[t][0] - mnew);
      float p1 = exp2f(sT[t][1] - mnew);
      float p2 = exp2f(sT[t][2] - mnew);
      float p3 = exp2f(sT[t][3] - mnew);
      rs0 += p0 + p1;
      rs1 += p2 + p3;
      pkw[t][0] = cvt_pk_bf16(p0, p1);
      pkw[t][1] = cvt_pk_bf16(p2, p3);
    }
    float rs = qsum4(rs0 + rs1);
    l_r = l_r * alpha + rs;
#pragma unroll
    for (int r = 0; r < 4; r++) { o0[r] *= alpha; o1[r] *= alpha; }

    __builtin_amdgcn_s_setprio(1);
#pragma unroll
    for (int cc = 0; cc < 4; cc++) {
      uint2v t1 = __builtin_amdgcn_permlane32_swap(pkw[2 * cc][0], pkw[2 * cc + 1][0], false, false);
      uint2v t2 = __builtin_amdgcn_permlane16_swap(t1.x, t1.y, false, false);
      uint2v t3 = __builtin_amdgcn_permlane32_swap(pkw[2 * cc][1], pkw[2 * cc + 1][1], false, false);
      uint2v t4 = __builtin_amdgcn_permlane16_swap(t3.x, t3.y, false, false);
      uint4v pw = {t2.x, t4.x, t2.y, t4.y};
      short8 pa = *(short8*)&pw;
      const us* vb = vblk + ((size_t)(b * NHW + kb + cc * 32) >> 5) * 1024 + quad * 8;
      short8 av0 = ld8(vb + (size_t)l16 * 32);
      short8 av1 = ld8(vb + (size_t)(l16 + 16) * 32);
      o0 = __builtin_amdgcn_mfma_f32_16x16x32_bf16(av0, pa, o0, 0, 0, 0);
      o1 = __builtin_amdgcn_mfma_f32_16x16x32_bf16(av1, pa, o1, 0, 0, 0);
    }
    __builtin_amdgcn_s_setprio(0);
  }

  int q = qbase + l16;
  size_t qg = (size_t)b * NHW + q;
  us* dst = Opart + ((size_t)kh * NBN + qg) * 32;
  short4v e0, e1;
#pragma unroll
  for (int r = 0; r < 4; r++) { e0[r] = (short)f2bu(o0[r]); e1[r] = (short)f2bu(o1[r]); }
  *(short4v*)(dst + quad * 4) = e0;
  *(short4v*)(dst + 16 + quad * 4) = e1;
  if (quad == 0) {
    ml[(size_t)kh * NBN + qg] = m_r;
    ml[(size_t)KSPLIT * NBN + (size_t)kh * NBN + qg] = l_r;
  }
}

// ---------------- 4b. merge 4 split-K partials -> avb px-major bf16 (exp2 domain)
__global__ __launch_bounds__(256) void k_merge(const us* Opart, const float* ml, us* avb) {
  int idx = blockIdx.x * 256 + threadIdx.x;
  int ch = idx & 31, qg = idx >> 5;
  float mk[KSPLIT];
  float m = -1e30f;
#pragma unroll
  for (int kh = 0; kh < KSPLIT; kh++) { mk[kh] = ml[kh * NBN + qg]; m = fmaxf(m, mk[kh]); }
  float l = 0.f, v = 0.f;
#pragma unroll
  for (int kh = 0; kh < KSPLIT; kh++) {
    float a = exp2f(mk[kh] - m);
    l += ml[KSPLIT * NBN + kh * NBN + qg] * a;
    v += bu2f(Opart[((size_t)(kh * NBN) + qg) * 32 + ch]) * a;
  }
  avb[idx] = f2bu(v / l);
}

// ---------------- 5. proj GEMM, N-SPLIT x4 -> grid 1024
__global__ __launch_bounds__(256) void k_proj_g(const us* avb, const us* xT, const us* wpj, fp bias, us* x2T) {
  int wave = threadIdx.x >> 6, lane = threadIdx.x & 63;
  int quad = lane >> 4, l16 = lane & 15;
  int seg = blockIdx.x >> 8;
  int pxg0 = (blockIdx.x & 255) * 64 + wave * 16;
  short8 act = ld8(avb + (size_t)(pxg0 + l16) * 32 + quad * 8);
  floatx4 acc[4];
#pragma unroll
  for (int jn = 0; jn < 4; jn++) {
    int n = seg * 4 + jn;
    short8 wf = ld8(wpj + (size_t)(n * 16 + l16) * 32 + quad * 8);
    floatx4 z = {0.f, 0.f, 0.f, 0.f};
    acc[jn] = __builtin_amdgcn_mfma_f32_16x16x32_bf16(act, wf, z, 0, 0, 0);
  }
#pragma unroll
  for (int jn = 0; jn < 4; jn++)
#pragma unroll
    for (int r = 0; r < 4; r++) {
      int px = pxg0 + quad * 4 + r;
      int oc = (seg * 4 + jn) * 16 + l16;
      size_t oidx = (size_t)px * 256 + oc;
      x2T[oidx] = f2bu(acc[jn][r] + bias[oc] + bu2f(xT[oidx]));
    }
}

// ---------------- 6. channel mean + thick: 8 lanes/px + shfl reduce (512 blocks)
__global__ __launch_bounds__(256) void k_meanthick(const float* su, fp tw, fp tb, float* sm, float* thick) {
  int idx = blockIdx.x * 256 + threadIdx.x;   // NB*NHW*8
  int l8 = idx & 7, pxg = idx >> 3;
  int hw = pxg & 4095, b = pxg >> 12;
  const float* p = su + ((size_t)(b * 64 + l8 * 8)) * NHW + hw;
  float s = 0.f, ts = 0.f;
#pragma unroll
  for (int c = 0; c < 8; c++) {
    float v = p[(size_t)c * NHW];
    s += v;
    ts += v * tw[l8 * 8 + c];
  }
  s += __shfl_xor(s, 1); ts += __shfl_xor(ts, 1);
  s += __shfl_xor(s, 2); ts += __shfl_xor(ts, 2);
  s += __shfl_xor(s, 4); ts += __shfl_xor(ts, 4);
  if (l8 == 0) {
    sm[pxg] = s * (1.f / 64.f);
    thick[pxg] = 1.f / (1.f + __expf(-(ts + tb[0])));
  }
}

// ---------------- 7. edge conv 3x3 px-major: thread=(px, 8-oc block) -> edgeT bf16 [b*N][64]
__global__ __launch_bounds__(256) void k_edge_px(const float* sm, const us* ewT, us* edgeT) {
  int idx = blockIdx.x * 256 + threadIdx.x;   // NB*NHW*8
  int cb = idx & 7, pxg = idx >> 3;
  int b = pxg >> 12, hw = pxg & 4095;
  int y = hw >> 6, x = hw & 63;
  int c0 = cb * 8;
  float acc[8] = {0.f, 0.f, 0.f, 0.f, 0.f, 0.f, 0.f, 0.f};
#pragma unroll
  for (int ky = 0; ky < 3; ky++) {
#pragma unroll
    for (int kx = 0; kx < 3; kx++) {
      int yy = y + ky - 1, xx = x + kx - 1;
      if (yy >= 0 && yy < 64 && xx >= 0 && xx < 64) {
        float sv = sm[b * NHW + yy * 64 + xx];
        short8 wv = ld8(ewT + (ky * 3 + kx) * 64 + c0);
#pragma unroll
        for (int j = 0; j < 8; j++) acc[j] += sv * bu2f((us)wv[j]);
      }
    }
  }
  short8 pk;
#pragma unroll
  for (int j = 0; j < 8; j++) pk[j] = (short)f2bu(acc[j]);
  *(short8*)(edgeT + (size_t)pxg * 64 + c0) = pk;
}

// ---------------- 8. offset conv as MFMA GEMM: K=9x64, N=32(18 used), act=shifted edgeT rows
__global__ __launch_bounds__(256) void k_off_g(const us* edgeT, const us* woff, fp ob,
                                               const float* thick, float* offb) {
  int wave = threadIdx.x >> 6, lane = threadIdx.x & 63;
  int quad = lane >> 4, l16 = lane & 15;
  int pxg0 = blockIdx.x * 64 + wave * 16;
  int b = pxg0 >> 12;
  int pxl = pxg0 + l16;
  int hwl = pxl & 4095;
  int yl = hwl >> 6, xl = hwl & 63;
  floatx4 acc[2];
  acc[0] = (floatx4){0.f, 0.f, 0.f, 0.f};
  acc[1] = (floatx4){0.f, 0.f, 0.f, 0.f};
  const short8 zz = {0, 0, 0, 0, 0, 0, 0, 0};
#pragma unroll
  for (int t = 0; t < 9; t++) {
    int yy = yl + t / 3 - 1, xx = xl + t % 3 - 1;
    bool valid = (yy >= 0 && yy < 64 && xx >= 0 && xx < 64);
    const us* arow = edgeT + ((size_t)(b * NHW + yy * 64 + xx)) * 64;
#pragma unroll
    for (int s = 0; s < 2; s++) {
      short8 act = valid ? ld8(arow + s * 32 + quad * 8) : zz;
      int kk = t * 64 + s * 32 + quad * 8;
#pragma unroll
      for (int n = 0; n < 2; n++) {
        short8 wf = ld8(woff + (size_t)(n * 16 + l16) * 576 + kk);
        acc[n] = __builtin_amdgcn_mfma_f32_16x16x32_bf16(act, wf, acc[n], 0, 0, 0);
      }
    }
  }
#pragma unroll
  for (int n = 0; n < 2; n++)
#pragma unroll
    for (int r = 0; r < 4; r++) {
      int oc = n * 16 + l16;
      if (oc < 18) {
        int px = pxg0 + quad * 4 + r;
        int hw = px & 4095;
        float v = (acc[n][r] + ob[oc]) * (1.f + 16.f * thick[px]);
        offb[(size_t)(b * 18 + oc) * NHW + hw] = v;
      }
    }
}

// ---------------- 9. MFMA deformable conv (r10 structure; edge residual from edgeT rows)
__global__ __launch_bounds__(256) void k_deform(const float* su, const float* offb,
                                                const us* wbf, fp db,
                                                const us* edgeT, us* dbufT) {
  __shared__ __align__(16) us samT[4][16][72];
  int tid = threadIdx.x;
  int wave = tid >> 6, lane = tid & 63;
  int quad = lane >> 4, l16 = lane & 15;
  int b = blockIdx.x >> 6, row = blockIdx.x & 63;
  const float* sub = su + (size_t)b * 64 * NHW;

  int sp = lane & 15, sq = lane >> 4;
  int hw_s = row * 64 + wave * 16 + sp;
  int x_s = wave * 16 + sp;

  floatx4 acc[4];
#pragma unroll
  for (int a = 0; a < 4; a++) acc[a] = (floatx4){0.f, 0.f, 0.f, 0.f};

  for (int k = 0; k < 9; k++) {
    float dy = offb[((size_t)(b * 18 + 2 * k)) * NHW + hw_s];
    float dx = offb[((size_t)(b * 18 + 2 * k + 1)) * NHW + hw_s];
    float py = (float)(row + k / 3 - 1) + dy;
    float pxf = (float)(x_s + k % 3 - 1) + dx;
    float y0f = floorf(py), x0f = floorf(pxf);
    float wy = py - y0f, wx = pxf - x0f;
    int y0 = (int)y0f, x0 = (int)x0f;
    int y1 = y0 + 1, x1 = x0 + 1;
    float vy0 = (y0 >= 0 && y0 < 64) ? 1.f : 0.f;
    float vy1 = (y1 >= 0 && y1 < 64) ? 1.f : 0.f;
    float vx0 = (x0 >= 0 && x0 < 64) ? 1.f : 0.f;
    float vx1 = (x1 >= 0 && x1 < 64) ? 1.f : 0.f;
    float w00 = (1.f - wy) * (1.f - wx) * vy0 * vx0;
    float w01 = (1.f - wy) * wx * vy0 * vx1;
    float w10 = wy * (1.f - wx) * vy1 * vx0;
    float w11 = wy * wx * vy1 * vx1;
    int y0c = min(63, max(0, y0)), y1c = min(63, max(0, y1));
    int x0c = min(63, max(0, x0)), x1c = min(63, max(0, x1));
    int i00 = y0c * 64 + x0c, i01 = y0c * 64 + x1c;
    int i10 = y1c * 64 + x0c, i11 = y1c * 64 + x1c;

#pragma unroll
    for (int i = 0; i < 16; i += 2) {
      int c0 = sq * 16 + i;
      const float* s0 = sub + (size_t)c0 * NHW;
      const float* s1 = s0 + NHW;
      float v0 = w00 * s0[i00] + w01 * s0[i01] + w10 * s0[i10] + w11 * s0[i11];
      float v1 = w00 * s1[i00] + w01 * s1[i01] + w10 * s1[i10] + w11 * s1[i11];
      unsigned int pk = (unsigned int)f2bu(v0) | ((unsigned int)f2bu(v1) << 16);
      *(unsigned int*)&samT[wave][sp][c0] = pk;
    }

#pragma unroll
    for (int s = 0; s < 2; s++) {
      short8 bfrag = *(const short8*)&samT[wave][l16][s * 32 + quad * 8];
#pragma unroll
      for (int a = 0; a < 4; a++) {
        short8 afrag = ld8(wbf + ((size_t)(k * 64 + a * 16 + l16) * 64 + s * 32 + quad * 8));
        acc[a] = __builtin_amdgcn_mfma_f32_16x16x32_bf16(bfrag, afrag, acc[a], 0, 0, 0);
      }
    }
  }

#pragma unroll
  for (int a = 0; a < 4; a++)
#pragma unroll
    for (int r = 0; r < 4; r++) {
      int oc = a * 16 + l16;
      int pxr = row * 64 + wave * 16 + quad * 4 + r;
      size_t rowi = (size_t)(b * NHW) + pxr;
      float v = acc[a][r] + db[oc] + bu2f(edgeT[rowi * 64 + oc]);
      dbufT[rowi * 64 + oc] = f2bu(v);
    }
}

// ---------------- 10. down GEMM, N-SPLIT x4 (1 m-block each) -> grid 1024
__global__ __launch_bounds__(256) void k_down_g(const us* x2T, const us* dbufT, const us* wd, fp bias, float* ebufT) {
  int wave = threadIdx.x >> 6, lane = threadIdx.x & 63;
  int quad = lane >> 4, l16 = lane & 15;
  int seg = blockIdx.x >> 8;
  int pxg0 = (blockIdx.x & 255) * 64 + wave * 16;
  floatx4 acc = {0.f, 0.f, 0.f, 0.f};
  const us* xrow = x2T + (size_t)(pxg0 + l16) * 256 + quad * 8;
  const us* wrow = wd + (size_t)(seg * 16 + l16) * 320 + quad * 8;
#pragma unroll
  for (int k0 = 0; k0 < 256; k0 += 32) {
    short8 act = ld8(xrow + k0);
    short8 wf = ld8(wrow + k0);
    acc = __builtin_amdgcn_mfma_f32_16x16x32_bf16(act, wf, acc, 0, 0, 0);
  }
  const us* drow = dbufT + (size_t)(pxg0 + l16) * 64 + quad * 8;
#pragma unroll
  for (int k0 = 0; k0 < 64; k0 += 32) {
    short8 act = ld8(drow + k0);
    short8 wf = ld8(wrow + 256 + k0);
    acc = __builtin_amdgcn_mfma_f32_16x16x32_bf16(act, wf, acc, 0, 0, 0);
  }
  int oc = seg * 16 + l16;
#pragma unroll
  for (int r = 0; r < 4; r++) {
    int px = pxg0 + quad * 4 + r;
    ebufT[(size_t)px * 64 + oc] = acc[r] + bias[oc];
  }
}

// ---------------- 11. LayerNorm px-major: 8 lanes/px + shfl reduce (512 blocks)
__global__ __launch_bounds__(256) void k_ln(const float* eT, fp g, fp bt, us* hnT) {
  int idx = blockIdx.x * 256 + threadIdx.x;   // NB*NHW*8
  int l8 = idx & 7, px = idx >> 3;
  const float* p = eT + (size_t)px * 64 + l8 * 8;
  float v[8];
  float s = 0.f;
#pragma unroll
  for (int i = 0; i < 2; i++) {
    float4 t = ((const float4*)p)[i];
    v[i * 4] = t.x; v[i * 4 + 1] = t.y; v[i * 4 + 2] = t.z; v[i * 4 + 3] = t.w;
    s += t.x + t.y + t.z + t.w;
  }
  s += __shfl_xor(s, 1);
  s += __shfl_xor(s, 2);
  s += __shfl_xor(s, 4);
  float mu = s * (1.f / 64.f);
  float q = 0.f;
#pragma unroll
  for (int c = 0; c < 8; c++) { float d = v[c] - mu; q += d * d; }
  q += __shfl_xor(q, 1);
  q += __shfl_xor(q, 2);
  q += __shfl_xor(q, 4);
  float rstd = rsqrtf(q * (1.f / 64.f) + 1e-5f);
  short8 pk;
#pragma unroll
  for (int t = 0; t < 8; t++)
    pk[t] = (short)f2bu((v[t] - mu) * rstd * g[l8 * 8 + t] + bt[l8 * 8 + t]);
  *(short8*)(hnT + (size_t)px * 64 + l8 * 8) = pk;
}

// ---------------- 12. mlp1 GEMM, N-SPLIT x4 (4 m-blocks each) -> grid 1024
__global__ __launch_bounds__(256) void k_mlp1_g(const us* hnT, const us* wm1, fp bias, us* h1T) {
  int wave = threadIdx.x >> 6, lane = threadIdx.x & 63;
  int quad = lane >> 4, l16 = lane & 15;
  int seg = blockIdx.x >> 8;
  int pxg0 = (blockIdx.x & 255) * 64 + wave * 16;
  floatx4 acc[4];
#pragma unroll
  for (int j = 0; j < 4; j++) acc[j] = (floatx4){0.f, 0.f, 0.f, 0.f};
  const us* hrow = hnT + (size_t)(pxg0 + l16) * 64 + quad * 8;
#pragma unroll
  for (int k0 = 0; k0 < 64; k0 += 32) {
    short8 act = ld8(hrow + k0);
#pragma unroll
    for (int j = 0; j < 4; j++) {
      int m = seg * 4 + j;
      short8 wf = ld8(wm1 + (size_t)(m * 16 + l16) * 64 + k0 + quad * 8);
      acc[j] = __builtin_amdgcn_mfma_f32_16x16x32_bf16(act, wf, acc[j], 0, 0, 0);
    }
  }
#pragma unroll
  for (int j = 0; j < 4; j++)
#pragma unroll
    for (int r = 0; r < 4; r++) {
      int px = pxg0 + quad * 4 + r;
      int oc = (seg * 4 + j) * 16 + l16;
      h1T[(size_t)px * 256 + oc] = f2bu(gelu_ex(acc[j][r] + bias[oc]));
    }
}

// ---------------- 13. depthwise 3x3 + GELU, px-major (r12 verbatim)
__global__ __launch_bounds__(256) void k_dw(const us* h1T, const us* wdwT, fp bias, us* h2T) {
  int idx = blockIdx.x * 256 + threadIdx.x;   // NB*NHW*32
  int cb = idx & 31, pxg = idx >> 5;
  int b = pxg >> 12, hw = pxg & 4095;
  int y = hw >> 6, x = hw & 63;
  int c0 = cb * 8;
  float4 b0 = *(const float4*)(bias + c0);
  float4 b1 = *(const float4*)(bias + c0 + 4);
  float acc[8] = {b0.x, b0.y, b0.z, b0.w, b1.x, b1.y, b1.z, b1.w};
#pragma unroll
  for (int ky = 0; ky < 3; ky++) {
#pragma unroll
    for (int kx = 0; kx < 3; kx++) {
      int tap = ky * 3 + kx;
      short8 wv = ld8(wdwT + tap * 256 + c0);
      int yy = y + ky - 1, xx = x + kx - 1;
      if (yy >= 0 && yy < 64 && xx >= 0 && xx < 64) {
        short8 vv = ld8(h1T + ((size_t)(b * NHW + yy * 64 + xx)) * 256 + c0);
#pragma unroll
        for (int j = 0; j < 8; j++)
          acc[j] += bu2f((us)vv[j]) * bu2f((us)wv[j]);
      }
    }
  }
  short8 pk;
#pragma unroll
  for (int j = 0; j < 8; j++) pk[j] = (short)f2bu(gelu_ex(acc[j]));
  *(short8*)(h2T + (size_t)pxg * 256 + c0) = pk;
}

// ---------------- 14. mlp2 GEMM, N-SPLIT x4 (1 m-block each) -> grid 1024
__global__ __launch_bounds__(256) void k_mlp2_g(const us* h2T, const us* wm2, fp bias, const float* ebufT, us* tbufT) {
  int wave = threadIdx.x >> 6, lane = threadIdx.x & 63;
  int quad = lane >> 4, l16 = lane & 15;
  int seg = blockIdx.x >> 8;
  int pxg0 = (blockIdx.x & 255) * 64 + wave * 16;
  floatx4 acc = {0.f, 0.f, 0.f, 0.f};
  const us* hrow = h2T + (size_t)(pxg0 + l16) * 256 + quad * 8;
  const us* wrow = wm2 + (size_t)(seg * 16 + l16) * 256 + quad * 8;
#pragma unroll
  for (int k0 = 0; k0 < 256; k0 += 32) {
    short8 act = ld8(hrow + k0);
    short8 wf = ld8(wrow + k0);
    acc = __builtin_amdgcn_mfma_f32_16x16x32_bf16(act, wf, acc, 0, 0, 0);
  }
  int oc = seg * 16 + l16;
#pragma unroll
  for (int r = 0; r < 4; r++) {
    int px = pxg0 + quad * 4 + r;
    size_t oidx = (size_t)px * 64 + oc;
    tbufT[oidx] = f2bu(acc[r] + bias[oc] + ebufT[oidx]);
  }
}

// ---------------- 15. up GEMM, N-SPLIT x4 (4 m-blocks each) -> grid 1024
__global__ __launch_bounds__(256) void k_up_g(const us* tbufT, const us* wu, fp bias, float* out) {
  int wave = threadIdx.x >> 6, lane = threadIdx.x & 63;
  int quad = lane >> 4, l16 = lane & 15;
  int seg = blockIdx.x >> 8;
  int pxg0 = (blockIdx.x & 255) * 64 + wave * 16;
  int b = pxg0 >> 12, hw0 = pxg0 & 4095;
  floatx4 acc[4];
#pragma unroll
  for (int j = 0; j < 4; j++) acc[j] = (floatx4){0.f, 0.f, 0.f, 0.f};
  const us* trow = tbufT + (size_t)(pxg0 + l16) * 64 + quad * 8;
#pragma unroll
  for (int k0 = 0; k0 < 64; k0 += 32) {
    short8 bf = ld8(trow + k0);
#pragma unroll
    for (int j = 0; j < 4; j++) {
      int m = seg * 4 + j;
      short8 af = ld8(wu + (size_t)(m * 16 + l16) * 64 + k0 + quad * 8);
      acc[j] = __builtin_amdgcn_mfma_f32_16x16x32_bf16(af, bf, acc[j], 0, 0, 0);
    }
  }
#pragma unroll
  for (int j = 0; j < 4; j++)
#pragma unroll
    for (int r = 0; r < 4; r++) {
      int oc = (seg * 4 + j) * 16 + quad * 4 + r;
      out[(size_t)(b * 256 + oc) * NHW + hw0 + l16] = acc[j][r] + bias[oc];
    }
}

extern "C" void kernel_launch(void* const* d_in, const int* in_sizes, int n_in,
                              void* d_out, int out_size, void* d_ws, size_t ws_size,
                              hipStream_t stream) {
  fp x = (fp)d_in[0], skip = (fp)d_in[1], qkv_w = (fp)d_in[2], qkv_b = (fp)d_in[3],
     proj_w = (fp)d_in[4], proj_b = (fp)d_in[5], edge_w = (fp)d_in[6], thick_w = (fp)d_in[7],
     thick_b = (fp)d_in[8], off_w = (fp)d_in[9], off_b = (fp)d_in[10], deform_w = (fp)d_in[11],
     deform_b = (fp)d_in[12], ln_g = (fp)d_in[13], ln_b = (fp)d_in[14], mlp1_w = (fp)d_in[15],
     mlp1_b = (fp)d_in[16], dw_w = (fp)d_in[17], dw_b = (fp)d_in[18], mlp2_w = (fp)d_in[19],
     mlp2_b = (fp)d_in[20], down_w = (fp)d_in[21], down_b = (fp)d_in[22], up_w = (fp)d_in[23],
     up_b = (fp)d_in[24];

  float* ws = (float*)d_ws;
  // ---- layout; wc 99,136 shorts; ml 2*4*NBN f32; kpx + vblk + wbf in free gap ----
  float* su    = ws + 0;              // f32 [0, 1048576)
  us* qkvb  = (us*)(ws + 1048576);    // bf16 Q-only [b][32][N] [1048576, 1835008)
  us* avb   = (us*)(ws + 1835008);    // bf16 524,288 elems [1835008, 2097152)
  us* wc    = (us*)(ws + 2097152);    // bf16 99,136 elems  [2097152, 2146720)
  float* ml = ws + 2146720;           // f32 2*4*NBN = 131,072  [2146720, 2277792)
  us* kpx   = (us*)(ws + 2277792);    // bf16 K px-major [b*N][32]: [2277792, 2539936)
  us* vblk  = (us*)(ws + 2539936);    // bf16 V blocked [(b*N)/32][32ch][32key]: [2539936, 2802080)
  us* wbf   = (us*)(ws + 2802080);    // bf16 deform W 36,864 elems [2802080, 2820512)
  us* x2T   = (us*)(ws + 3145728);    // bf16 px-major [b*N][256]: [3145728, 5242880)
  us* edgeT = (us*)(ws + 5242880);    // bf16 px-major [b*N][64]
  float* offb  = ws + 6291456;        // f32 [6291456, 6586368)
  float* sm    = ws + 6586368;        // f32 (dead after edge)
  float* thick = ws + 6602752;        // f32 (dead after off)
  us* dbufT = (us*)(ws + 6619136);    // bf16 px-major [b*N][64]
  float* ebufT = ws + 7143424;        // f32 px-major [b*N][64]
  // aliases of dead/late regions:
  us* xT   = x2T;                     // xT live wall..proj; proj updates in-place
  us* wq   = dbufT;                   // wq written k_wall, read k_qkv_g; dbufT written k_deform (later)
  us* Opart = (us*)ebufT;             // attn partials x4; ebufT written k_down_g (later)
  us* hnT  = qkvb;                    // qkvb dead after attn
  us* h1T  = x2T;                     // x2T dead after down
  us* h2T  = (us*)ws;                 // [0, 2097152) dead by k_dw
  us* tbufT = edgeT;                  // edgeT dead after deform

  dim3 blk(256);
  k_wall<<<628, blk, 0, stream>>>(qkv_w, proj_w, mlp1_w, down_w, mlp2_w, up_w,
                                  dw_w, edge_w, off_w, deform_w, wq, wc, wbf);
  k_upsample<<<(NB * 64 * NHW) / 256, blk, 0, stream>>>(skip, su);
  k_xpose<<<1024, blk, 0, stream>>>(x, xT);
  k_qkv_g<<<3 * 256, blk, 0, stream>>>(xT, wq, qkv_b, qkvb, kpx, vblk);
  k_attn<<<(NB * NHW / 64) * KSPLIT, blk, 0, stream>>>(qkvb, kpx, vblk, Opart, ml);
  k_merge<<<(NB * NHW * 32) / 256, blk, 0, stream>>>(Opart, ml, avb);
  k_proj_g<<<4 * 256, blk, 0, stream>>>(avb, xT, wc, proj_b, x2T);
  k_meanthick<<<(NB * NHW * 8) / 256, blk, 0, stream>>>(su, thick_w, thick_b, sm, thick);
  k_edge_px<<<(NB * NHW * 8) / 256, blk, 0, stream>>>(sm, wc + 80128, edgeT);
  k_off_g<<<(NB * NHW) / 64, blk, 0, stream>>>(edgeT, wc + 80704, off_b, thick, offb);
  k_deform<<<NB * 64, blk, 0, stream>>>(su, offb, wbf, deform_b, edgeT, dbufT);
  k_down_g<<<4 * 256, blk, 0, stream>>>(x2T, dbufT, wc + 24576, down_b, ebufT);
  k_ln<<<(NB * NHW * 8) / 256, blk, 0, stream>>>(ebufT, ln_g, ln_b, hnT);
  k_mlp1_g<<<4 * 256, blk, 0, stream>>>(hnT, wc + 8192, mlp1_b, h1T);
  k_dw<<<(NB * NHW * 32) / 256, blk, 0, stream>>>(h1T, wc + 77824, dw_b, h2T);
  k_mlp2_g<<<4 * 256, blk, 0, stream>>>(h2T, wc + 45056, mlp2_b, ebufT, tbufT);
  k_up_g<<<4 * 256, blk, 0, stream>>>(tbufT, wc + 61440, up_b, (float*)d_out);
}